// Round 3
// baseline (1265.736 us; speedup 1.0000x reference)
//
#include <hip/hip_runtime.h>
#include <math.h>

#define B_    4
#define T_    2048
#define D_    1024
#define H_    4
#define DK_   256
#define DV_   512
#define KDIM_ 1024
#define VDIM_ 2048
#define FFN_  4096
#define BT_   8192   // B_*T_

typedef unsigned short bf16;
typedef __attribute__((ext_vector_type(8))) short short8;   // MFMA A/B frag (8 bf16)
typedef __attribute__((ext_vector_type(4))) short short4v;  // 4 bf16
typedef __attribute__((ext_vector_type(4))) float f32x4;    // MFMA C/D frag

// ---------------- helpers ----------------

__device__ __forceinline__ float sigmoidf_(float x) { return 1.f / (1.f + expf(-x)); }
__device__ __forceinline__ float siluf_(float x)    { return x / (1.f + expf(-x)); }
__device__ __forceinline__ float geluf_(float x)    { return 0.5f * x * (1.f + erff(x * 0.70710678118654752f)); }

__device__ __forceinline__ float bf2f(bf16 u) {
  union { unsigned int i; float f; } c; c.i = (unsigned int)u << 16; return c.f;
}
__device__ __forceinline__ bf16 f2bf(float f) {
  union { unsigned int i; float f; } c; c.f = f;
  unsigned int r = c.i + 0x7fffu + ((c.i >> 16) & 1u);   // RNE
  return (bf16)(r >> 16);
}

// async global->LDS, 16B per lane
__device__ __forceinline__ void gload16(const bf16* g, bf16* l) {
  __builtin_amdgcn_global_load_lds((__attribute__((address_space(1))) const void*)g,
                                   (__attribute__((address_space(3))) void*)l, 16, 0, 0);
}

__device__ __forceinline__ void storeC(float* p, float v) { *p = v; }
__device__ __forceinline__ void storeC(bf16* p, float v)  { *p = f2bf(v); }

// load 8 bf16 from an 8B-aligned LDS address as two b64s
__device__ __forceinline__ short8 ld76(const bf16* p) {
  union { short8 v; short4v h[2]; } u;
  u.h[0] = *(const short4v*)p;
  u.h[1] = *(const short4v*)(p + 4);
  return u.v;
}
// pack f32x4 -> 4 bf16, 8B store
__device__ __forceinline__ void st4bf(bf16* p, f32x4 v) {
  short4v o;
  o[0] = (short)f2bf(v[0]); o[1] = (short)f2bf(v[1]);
  o[2] = (short)f2bf(v[2]); o[3] = (short)f2bf(v[3]);
  *(short4v*)p = o;
}

__device__ __forceinline__ float block_sum256(float v, float* red) {
#pragma unroll
  for (int off = 32; off; off >>= 1) v += __shfl_xor(v, off, 64);
  __syncthreads();
  if ((threadIdx.x & 63) == 0) red[threadIdx.x >> 6] = v;
  __syncthreads();
  return red[0] + red[1] + red[2] + red[3];
}

// ---------------- diagnostic sentinel (ws too small) ----------------

__global__ __launch_bounds__(256) void sentinel_kernel(float* out, int n) {
  int i = blockIdx.x * 256 + threadIdx.x;
  if (i < n) out[i] = 12345.0f;
}

// ---------------- LayerNorm -> bf16 ----------------

__global__ __launch_bounds__(256) void ln_kernel(const float* __restrict__ x,
                                                 const float* __restrict__ w,
                                                 const float* __restrict__ b,
                                                 bf16* __restrict__ y) {
  __shared__ float red[4];
  int row = blockIdx.x;
  const float* xr = x + (size_t)row * D_;
  float xv[4];
  float s = 0.f;
#pragma unroll
  for (int i = 0; i < 4; i++) { xv[i] = xr[threadIdx.x + 256 * i]; s += xv[i]; }
  float mean = block_sum256(s, red) * (1.f / D_);
  float s2 = 0.f;
#pragma unroll
  for (int i = 0; i < 4; i++) { float d = xv[i] - mean; s2 += d * d; }
  float var = block_sum256(s2, red) * (1.f / D_);
  float inv = rsqrtf(var + 1e-5f);
  bf16* yr = y + (size_t)row * D_;
#pragma unroll
  for (int i = 0; i < 4; i++) {
    int c = threadIdx.x + 256 * i;
    yr[c] = f2bf((xv[i] - mean) * inv * w[c] + b[c]);
  }
}

// ---------------- weight convert+transpose: fp32 [K][N] -> bf16 [N][K] ----------------

__global__ __launch_bounds__(256) void convT_kernel(const float* __restrict__ src,
                                                    bf16* __restrict__ dst,
                                                    int K, int N) {
  __shared__ float t[32][33];
  int n0 = blockIdx.x * 32, k0 = blockIdx.y * 32;
  int tx = threadIdx.x & 31, ty = threadIdx.x >> 5;
#pragma unroll
  for (int i = 0; i < 4; i++)
    t[ty + i * 8][tx] = src[(size_t)(k0 + ty + i * 8) * N + n0 + tx];
  __syncthreads();
#pragma unroll
  for (int i = 0; i < 4; i++)
    dst[(size_t)(n0 + ty + i * 8) * K + k0 + tx] = f2bf(t[tx][ty + i * 8]);
}

// ---------------- k transpose per head: k16 [b][t][h*DK+dk] -> kT [bh][dk][t] ----------------

__global__ __launch_bounds__(256) void kT_kernel(const bf16* __restrict__ k16,
                                                 bf16* __restrict__ kT) {
  __shared__ bf16 tile[32][34];
  int t0 = blockIdx.x * 32;
  int d0 = blockIdx.y * 32;
  int bh = blockIdx.z;
  int b = bh >> 2, h = bh & 3;
  int tx = threadIdx.x & 31, ty = threadIdx.x >> 5;
#pragma unroll
  for (int i = 0; i < 4; i++)
    tile[ty + 8 * i][tx] = k16[(size_t)(b * T_ + t0 + ty + 8 * i) * KDIM_ + h * DK_ + d0 + tx];
  __syncthreads();
#pragma unroll
  for (int i = 0; i < 4; i++)
    kT[((size_t)bh * DK_ + d0 + ty + 8 * i) * T_ + t0 + tx] = tile[tx][ty + 8 * i];
}

// ---------------- bf16 MFMA GEMM (unchanged) ----------------

template <typename TC>
__global__ __launch_bounds__(256) void gemm_mfma(const bf16* __restrict__ A,
                                                 const bf16* __restrict__ Bt,
                                                 const float* __restrict__ bias,
                                                 const float* __restrict__ res,
                                                 TC* __restrict__ C,
                                                 int N, int K, int flags) {
  __shared__ __align__(16) bf16 As[128 * 32];
  __shared__ __align__(16) bf16 Bs[128 * 32];
  int tid = threadIdx.x;
  int wave = tid >> 6, lane = tid & 63;
  int bm = blockIdx.y * 128, bn = blockIdx.x * 128;
  int wm = (wave >> 1) * 64, wn = (wave & 1) * 64;
  int lm = lane & 15;
  int quad = lane >> 4;

  f32x4 acc[4][4];
#pragma unroll
  for (int i = 0; i < 4; i++)
#pragma unroll
    for (int j = 0; j < 4; j++) acc[i][j] = (f32x4){0.f, 0.f, 0.f, 0.f};

  int srow = wave * 32 + (lane >> 2);
  int scol = (lane & 3) * 8;
  const bf16* ag = A  + (size_t)(bm + srow) * K + scol;
  const bf16* bg = Bt + (size_t)(bn + srow) * K + scol;
  bf16* al = As + wave * 32 * 32;
  bf16* bl = Bs + wave * 32 * 32;
  const size_t gstep = (size_t)16 * K;

  for (int k0 = 0; k0 < K; k0 += 32) {
    gload16(ag + k0,         al);
    gload16(ag + k0 + gstep, al + 16 * 32);
    gload16(bg + k0,         bl);
    gload16(bg + k0 + gstep, bl + 16 * 32);
    __syncthreads();

    short8 af[4], bf[4];
#pragma unroll
    for (int i = 0; i < 4; i++)
      af[i] = *(const short8*)&As[(wm + i * 16 + lm) * 32 + quad * 8];
#pragma unroll
    for (int j = 0; j < 4; j++)
      bf[j] = *(const short8*)&Bs[(wn + j * 16 + lm) * 32 + quad * 8];
#pragma unroll
    for (int i = 0; i < 4; i++)
#pragma unroll
      for (int j = 0; j < 4; j++)
        acc[i][j] = __builtin_amdgcn_mfma_f32_16x16x32_bf16(af[i], bf[j], acc[i][j], 0, 0, 0);
    __syncthreads();
  }

#pragma unroll
  for (int i = 0; i < 4; i++) {
    int row0 = bm + wm + i * 16 + quad * 4;
#pragma unroll
    for (int j = 0; j < 4; j++) {
      int col = bn + wn + j * 16 + lm;
      float badd = (flags & 1) ? bias[col] : 0.f;
#pragma unroll
      for (int r = 0; r < 4; r++) {
        float v = acc[i][j][r] + badd;
        if (flags & 2) v = geluf_(v);
        if (flags & 4) v += res[(size_t)(row0 + r) * N + col];
        storeC(&C[(size_t)(row0 + r) * N + col], v);
      }
    }
  }
}

// ---------------- fused Wa/Wb projections -> g, beta ----------------

__global__ __launch_bounds__(256) void ab_kernel(const bf16* __restrict__ normed,
                                                 const float* __restrict__ Wa,
                                                 const float* __restrict__ Wb,
                                                 const float* __restrict__ A_log,
                                                 const float* __restrict__ dt_bias,
                                                 float* __restrict__ g,
                                                 float* __restrict__ beta) {
  __shared__ float red[4];
  int row = blockIdx.x;
  const bf16* xr = normed + (size_t)row * D_;
  float aacc[4] = {}, bacc[4] = {};
#pragma unroll
  for (int i = 0; i < 4; i++) {
    int d = threadIdx.x + 256 * i;
    float xv = bf2f(xr[d]);
    float4 wa = *(const float4*)&Wa[d * 4];
    float4 wb = *(const float4*)&Wb[d * 4];
    aacc[0] += xv * wa.x; aacc[1] += xv * wa.y; aacc[2] += xv * wa.z; aacc[3] += xv * wa.w;
    bacc[0] += xv * wb.x; bacc[1] += xv * wb.y; bacc[2] += xv * wb.z; bacc[3] += xv * wb.w;
  }
  float sa[4], sb[4];
#pragma unroll
  for (int h = 0; h < 4; h++) {
    sa[h] = block_sum256(aacc[h], red);
    sb[h] = block_sum256(bacc[h], red);
  }
  if (threadIdx.x < 4) {
    int h = threadIdx.x;
    float xa = sa[h] + dt_bias[h];
    float sp = (xa > 20.f) ? xa : log1pf(expf(xa));
    g[row * 4 + h] = -expf(A_log[h]) * sp;
    beta[row * 4 + h] = sigmoidf_(sb[h]);
  }
}

// ---------------- causal conv(4) + SiLU (+ L2 norm for q/k) ----------------

__global__ __launch_bounds__(256) void conv_qk_kernel(const float* __restrict__ pre,
                                                      const float* __restrict__ convw,
                                                      bf16* __restrict__ out,
                                                      float scale) {
  __shared__ float red[4];
  int blk = blockIdx.x;
  int h = blk & 3;
  int bt = blk >> 2;
  int t = bt & (T_ - 1);
  int c = h * DK_ + threadIdx.x;
  float y = 0.f;
#pragma unroll
  for (int i = 0; i < 4; i++) {
    int tt = t + i - 3;
    if (tt >= 0) y += pre[(size_t)(bt + i - 3) * KDIM_ + c] * convw[c * 4 + i];
  }
  y = siluf_(y);
  float ss = block_sum256(y * y, red);
  y *= rsqrtf(ss + 1e-6f) * scale;
  out[(size_t)bt * KDIM_ + c] = f2bf(y);
}

__global__ __launch_bounds__(256) void conv_v_kernel(const float* __restrict__ pre,
                                                     const float* __restrict__ convw,
                                                     bf16* __restrict__ out) {
  int idx = blockIdx.x * 256 + threadIdx.x;
  int c = idx & (VDIM_ - 1);
  int bt = idx >> 11;
  int t = bt & (T_ - 1);
  float y = 0.f;
#pragma unroll
  for (int i = 0; i < 4; i++) {
    int tt = t + i - 3;
    if (tt >= 0) y += pre[(size_t)(bt + i - 3) * VDIM_ + c] * convw[c * 4 + i];
  }
  out[idx] = f2bf(siluf_(y));
}

// ---------------- delta rule phase 1 (parallel over bh x chunk) ----------------

#define SP 76

__global__ __launch_bounds__(256, 2) void delta_p1(const bf16* __restrict__ q,
                                                   const bf16* __restrict__ k,
                                                   const bf16* __restrict__ v,
                                                   const float* __restrict__ g,
                                                   const float* __restrict__ beta,
                                                   bf16* __restrict__ Pg,
                                                   bf16* __restrict__ Wg,
                                                   bf16* __restrict__ Yg,
                                                   float* __restrict__ gsc) {
  __shared__ bf16 Abf[64 * SP];
  __shared__ bf16 DTg[64 * SP];
  __shared__ float Ub[64 * 64];
  __shared__ float Gc[64], Lm[64], Bt[64];

  int blk = blockIdx.x;
  int c = blk & 31, bh = blk >> 5;
  int b = bh >> 2, h = bh & 3;
  int tid = threadIdx.x;
  int wave = tid >> 6, lane = tid & 63;
  int lm = lane & 15, quad = lane >> 4;
  int r0 = c * 64;

  const bf16* kb = k + (size_t)b * T_ * KDIM_ + h * DK_;
  const bf16* qb = q + (size_t)b * T_ * KDIM_ + h * DK_;
  const bf16* vb = v + (size_t)b * T_ * VDIM_ + h * DV_;
  const float* gbp = g    + (size_t)b * T_ * H_ + h;
  const float* bbp = beta + (size_t)b * T_ * H_ + h;
  size_t cb = (size_t)bh * 32 + c;
  bf16* PgC = Pg + cb * 4096;
  bf16* WgC = Wg + cb * 64 * 512;
  bf16* YgC = Yg + cb * 64 * 256;

  // (a) cumsum of g -> Gc, Lam, beta
  if (wave == 0) {
    float gv = gbp[(size_t)(r0 + lane) * H_];
    float bv = bbp[(size_t)(r0 + lane) * H_];
#pragma unroll
    for (int d = 1; d < 64; d <<= 1) {
      float nn = __shfl_up(gv, (unsigned)d, 64);
      if (lane >= d) gv += nn;
    }
    Gc[lane] = gv; Lm[lane] = expf(gv); Bt[lane] = bv;
    gsc[cb * 64 + lane] = gv;
  }
  __syncthreads();

  // (b,c) KK^T -> Abf, QK^T -> Pg
  {
    f32x4 akk[4], aqk[4];
#pragma unroll
    for (int j = 0; j < 4; j++) { akk[j] = (f32x4){0.f,0.f,0.f,0.f}; aqk[j] = (f32x4){0.f,0.f,0.f,0.f}; }
    const bf16* krow = kb + (size_t)(r0 + 16 * wave + lm) * KDIM_;
    const bf16* qrow = qb + (size_t)(r0 + 16 * wave + lm) * KDIM_;
#pragma unroll
    for (int ks = 0; ks < 8; ks++) {
      short8 ak = *(const short8*)(krow + 8 * quad + 32 * ks);
      short8 aq = *(const short8*)(qrow + 8 * quad + 32 * ks);
#pragma unroll
      for (int j = 0; j < 4; j++) {
        short8 bk = *(const short8*)(kb + (size_t)(r0 + 16 * j + lm) * KDIM_ + 8 * quad + 32 * ks);
        akk[j] = __builtin_amdgcn_mfma_f32_16x16x32_bf16(ak, bk, akk[j], 0, 0, 0);
        aqk[j] = __builtin_amdgcn_mfma_f32_16x16x32_bf16(aq, bk, aqk[j], 0, 0, 0);
      }
    }
    float gi[4], bi[4];
#pragma unroll
    for (int r = 0; r < 4; r++) {
      int i = 16 * wave + 4 * quad + r;
      gi[r] = Gc[i]; bi[r] = Bt[i];
    }
#pragma unroll
    for (int j = 0; j < 4; j++) {
      int s = 16 * j + lm;
      float gs = Gc[s];
#pragma unroll
      for (int r = 0; r < 4; r++) {
        int i = 16 * wave + 4 * quad + r;
        float dec = expf(gi[r] - gs);
        Abf[(size_t)i * SP + s] = f2bf((s < i)  ? bi[r] * dec * akk[j][r] : 0.f);
        PgC[(size_t)i * 64 + s] = f2bf((s <= i) ? dec * aqk[j][r]        : 0.f);
      }
    }
  }

  // 12 column groups of 64: grp 0..7 -> W (RHS beta*V), grp 8..11 -> Y (RHS beta*Lam*K)
  for (int grp = 0; grp < 12; grp++) {
    __syncthreads();        // Abf ready (grp0) / prev DTg stores done
    {
      int* dz = (int*)DTg;
#pragma unroll
      for (int i = 0; i < 10; i++) {
        int idx = tid + 256 * i;
        if (idx < 64 * SP / 2) dz[idx] = 0;
      }
    }
    int cg = 16 * wave + lm;
#pragma unroll
    for (int ti = 0; ti < 4; ti++)
#pragma unroll
      for (int r = 0; r < 4; r++) {
        int t = 16 * ti + 4 * quad + r;
        float val;
        if (grp < 8) val = Bt[t] * bf2f(vb[(size_t)(r0 + t) * VDIM_ + grp * 64 + cg]);
        else         val = Bt[t] * Lm[t] * bf2f(kb[(size_t)(r0 + t) * KDIM_ + (grp - 8) * 64 + cg]);
        Ub[t * 64 + cg] = val;
      }
    __syncthreads();

    // forward substitution
#pragma unroll
    for (int j = 0; j < 4; j++) {
      if (j > 0) {
        f32x4 racc = (f32x4){0.f, 0.f, 0.f, 0.f};
        int nk = (j == 3) ? 2 : 1;
        for (int ks = 0; ks < nk; ks++) {
          short8 aa = ld76(&Abf[(size_t)(16 * j + lm) * SP + 8 * quad + 32 * ks]);
          short8 bd = ld76(&DTg[(size_t)(16 * wave + lm) * SP + 8 * quad + 32 * ks]);
          racc = __builtin_amdgcn_mfma_f32_16x16x32_bf16(aa, bd, racc, 0, 0, 0);
        }
#pragma unroll
        for (int r = 0; r < 4; r++)
          Ub[(16 * j + 4 * quad + r) * 64 + 16 * wave + lm] -= racc[r];
        __syncthreads();
      }
      if (wave == 0) {
        int tl = lane & 15, sg = lane >> 4;
        short4v ab4 = *(const short4v*)&Abf[(size_t)(16 * j + tl) * SP + 16 * j + 4 * sg];
        float av[4];
        av[0] = bf2f((bf16)ab4[0]); av[1] = bf2f((bf16)ab4[1]);
        av[2] = bf2f((bf16)ab4[2]); av[3] = bf2f((bf16)ab4[3]);
        float d[16];
#pragma unroll
        for (int t = 0; t < 16; t++) {
          float val = Ub[(16 * j + t) * 64 + lane];
#pragma unroll
          for (int s = 0; s < t; s++) {
            float ats = __shfl(av[s & 3], t + 16 * (s >> 2), 64);
            val -= ats * d[s];
          }
          d[t] = val;
          DTg[(size_t)lane * SP + 16 * j + t] = f2bf(val);
        }
      }
      __syncthreads();
    }

    // store group to Wg / Yg (row-major [t][col])
#pragma unroll
    for (int ti = 0; ti < 4; ti++)
#pragma unroll
      for (int r = 0; r < 4; r++) {
        int t = 16 * ti + 4 * quad + r;
        bf16 val = DTg[(size_t)(16 * wave + lm) * SP + t];
        if (grp < 8) WgC[(size_t)t * 512 + grp * 64 + cg] = val;
        else         YgC[(size_t)t * 256 + (grp - 8) * 64 + cg] = val;
      }
  }
}

// ---------------- delta rule phase 2 (sequential chunks) ----------------
// R3: 512 blocks (32 v-slices of 16 cols) -> 2 blocks/CU for TLP, with
// XCD-locality mapping bh = blk & 15 (16*vs == 0 mod 8, so all 32 blocks of
// one bh land on the same XCD -> shared q/Y/P/Ks become XCD-L2 hits).
// LDS 47KB/block so two co-reside. Pipeline structure unchanged from R2.

#define SP2 264
#define SD  72

__global__ __launch_bounds__(256, 2) void delta_p2(const bf16* __restrict__ q,
                                                   const bf16* __restrict__ kT,
                                                   const bf16* __restrict__ Wg,
                                                   const bf16* __restrict__ Yg,
                                                   const bf16* __restrict__ Pg,
                                                   const float* __restrict__ gsc,
                                                   bf16* __restrict__ o) {
  __shared__ __align__(16) bf16 ST[16 * SP2];    // S^T [v][dk] bf16
  __shared__ __align__(16) bf16 dT[16 * SD];     // delta^T [v][t]
  __shared__ __align__(16) bf16 dTe[16 * SD];    // (e*delta)^T [v][t]
  __shared__ float Gc[64];
  __shared__ __align__(16) bf16 Ks[8 * 256 * 8]; // kT chunk, unit (i*256+dk) -> 8 bf16
  __shared__ __align__(16) bf16 Ws[64 * 16];     // W chunk slab [t][16 v-cols], linear

  int blk = blockIdx.x;
  int bh = blk & 15, vs = blk >> 4;    // XCD-local: blk%8 == bh%8 for all vs
  int b = bh >> 2, h = bh & 3;
  int tid = threadIdx.x;
  int wave = tid >> 6, lane = tid & 63;
  int lm = lane & 15, quad = lane >> 4;
  int rt = wave;                       // row-tile (t rows 16rt..16rt+15)
  int v0 = vs * 16;

  const bf16* qb  = q  + (size_t)b * T_ * KDIM_ + h * DK_;
  const bf16* kTb = kT + (size_t)bh * DK_ * T_;
  bf16*       ob  = o  + (size_t)b * T_ * VDIM_ + h * DV_ + v0;

  f32x4 Sacc[4];                       // dk-tile (4*wave+dd) x 16 v-cols
#pragma unroll
  for (int dd = 0; dd < 4; dd++) Sacc[dd] = (f32x4){0.f, 0.f, 0.f, 0.f};

  // ---- prologue: prefetch chunk-0 q/Y fragments + gsc ----
  float gnext = gsc[(size_t)bh * 2048 + lane];
  short8 qfr[8], yfr[8];
  {
    const bf16* qrow = qb + (size_t)(16 * rt + lm) * KDIM_;
    const bf16* yrow = Yg + (size_t)bh * 32 * 16384 + (size_t)(16 * rt + lm) * 256;
#pragma unroll
    for (int kf = 0; kf < 8; kf++) {
      qfr[kf] = *(const short8*)(qrow + 8 * quad + 32 * kf);
      yfr[kf] = *(const short8*)(yrow + 8 * quad + 32 * kf);
    }
  }

  for (int c = 0; c < 32; c++) {
    const int r0 = c * 64;
    const size_t cb = (size_t)bh * 32 + c;

    // S1: stage kT slab + W slab -> LDS (async, consumed at S9 / S7)
#pragma unroll
    for (int i = 0; i < 8; i++)
      gload16(kTb + (size_t)tid * T_ + r0 + i * 8, Ks + i * 2048 + wave * 512);
    if (tid < 128)
      gload16(Wg + cb * 32768 + (size_t)(tid >> 1) * 512 + v0 + (tid & 1) * 8, Ws + tid * 8);
    __builtin_amdgcn_sched_barrier(0);

    // S2: P fragments (issued AFTER Ks/Ws -> their wait covers both)
    const bf16* pc = Pg + cb * 4096 + (size_t)(16 * rt + lm) * 64 + 8 * quad;
    short8 pfr[2];
    pfr[0] = *(const short8*)(pc);
    pfr[1] = *(const short8*)(pc + 32);
    __builtin_amdgcn_sched_barrier(0);

    // S4: stage S^T + Gc; raw barrier (vm loads stay in flight)
#pragma unroll
    for (int dd = 0; dd < 4; dd++)
      st4bf(&ST[(size_t)lm * SP2 + 16 * (4 * wave + dd) + 4 * quad], Sacc[dd]);
    Gc[lane] = gnext;   // all 4 waves write identical values (benign)
    asm volatile("s_waitcnt lgkmcnt(0)" ::: "memory");
    __builtin_amdgcn_s_barrier();

    // S5: Y = Yg@S^T, O = Q@S^T (A-frags unique per wave)
    short8 Bs[8];
#pragma unroll
    for (int kf = 0; kf < 8; kf++)
      Bs[kf] = *(const short8*)&ST[(size_t)lm * SP2 + 8 * quad + 32 * kf];
    f32x4 Yacc = (f32x4){0.f, 0.f, 0.f, 0.f};
    f32x4 Oacc = (f32x4){0.f, 0.f, 0.f, 0.f};
#pragma unroll
    for (int kf = 0; kf < 8; kf++) {
      Yacc = __builtin_amdgcn_mfma_f32_16x16x32_bf16(yfr[kf], Bs[kf], Yacc, 0, 0, 0);
      Oacc = __builtin_amdgcn_mfma_f32_16x16x32_bf16(qfr[kf], Bs[kf], Oacc, 0, 0, 0);
    }
    __builtin_amdgcn_sched_barrier(0);

    // S6: prefetch NEXT chunk's q/Y fragments + gsc
    {
      int cn = (c + 1) & 31;          // c=31 wraps: valid addresses, unused
      size_t cbn = (size_t)bh * 32 + cn;
      gnext = gsc[cbn * 64 + lane];
      const bf16* qrow = qb + (size_t)(cn * 64 + 16 * rt + lm) * KDIM_;
      const bf16* yrow = Yg + cbn * 16384 + (size_t)(16 * rt + lm) * 256;
#pragma unroll
      for (int kf = 0; kf < 8; kf++) {
        qfr[kf] = *(const short8*)(qrow + 8 * quad + 32 * kf);
        yfr[kf] = *(const short8*)(yrow + 8 * quad + 32 * kf);
      }
    }
    __builtin_amdgcn_sched_barrier(0);

    // S7: wait pfr (covers Ks/Ws); delta = W - Y@S; dT/dTe; scale O by lam
    asm volatile("" : : "v"(*(const int*)&pfr[0]), "v"(*(const int*)&pfr[1]) : "memory");
    __builtin_amdgcn_sched_barrier(0);
    float g63 = Gc[63];
    float lamv[4], erv[4];
#pragma unroll
    for (int rr = 0; rr < 4; rr++) {
      float gr = Gc[16 * rt + 4 * quad + rr];
      lamv[rr] = __expf(gr);
      erv[rr]  = __expf(g63 - gr);
    }
    {
      short4v dpack, depack;
#pragma unroll
      for (int rr = 0; rr < 4; rr++) {
        int row = 16 * rt + 4 * quad + rr;
        float dv = bf2f(Ws[row * 16 + lm]) - Yacc[rr];
        Oacc[rr] *= lamv[rr];
        dpack[rr]  = (short)f2bf(dv);
        depack[rr] = (short)f2bf(dv * erv[rr]);
      }
      *(short4v*)&dT [(size_t)lm * SD + 16 * rt + 4 * quad] = dpack;
      *(short4v*)&dTe[(size_t)lm * SD + 16 * rt + 4 * quad] = depack;
    }
    asm volatile("s_waitcnt lgkmcnt(0)" ::: "memory");
    __builtin_amdgcn_s_barrier();

    // S9 first (critical path): S <- lend*S + K^T @ (e*delta)
    float lend = __expf(g63);
    short8 Be[2];
#pragma unroll
    for (int kf = 0; kf < 2; kf++)
      Be[kf] = ld76(&dTe[(size_t)lm * SD + 8 * quad + 32 * kf]);
#pragma unroll
    for (int dd = 0; dd < 4; dd++) {
      int Dt = 4 * wave + dd;
      f32x4 s = Sacc[dd];
      s[0] *= lend; s[1] *= lend; s[2] *= lend; s[3] *= lend;
#pragma unroll
      for (int kf = 0; kf < 2; kf++) {
        short8 ka = *(const short8*)&Ks[((size_t)(quad + 4 * kf) * 256 + 16 * Dt + lm) * 8];
        s = __builtin_amdgcn_mfma_f32_16x16x32_bf16(ka, Be[kf], s, 0, 0, 0);
      }
      Sacc[dd] = s;
    }

    // S8: O += P@delta, store O
#pragma unroll
    for (int kf = 0; kf < 2; kf++) {
      short8 bd = ld76(&dT[(size_t)lm * SD + 8 * quad + 32 * kf]);
      Oacc = __builtin_amdgcn_mfma_f32_16x16x32_bf16(pfr[kf], bd, Oacc, 0, 0, 0);
    }
#pragma unroll
    for (int rr = 0; rr < 4; rr++) {
      int row = 16 * rt + 4 * quad + rr;
      ob[(size_t)(r0 + row) * VDIM_ + lm] = f2bf(Oacc[rr]);
    }
    asm volatile("s_waitcnt lgkmcnt(0)" ::: "memory");
    __builtin_amdgcn_s_barrier();      // protect ST/dT/dTe/Ks/Ws overwrite next iter
  }
}

// ---------------- gated RMSNorm (in place, bf16) ----------------

__global__ __launch_bounds__(256) void gated_rms_kernel(bf16* __restrict__ o,
                                                        const bf16* __restrict__ gate,
                                                        const float* __restrict__ onw) {
  __shared__ float red[4];
  int blk = blockIdx.x;
  int h = blk & 3;
  int bt = blk >> 2;
  size_t base = (size_t)bt * VDIM_ + h * DV_;
  int tid = threadIdx.x;
  float o1 = bf2f(o[base + tid]), o2 = bf2f(o[base + tid + 256]);
  float ss = block_sum256(o1 * o1 + o2 * o2, red);
  float s = rsqrtf(ss * (1.f / DV_) + 1e-5f);
  float g1 = bf2f(gate[base + tid]), g2 = bf2f(gate[base + tid + 256]);
  o[base + tid]       = f2bf(o1 * s * onw[tid] * siluf_(g1));
  o[base + tid + 256] = f2bf(o2 * s * onw[tid + 256] * siluf_(g2));
}

// ---------------- launch ----------------

extern "C" void kernel_launch(void* const* d_in, const int* in_sizes, int n_in,
                              void* d_out, int out_size, void* d_ws, size_t ws_size,
                              hipStream_t stream) {
  const float* x        = (const float*)d_in[0];
  const float* Wq       = (const float*)d_in[1];
  const float* Wk       = (const float*)d_in[2];
  const float* Wv       = (const float*)d_in[3];
  const float* Wa       = (const float*)d_in[4];
  const float* Wb       = (const float*)d_in[5];
  const float* Wg       = (const float*)d_in[6];
  const float* conv_q_w = (const float*)d_in[7];
  const float* conv_k_w = (const float*)d_in[8];
  const float* conv_v_w = (const float*)d_in[9];
  const float* A_log    = (const float*)d_in[10];
  const float* dt_bias  = (const float*)d_in[11];
  const float* o_norm_w = (const float*)d_in[12];
  const float* Wo       = (const float*)d_in[13];
  const float* ln1_w    = (const float*)d_in[14];
  const float* ln1_b    = (const float*)d_in[15];
  const float* ln2_w    = (const float*)d_in[16];
  const float* ln2_b    = (const float*)d_in[17];
  const float* ffn_w1   = (const float*)d_in[18];
  const float* ffn_b1   = (const float*)d_in[19];
  const float* ffn_w2   = (const float*)d_in[20];
  const float* ffn_b2   = (const float*)d_in[21];

  size_t required = (size_t)218 << 20;
  if (ws_size < required) {
    sentinel_kernel<<<(out_size + 255) / 256, 256, 0, stream>>>((float*)d_out, out_size);
    return;
  }

  char* base = (char*)d_ws;
  float* pre    = (float*)(base);                        // 64MB scratch (proj outs)
  bf16*  normed = (bf16*)(base + ((size_t)64  << 20));   // 16MB
  bf16*  q16    = (bf16*)(base + ((size_t)80  << 20));   // 16MB
  bf16*  k16    = (bf16*)(base + ((size_t)96  << 20));   // 16MB
  bf16*  v16    = (bf16*)(base + ((size_t)112 << 20));   // 32MB
  bf16*  g16    = (bf16*)(base + ((size_t)144 << 20));   // 32MB
  bf16*  o16    = (bf16*)(base + ((size_t)176 << 20));   // 32MB
  bf16*  wslot  = (bf16*)(base + ((size_t)208 << 20));   // 8MB JIT weight slot
  float* gvec   = (float*)(base + ((size_t)216 << 20));  // 128KB
  float* bvec   = gvec + (size_t)BT_ * H_;               // 128KB
  float* gsc    = (float*)(base + ((size_t)217 << 20));  // 128KB
  // delta-phase buffers (pre region + normed region, dead after ab_kernel):
  bf16*  Yg     = (bf16*)(base);                         // 16MB  [0,16)
  bf16*  Wgb    = (bf16*)(base + ((size_t)16 << 20));    // 32MB  [16,48)
  bf16*  Pg     = (bf16*)(base + ((size_t)48 << 20));    // 4MB   [48,52)
  bf16*  kTg    = (bf16*)(base + ((size_t)52 << 20));    // 16MB  [52,68)
  // later reuses:
  float* x2     = (float*)(base);                        // 32MB (after delta)
  bf16*  hb16   = (bf16*)(base + ((size_t)64  << 20));
  bf16*  ffn1   = (bf16*)(base + ((size_t)80  << 20));

  // 1) LN1 -> bf16
  ln_kernel<<<BT_, 256, 0, stream>>>(x, ln1_w, ln1_b, normed);

  // 2) projections + convs
  convT_kernel<<<dim3(KDIM_ / 32, D_ / 32), 256, 0, stream>>>(Wq, wslot, D_, KDIM_);
  gemm_mfma<float><<<dim3(KDIM_ / 128, BT_ / 128), 256, 0, stream>>>(normed, wslot, nullptr, nullptr, pre, KDIM_, D_, 0);
  conv_qk_kernel<<<BT_ * H_, 256, 0, stream>>>(pre, conv_q_w, q16, 0.0625f);

  convT_kernel<<<dim3(KDIM_ / 32, D_ / 32), 256, 0, stream>>>(Wk, wslot, D_, KDIM_);
  gemm_mfma<float><<<dim3(KDIM_ / 128, BT_ / 128), 256, 0, stream>>>(normed, wslot, nullptr, nullptr, pre, KDIM_, D_, 0);
  conv_qk_kernel<<<BT_ * H_, 256, 0, stream>>>(pre, conv_k_w, k16, 1.0f);

  convT_kernel<<<dim3(VDIM_ / 32, D_ / 32), 256, 0, stream>>>(Wv, wslot, D_, VDIM_);
  gemm_mfma<float><<<dim3(VDIM_ / 128, BT_ / 128), 256, 0, stream>>>(normed, wslot, nullptr, nullptr, pre, VDIM_, D_, 0);
  conv_v_kernel<<<(BT_ * VDIM_) / 256, 256, 0, stream>>>(pre, conv_v_w, v16);

  convT_kernel<<<dim3(VDIM_ / 32, D_ / 32), 256, 0, stream>>>(Wg, wslot, D_, VDIM_);
  gemm_mfma<bf16><<<dim3(VDIM_ / 128, BT_ / 128), 256, 0, stream>>>(normed, wslot, nullptr, nullptr, g16, VDIM_, D_, 0);

  ab_kernel<<<BT_, 256, 0, stream>>>(normed, Wa, Wb, A_log, dt_bias, gvec, bvec);

  // 3) delta rule: kT transpose + parallel phase 1 + pipelined sequential phase 2
  kT_kernel<<<dim3(T_ / 32, DK_ / 32, 16), 256, 0, stream>>>(k16, kTg);
  delta_p1<<<512, 256, 0, stream>>>(q16, k16, v16, gvec, bvec, Pg, Wgb, Yg, gsc);
  delta_p2<<<512, 256, 0, stream>>>(q16, kTg, Wgb, Yg, Pg, gsc, o16);

  // 4) gated RMSNorm (in place)
  gated_rms_kernel<<<BT_ * H_, 256, 0, stream>>>(o16, g16, o_norm_w);

  // 5) x2 = x + o @ Wo
  convT_kernel<<<dim3(D_ / 32, VDIM_ / 32), 256, 0, stream>>>(Wo, wslot, VDIM_, D_);
  gemm_mfma<float><<<dim3(D_ / 128, BT_ / 128), 256, 0, stream>>>(o16, wslot, nullptr, x, x2, D_, VDIM_, 4);

  // 6) LN2 -> bf16
  ln_kernel<<<BT_, 256, 0, stream>>>(x2, ln2_w, ln2_b, hb16);

  // 7) FFN
  convT_kernel<<<dim3(FFN_ / 32, D_ / 32), 256, 0, stream>>>(ffn_w1, wslot, D_, FFN_);
  gemm_mfma<bf16><<<dim3(FFN_ / 128, BT_ / 128), 256, 0, stream>>>(hb16, wslot, ffn_b1, nullptr, ffn1, FFN_, D_, 1 | 2);
  convT_kernel<<<dim3(D_ / 32, FFN_ / 32), 256, 0, stream>>>(ffn_w2, wslot, FFN_, D_);
  gemm_mfma<float><<<dim3(D_ / 128, BT_ / 128), 256, 0, stream>>>(ffn1, wslot, ffn_b2, x2, (float*)d_out, D_, FFN_, 1 | 4);
}

// Round 4
// 1206.196 us; speedup vs baseline: 1.0494x; 1.0494x over previous
//
#include <hip/hip_runtime.h>
#include <math.h>

#define B_    4
#define T_    2048
#define D_    1024
#define H_    4
#define DK_   256
#define DV_   512
#define KDIM_ 1024
#define VDIM_ 2048
#define FFN_  4096
#define BT_   8192   // B_*T_

typedef unsigned short bf16;
typedef __attribute__((ext_vector_type(8))) short short8;   // MFMA A/B frag (8 bf16)
typedef __attribute__((ext_vector_type(4))) short short4v;  // 4 bf16
typedef __attribute__((ext_vector_type(4))) float f32x4;    // MFMA C/D frag

// ---------------- helpers ----------------

__device__ __forceinline__ float sigmoidf_(float x) { return 1.f / (1.f + expf(-x)); }
__device__ __forceinline__ float siluf_(float x)    { return x / (1.f + expf(-x)); }
__device__ __forceinline__ float geluf_(float x)    { return 0.5f * x * (1.f + erff(x * 0.70710678118654752f)); }

__device__ __forceinline__ float bf2f(bf16 u) {
  union { unsigned int i; float f; } c; c.i = (unsigned int)u << 16; return c.f;
}
__device__ __forceinline__ bf16 f2bf(float f) {
  union { unsigned int i; float f; } c; c.f = f;
  unsigned int r = c.i + 0x7fffu + ((c.i >> 16) & 1u);   // RNE
  return (bf16)(r >> 16);
}

// async global->LDS, 16B per lane
__device__ __forceinline__ void gload16(const bf16* g, bf16* l) {
  __builtin_amdgcn_global_load_lds((__attribute__((address_space(1))) const void*)g,
                                   (__attribute__((address_space(3))) void*)l, 16, 0, 0);
}

__device__ __forceinline__ void storeC(float* p, float v) { *p = v; }
__device__ __forceinline__ void storeC(bf16* p, float v)  { *p = f2bf(v); }

// load 8 bf16 from an 8B-aligned LDS address as two b64s
__device__ __forceinline__ short8 ld76(const bf16* p) {
  union { short8 v; short4v h[2]; } u;
  u.h[0] = *(const short4v*)p;
  u.h[1] = *(const short4v*)(p + 4);
  return u.v;
}
// pack f32x4 -> 4 bf16, 8B store
__device__ __forceinline__ void st4bf(bf16* p, f32x4 v) {
  short4v o;
  o[0] = (short)f2bf(v[0]); o[1] = (short)f2bf(v[1]);
  o[2] = (short)f2bf(v[2]); o[3] = (short)f2bf(v[3]);
  *(short4v*)p = o;
}

__device__ __forceinline__ float block_sum256(float v, float* red) {
#pragma unroll
  for (int off = 32; off; off >>= 1) v += __shfl_xor(v, off, 64);
  __syncthreads();
  if ((threadIdx.x & 63) == 0) red[threadIdx.x >> 6] = v;
  __syncthreads();
  return red[0] + red[1] + red[2] + red[3];
}

// ---------------- diagnostic sentinel (ws too small) ----------------

__global__ __launch_bounds__(256) void sentinel_kernel(float* out, int n) {
  int i = blockIdx.x * 256 + threadIdx.x;
  if (i < n) out[i] = 12345.0f;
}

// ---------------- LayerNorm -> bf16 ----------------

__global__ __launch_bounds__(256) void ln_kernel(const float* __restrict__ x,
                                                 const float* __restrict__ w,
                                                 const float* __restrict__ b,
                                                 bf16* __restrict__ y) {
  __shared__ float red[4];
  int row = blockIdx.x;
  const float* xr = x + (size_t)row * D_;
  float xv[4];
  float s = 0.f;
#pragma unroll
  for (int i = 0; i < 4; i++) { xv[i] = xr[threadIdx.x + 256 * i]; s += xv[i]; }
  float mean = block_sum256(s, red) * (1.f / D_);
  float s2 = 0.f;
#pragma unroll
  for (int i = 0; i < 4; i++) { float d = xv[i] - mean; s2 += d * d; }
  float var = block_sum256(s2, red) * (1.f / D_);
  float inv = rsqrtf(var + 1e-5f);
  bf16* yr = y + (size_t)row * D_;
#pragma unroll
  for (int i = 0; i < 4; i++) {
    int c = threadIdx.x + 256 * i;
    yr[c] = f2bf((xv[i] - mean) * inv * w[c] + b[c]);
  }
}

// ---------------- weight convert+transpose: fp32 [K][N] -> bf16 [N][K] ----------------

__global__ __launch_bounds__(256) void convT_kernel(const float* __restrict__ src,
                                                    bf16* __restrict__ dst,
                                                    int K, int N) {
  __shared__ float t[32][33];
  int n0 = blockIdx.x * 32, k0 = blockIdx.y * 32;
  int tx = threadIdx.x & 31, ty = threadIdx.x >> 5;
#pragma unroll
  for (int i = 0; i < 4; i++)
    t[ty + i * 8][tx] = src[(size_t)(k0 + ty + i * 8) * N + n0 + tx];
  __syncthreads();
#pragma unroll
  for (int i = 0; i < 4; i++)
    dst[(size_t)(n0 + ty + i * 8) * K + k0 + tx] = f2bf(t[tx][ty + i * 8]);
}

// ---------------- k transpose per head: k16 [b][t][h*DK+dk] -> kT [bh][dk][t] ----------------

__global__ __launch_bounds__(256) void kT_kernel(const bf16* __restrict__ k16,
                                                 bf16* __restrict__ kT) {
  __shared__ bf16 tile[32][34];
  int t0 = blockIdx.x * 32;
  int d0 = blockIdx.y * 32;
  int bh = blockIdx.z;
  int b = bh >> 2, h = bh & 3;
  int tx = threadIdx.x & 31, ty = threadIdx.x >> 5;
#pragma unroll
  for (int i = 0; i < 4; i++)
    tile[ty + 8 * i][tx] = k16[(size_t)(b * T_ + t0 + ty + 8 * i) * KDIM_ + h * DK_ + d0 + tx];
  __syncthreads();
#pragma unroll
  for (int i = 0; i < 4; i++)
    kT[((size_t)bh * DK_ + d0 + ty + 8 * i) * T_ + t0 + tx] = tile[tx][ty + 8 * i];
}

// ---------------- bf16 MFMA GEMM (unchanged) ----------------

template <typename TC>
__global__ __launch_bounds__(256) void gemm_mfma(const bf16* __restrict__ A,
                                                 const bf16* __restrict__ Bt,
                                                 const float* __restrict__ bias,
                                                 const float* __restrict__ res,
                                                 TC* __restrict__ C,
                                                 int N, int K, int flags) {
  __shared__ __align__(16) bf16 As[128 * 32];
  __shared__ __align__(16) bf16 Bs[128 * 32];
  int tid = threadIdx.x;
  int wave = tid >> 6, lane = tid & 63;
  int bm = blockIdx.y * 128, bn = blockIdx.x * 128;
  int wm = (wave >> 1) * 64, wn = (wave & 1) * 64;
  int lm = lane & 15;
  int quad = lane >> 4;

  f32x4 acc[4][4];
#pragma unroll
  for (int i = 0; i < 4; i++)
#pragma unroll
    for (int j = 0; j < 4; j++) acc[i][j] = (f32x4){0.f, 0.f, 0.f, 0.f};

  int srow = wave * 32 + (lane >> 2);
  int scol = (lane & 3) * 8;
  const bf16* ag = A  + (size_t)(bm + srow) * K + scol;
  const bf16* bg = Bt + (size_t)(bn + srow) * K + scol;
  bf16* al = As + wave * 32 * 32;
  bf16* bl = Bs + wave * 32 * 32;
  const size_t gstep = (size_t)16 * K;

  for (int k0 = 0; k0 < K; k0 += 32) {
    gload16(ag + k0,         al);
    gload16(ag + k0 + gstep, al + 16 * 32);
    gload16(bg + k0,         bl);
    gload16(bg + k0 + gstep, bl + 16 * 32);
    __syncthreads();

    short8 af[4], bf[4];
#pragma unroll
    for (int i = 0; i < 4; i++)
      af[i] = *(const short8*)&As[(wm + i * 16 + lm) * 32 + quad * 8];
#pragma unroll
    for (int j = 0; j < 4; j++)
      bf[j] = *(const short8*)&Bs[(wn + j * 16 + lm) * 32 + quad * 8];
#pragma unroll
    for (int i = 0; i < 4; i++)
#pragma unroll
      for (int j = 0; j < 4; j++)
        acc[i][j] = __builtin_amdgcn_mfma_f32_16x16x32_bf16(af[i], bf[j], acc[i][j], 0, 0, 0);
    __syncthreads();
  }

#pragma unroll
  for (int i = 0; i < 4; i++) {
    int row0 = bm + wm + i * 16 + quad * 4;
#pragma unroll
    for (int j = 0; j < 4; j++) {
      int col = bn + wn + j * 16 + lm;
      float badd = (flags & 1) ? bias[col] : 0.f;
#pragma unroll
      for (int r = 0; r < 4; r++) {
        float v = acc[i][j][r] + badd;
        if (flags & 2) v = geluf_(v);
        if (flags & 4) v += res[(size_t)(row0 + r) * N + col];
        storeC(&C[(size_t)(row0 + r) * N + col], v);
      }
    }
  }
}

// ---------------- fused Wa/Wb projections -> g, beta ----------------

__global__ __launch_bounds__(256) void ab_kernel(const bf16* __restrict__ normed,
                                                 const float* __restrict__ Wa,
                                                 const float* __restrict__ Wb,
                                                 const float* __restrict__ A_log,
                                                 const float* __restrict__ dt_bias,
                                                 float* __restrict__ g,
                                                 float* __restrict__ beta) {
  __shared__ float red[4];
  int row = blockIdx.x;
  const bf16* xr = normed + (size_t)row * D_;
  float aacc[4] = {}, bacc[4] = {};
#pragma unroll
  for (int i = 0; i < 4; i++) {
    int d = threadIdx.x + 256 * i;
    float xv = bf2f(xr[d]);
    float4 wa = *(const float4*)&Wa[d * 4];
    float4 wb = *(const float4*)&Wb[d * 4];
    aacc[0] += xv * wa.x; aacc[1] += xv * wa.y; aacc[2] += xv * wa.z; aacc[3] += xv * wa.w;
    bacc[0] += xv * wb.x; bacc[1] += xv * wb.y; bacc[2] += xv * wb.z; bacc[3] += xv * wb.w;
  }
  float sa[4], sb[4];
#pragma unroll
  for (int h = 0; h < 4; h++) {
    sa[h] = block_sum256(aacc[h], red);
    sb[h] = block_sum256(bacc[h], red);
  }
  if (threadIdx.x < 4) {
    int h = threadIdx.x;
    float xa = sa[h] + dt_bias[h];
    float sp = (xa > 20.f) ? xa : log1pf(expf(xa));
    g[row * 4 + h] = -expf(A_log[h]) * sp;
    beta[row * 4 + h] = sigmoidf_(sb[h]);
  }
}

// ---------------- causal conv(4) + SiLU (+ L2 norm for q/k) ----------------

__global__ __launch_bounds__(256) void conv_qk_kernel(const float* __restrict__ pre,
                                                      const float* __restrict__ convw,
                                                      bf16* __restrict__ out,
                                                      float scale) {
  __shared__ float red[4];
  int blk = blockIdx.x;
  int h = blk & 3;
  int bt = blk >> 2;
  int t = bt & (T_ - 1);
  int c = h * DK_ + threadIdx.x;
  float y = 0.f;
#pragma unroll
  for (int i = 0; i < 4; i++) {
    int tt = t + i - 3;
    if (tt >= 0) y += pre[(size_t)(bt + i - 3) * KDIM_ + c] * convw[c * 4 + i];
  }
  y = siluf_(y);
  float ss = block_sum256(y * y, red);
  y *= rsqrtf(ss + 1e-6f) * scale;
  out[(size_t)bt * KDIM_ + c] = f2bf(y);
}

__global__ __launch_bounds__(256) void conv_v_kernel(const float* __restrict__ pre,
                                                     const float* __restrict__ convw,
                                                     bf16* __restrict__ out) {
  int idx = blockIdx.x * 256 + threadIdx.x;
  int c = idx & (VDIM_ - 1);
  int bt = idx >> 11;
  int t = bt & (T_ - 1);
  float y = 0.f;
#pragma unroll
  for (int i = 0; i < 4; i++) {
    int tt = t + i - 3;
    if (tt >= 0) y += pre[(size_t)(bt + i - 3) * VDIM_ + c] * convw[c * 4 + i];
  }
  out[idx] = f2bf(siluf_(y));
}

// ---------------- delta rule phase 1 (parallel over bh x chunk) ----------------

#define SP 76

__global__ __launch_bounds__(256, 2) void delta_p1(const bf16* __restrict__ q,
                                                   const bf16* __restrict__ k,
                                                   const bf16* __restrict__ v,
                                                   const float* __restrict__ g,
                                                   const float* __restrict__ beta,
                                                   bf16* __restrict__ Pg,
                                                   bf16* __restrict__ Wg,
                                                   bf16* __restrict__ Yg,
                                                   float* __restrict__ gsc) {
  __shared__ bf16 Abf[64 * SP];
  __shared__ bf16 DTg[64 * SP];
  __shared__ float Ub[64 * 64];
  __shared__ float Gc[64], Lm[64], Bt[64];

  int blk = blockIdx.x;
  int c = blk & 31, bh = blk >> 5;
  int b = bh >> 2, h = bh & 3;
  int tid = threadIdx.x;
  int wave = tid >> 6, lane = tid & 63;
  int lm = lane & 15, quad = lane >> 4;
  int r0 = c * 64;

  const bf16* kb = k + (size_t)b * T_ * KDIM_ + h * DK_;
  const bf16* qb = q + (size_t)b * T_ * KDIM_ + h * DK_;
  const bf16* vb = v + (size_t)b * T_ * VDIM_ + h * DV_;
  const float* gbp = g    + (size_t)b * T_ * H_ + h;
  const float* bbp = beta + (size_t)b * T_ * H_ + h;
  size_t cb = (size_t)bh * 32 + c;
  bf16* PgC = Pg + cb * 4096;
  bf16* WgC = Wg + cb * 64 * 512;
  bf16* YgC = Yg + cb * 64 * 256;

  // (a) cumsum of g -> Gc, Lam, beta
  if (wave == 0) {
    float gv = gbp[(size_t)(r0 + lane) * H_];
    float bv = bbp[(size_t)(r0 + lane) * H_];
#pragma unroll
    for (int d = 1; d < 64; d <<= 1) {
      float nn = __shfl_up(gv, (unsigned)d, 64);
      if (lane >= d) gv += nn;
    }
    Gc[lane] = gv; Lm[lane] = expf(gv); Bt[lane] = bv;
    gsc[cb * 64 + lane] = gv;
  }
  __syncthreads();

  // (b,c) KK^T -> Abf, QK^T -> Pg
  {
    f32x4 akk[4], aqk[4];
#pragma unroll
    for (int j = 0; j < 4; j++) { akk[j] = (f32x4){0.f,0.f,0.f,0.f}; aqk[j] = (f32x4){0.f,0.f,0.f,0.f}; }
    const bf16* krow = kb + (size_t)(r0 + 16 * wave + lm) * KDIM_;
    const bf16* qrow = qb + (size_t)(r0 + 16 * wave + lm) * KDIM_;
#pragma unroll
    for (int ks = 0; ks < 8; ks++) {
      short8 ak = *(const short8*)(krow + 8 * quad + 32 * ks);
      short8 aq = *(const short8*)(qrow + 8 * quad + 32 * ks);
#pragma unroll
      for (int j = 0; j < 4; j++) {
        short8 bk = *(const short8*)(kb + (size_t)(r0 + 16 * j + lm) * KDIM_ + 8 * quad + 32 * ks);
        akk[j] = __builtin_amdgcn_mfma_f32_16x16x32_bf16(ak, bk, akk[j], 0, 0, 0);
        aqk[j] = __builtin_amdgcn_mfma_f32_16x16x32_bf16(aq, bk, aqk[j], 0, 0, 0);
      }
    }
    float gi[4], bi[4];
#pragma unroll
    for (int r = 0; r < 4; r++) {
      int i = 16 * wave + 4 * quad + r;
      gi[r] = Gc[i]; bi[r] = Bt[i];
    }
#pragma unroll
    for (int j = 0; j < 4; j++) {
      int s = 16 * j + lm;
      float gs = Gc[s];
#pragma unroll
      for (int r = 0; r < 4; r++) {
        int i = 16 * wave + 4 * quad + r;
        float dec = expf(gi[r] - gs);
        Abf[(size_t)i * SP + s] = f2bf((s < i)  ? bi[r] * dec * akk[j][r] : 0.f);
        PgC[(size_t)i * 64 + s] = f2bf((s <= i) ? dec * aqk[j][r]        : 0.f);
      }
    }
  }

  // 12 column groups of 64: grp 0..7 -> W (RHS beta*V), grp 8..11 -> Y (RHS beta*Lam*K)
  for (int grp = 0; grp < 12; grp++) {
    __syncthreads();        // Abf ready (grp0) / prev DTg stores done
    {
      int* dz = (int*)DTg;
#pragma unroll
      for (int i = 0; i < 10; i++) {
        int idx = tid + 256 * i;
        if (idx < 64 * SP / 2) dz[idx] = 0;
      }
    }
    int cg = 16 * wave + lm;
#pragma unroll
    for (int ti = 0; ti < 4; ti++)
#pragma unroll
      for (int r = 0; r < 4; r++) {
        int t = 16 * ti + 4 * quad + r;
        float val;
        if (grp < 8) val = Bt[t] * bf2f(vb[(size_t)(r0 + t) * VDIM_ + grp * 64 + cg]);
        else         val = Bt[t] * Lm[t] * bf2f(kb[(size_t)(r0 + t) * KDIM_ + (grp - 8) * 64 + cg]);
        Ub[t * 64 + cg] = val;
      }
    __syncthreads();

    // forward substitution
#pragma unroll
    for (int j = 0; j < 4; j++) {
      if (j > 0) {
        f32x4 racc = (f32x4){0.f, 0.f, 0.f, 0.f};
        int nk = (j == 3) ? 2 : 1;
        for (int ks = 0; ks < nk; ks++) {
          short8 aa = ld76(&Abf[(size_t)(16 * j + lm) * SP + 8 * quad + 32 * ks]);
          short8 bd = ld76(&DTg[(size_t)(16 * wave + lm) * SP + 8 * quad + 32 * ks]);
          racc = __builtin_amdgcn_mfma_f32_16x16x32_bf16(aa, bd, racc, 0, 0, 0);
        }
#pragma unroll
        for (int r = 0; r < 4; r++)
          Ub[(16 * j + 4 * quad + r) * 64 + 16 * wave + lm] -= racc[r];
        __syncthreads();
      }
      if (wave == 0) {
        int tl = lane & 15, sg = lane >> 4;
        short4v ab4 = *(const short4v*)&Abf[(size_t)(16 * j + tl) * SP + 16 * j + 4 * sg];
        float av[4];
        av[0] = bf2f((bf16)ab4[0]); av[1] = bf2f((bf16)ab4[1]);
        av[2] = bf2f((bf16)ab4[2]); av[3] = bf2f((bf16)ab4[3]);
        float d[16];
#pragma unroll
        for (int t = 0; t < 16; t++) {
          float val = Ub[(16 * j + t) * 64 + lane];
#pragma unroll
          for (int s = 0; s < t; s++) {
            float ats = __shfl(av[s & 3], t + 16 * (s >> 2), 64);
            val -= ats * d[s];
          }
          d[t] = val;
          DTg[(size_t)lane * SP + 16 * j + t] = f2bf(val);
        }
      }
      __syncthreads();
    }

    // store group to Wg / Yg (row-major [t][col])
#pragma unroll
    for (int ti = 0; ti < 4; ti++)
#pragma unroll
      for (int r = 0; r < 4; r++) {
        int t = 16 * ti + 4 * quad + r;
        bf16 val = DTg[(size_t)(16 * wave + lm) * SP + t];
        if (grp < 8) WgC[(size_t)t * 512 + grp * 64 + cg] = val;
        else         YgC[(size_t)t * 256 + (grp - 8) * 64 + cg] = val;
      }
  }
}

// ---------------- delta rule phase 2 (sequential chunks; 256 blocks) ----------------
// R4: back to 32-col slices (R2 shape, least duplication) + R3's proven
// XCD-locality mapping (bh = blk & 15) + FULL cross-chunk pipelining:
// Ks/Ws double-buffered in LDS, P prefetched into regs a chunk ahead.
// Every VMEM consumer now waits on loads issued a full chunk (~2K cy) earlier.

#define SP2 264
#define SD  72

__global__ __launch_bounds__(256, 1) void delta_p2(const bf16* __restrict__ q,
                                                   const bf16* __restrict__ kT,
                                                   const bf16* __restrict__ Wg,
                                                   const bf16* __restrict__ Yg,
                                                   const bf16* __restrict__ Pg,
                                                   const float* __restrict__ gsc,
                                                   bf16* __restrict__ o) {
  __shared__ __align__(16) bf16 ST[32 * SP2];       // S^T [v][dk] bf16
  __shared__ __align__(16) bf16 dT[32 * SD];        // delta^T [v][t]
  __shared__ __align__(16) bf16 dTe[32 * SD];       // (e*delta)^T [v][t]
  __shared__ float Gc[64];
  __shared__ __align__(16) bf16 Ks[2][8 * 256 * 8]; // kT chunk (dbuf)
  __shared__ __align__(16) bf16 Ws[2][64 * 32];     // W slab [t][32 cols] (dbuf)

  int blk = blockIdx.x;
  int bh = blk & 15, vs = blk >> 4;    // XCD-local: blk%8 == bh%8 for all vs
  int b = bh >> 2, h = bh & 3;
  int tid = threadIdx.x;
  int wave = tid >> 6, lane = tid & 63;
  int lm = lane & 15, quad = lane >> 4;
  int rt = wave;                       // row-tile (t rows 16rt..16rt+15)
  int v0 = vs * 32;

  const bf16* qb  = q  + (size_t)b * T_ * KDIM_ + h * DK_;
  const bf16* kTb = kT + (size_t)bh * DK_ * T_;
  const bf16* WgB = Wg + (size_t)bh * 32 * 32768 + (size_t)(tid >> 2) * 512 + v0 + (tid & 3) * 8;
  const bf16* PgB = Pg + (size_t)bh * 32 * 4096 + (size_t)(16 * rt + lm) * 64 + 8 * quad;
  bf16*       ob  = o  + (size_t)b * T_ * VDIM_ + h * DV_ + v0;

  f32x4 Sacc[4][2];                    // dk-tile (4*wave+dd) x v-col-tile cc
#pragma unroll
  for (int dd = 0; dd < 4; dd++)
#pragma unroll
    for (int cc = 0; cc < 2; cc++) Sacc[dd][cc] = (f32x4){0.f, 0.f, 0.f, 0.f};

  // ---- prologue: stage chunk 0 (Ks/Ws async; P/q/Y/gsc regs) ----
#pragma unroll
  for (int i = 0; i < 8; i++)
    gload16(kTb + (size_t)tid * T_ + i * 8, Ks[0] + i * 2048 + wave * 512);
  gload16(WgB, Ws[0] + tid * 8);
  __builtin_amdgcn_sched_barrier(0);
  short8 pfn[2];
  pfn[0] = *(const short8*)(PgB);          // issued AFTER Ks[0]/Ws[0]
  pfn[1] = *(const short8*)(PgB + 32);
  __builtin_amdgcn_sched_barrier(0);
  float gnext = gsc[(size_t)bh * 2048 + lane], gnn = 0.f;
  short8 qfr[8], yfr[8];
  {
    const bf16* qrow = qb + (size_t)(16 * rt + lm) * KDIM_;
    const bf16* yrow = Yg + (size_t)bh * 32 * 16384 + (size_t)(16 * rt + lm) * 256;
#pragma unroll
    for (int kf = 0; kf < 8; kf++) {
      qfr[kf] = *(const short8*)(qrow + 8 * quad + 32 * kf);
      yfr[kf] = *(const short8*)(yrow + 8 * quad + 32 * kf);
    }
  }

  for (int c = 0; c < 32; c++) {
    const int r0 = c * 64;
    const int idx = c & 1;
    const bf16* Ksb = Ks[idx];
    const bf16* Wsb = Ws[idx];
    bf16* Ksn = Ks[idx ^ 1];
    bf16* Wsn = Ws[idx ^ 1];

    // S4: stage S^T + Gc; raw barrier (vm prefetches stay in flight)
#pragma unroll
    for (int dd = 0; dd < 4; dd++)
#pragma unroll
      for (int cc = 0; cc < 2; cc++)
        st4bf(&ST[(size_t)(16 * cc + lm) * SP2 + 16 * (4 * wave + dd) + 4 * quad], Sacc[dd][cc]);
    Gc[lane] = gnext;   // all 4 waves write identical values (benign)
    asm volatile("s_waitcnt lgkmcnt(0)" ::: "memory");
    __builtin_amdgcn_s_barrier();

    // S5: Y = Yg@S^T, O = Q@S^T (consumes qfr/yfr prefetched last chunk)
    f32x4 Yacc[2], Oacc[2];
#pragma unroll
    for (int cc = 0; cc < 2; cc++) { Yacc[cc] = (f32x4){0.f,0.f,0.f,0.f}; Oacc[cc] = (f32x4){0.f,0.f,0.f,0.f}; }
#pragma unroll
    for (int cc = 0; cc < 2; cc++) {
      short8 Bs[8];
#pragma unroll
      for (int kf = 0; kf < 8; kf++)
        Bs[kf] = *(const short8*)&ST[(size_t)(16 * cc + lm) * SP2 + 8 * quad + 32 * kf];
#pragma unroll
      for (int kf = 0; kf < 8; kf++) {
        Yacc[cc] = __builtin_amdgcn_mfma_f32_16x16x32_bf16(yfr[kf], Bs[kf], Yacc[cc], 0, 0, 0);
        Oacc[cc] = __builtin_amdgcn_mfma_f32_16x16x32_bf16(qfr[kf], Bs[kf], Oacc[cc], 0, 0, 0);
      }
    }
    __builtin_amdgcn_sched_barrier(0);

    // ISSUE block for chunk c+1: Ks'/Ws' (gload_lds) then q/Y/gsc reg refill
    {
      int cn = (c + 1) & 31;           // c=31 wraps: valid addresses, unused
      int rn = cn * 64;
      size_t cbn = (size_t)bh * 32 + cn;
#pragma unroll
      for (int i = 0; i < 8; i++)
        gload16(kTb + (size_t)tid * T_ + rn + i * 8, Ksn + i * 2048 + wave * 512);
      gload16(WgB + (size_t)cn * 32768, Wsn + tid * 8);
      __builtin_amdgcn_sched_barrier(0);
      gnn = gsc[cbn * 64 + lane];
      const bf16* qrow = qb + (size_t)(rn + 16 * rt + lm) * KDIM_;
      const bf16* yrow = Yg + cbn * 16384 + (size_t)(16 * rt + lm) * 256;
#pragma unroll
      for (int kf = 0; kf < 8; kf++) {
        qfr[kf] = *(const short8*)(qrow + 8 * quad + 32 * kf);
        yfr[kf] = *(const short8*)(yrow + 8 * quad + 32 * kf);
      }
    }
    __builtin_amdgcn_sched_barrier(0);

    // S7: tie pfn (loaded last chunk AFTER Ks[idx]/Ws[idx] -> wait covers both,
    // with a full chunk of issue-to-use distance); delta = W - Y@S; dT/dTe.
    asm volatile("" : : "v"(*(const int*)&pfn[0]), "v"(*(const int*)&pfn[1]) : "memory");
    __builtin_amdgcn_sched_barrier(0);
    float g63 = Gc[63];
    float lamv[4], erv[4];
#pragma unroll
    for (int rr = 0; rr < 4; rr++) {
      float gr = Gc[16 * rt + 4 * quad + rr];
      lamv[rr] = __expf(gr);
      erv[rr]  = __expf(g63 - gr);
    }
#pragma unroll
    for (int cc = 0; cc < 2; cc++) {
      short4v dpack, depack;
#pragma unroll
      for (int rr = 0; rr < 4; rr++) {
        int row = 16 * rt + 4 * quad + rr;
        float dv = bf2f(Wsb[row * 32 + 16 * cc + lm]) - Yacc[cc][rr];
        Oacc[cc][rr] *= lamv[rr];
        dpack[rr]  = (short)f2bf(dv);
        depack[rr] = (short)f2bf(dv * erv[rr]);
      }
      *(short4v*)&dT [(size_t)(16 * cc + lm) * SD + 16 * rt + 4 * quad] = dpack;
      *(short4v*)&dTe[(size_t)(16 * cc + lm) * SD + 16 * rt + 4 * quad] = depack;
    }
    asm volatile("s_waitcnt lgkmcnt(0)" ::: "memory");
    __builtin_amdgcn_s_barrier();

    // S9 (critical path first): S <- lend*S + K^T @ (e*delta)
    float lend = __expf(g63);
    short8 Be[2][2];
#pragma unroll
    for (int cc = 0; cc < 2; cc++)
#pragma unroll
      for (int kf = 0; kf < 2; kf++)
        Be[cc][kf] = ld76(&dTe[(size_t)(16 * cc + lm) * SD + 8 * quad + 32 * kf]);
#pragma unroll
    for (int dd = 0; dd < 4; dd++) {
      int Dt = 4 * wave + dd;
#pragma unroll
      for (int cc = 0; cc < 2; cc++) {
        f32x4 s = Sacc[dd][cc];
        s[0] *= lend; s[1] *= lend; s[2] *= lend; s[3] *= lend;
#pragma unroll
        for (int kf = 0; kf < 2; kf++) {
          short8 ka = *(const short8*)&Ksb[((size_t)(quad + 4 * kf) * 256 + 16 * Dt + lm) * 8];
          s = __builtin_amdgcn_mfma_f32_16x16x32_bf16(ka, Be[cc][kf], s, 0, 0, 0);
        }
        Sacc[dd][cc] = s;
      }
    }

    // S8: O += P@delta (consumes pfn), store O
#pragma unroll
    for (int cc = 0; cc < 2; cc++) {
#pragma unroll
      for (int kf = 0; kf < 2; kf++) {
        short8 bd = ld76(&dT[(size_t)(16 * cc + lm) * SD + 8 * quad + 32 * kf]);
        Oacc[cc] = __builtin_amdgcn_mfma_f32_16x16x32_bf16(pfn[kf], bd, Oacc[cc], 0, 0, 0);
      }
#pragma unroll
      for (int rr = 0; rr < 4; rr++) {
        int row = 16 * rt + 4 * quad + rr;
        ob[(size_t)(r0 + row) * VDIM_ + 16 * cc + lm] = f2bf(Oacc[cc][rr]);
      }
    }
    __builtin_amdgcn_sched_barrier(0);

    // refill pfn for chunk c+1 (after consumption; after Ks'/Ws' in issue order)
    {
      int cn = (c + 1) & 31;
      const bf16* pc = PgB + (size_t)cn * 4096;
      pfn[0] = *(const short8*)(pc);
      pfn[1] = *(const short8*)(pc + 32);
    }
    gnext = gnn;
    asm volatile("s_waitcnt lgkmcnt(0)" ::: "memory");
    __builtin_amdgcn_s_barrier();      // protect ST/dT/dTe overwrite next iter
  }
}

// ---------------- gated RMSNorm (in place, bf16) ----------------

__global__ __launch_bounds__(256) void gated_rms_kernel(bf16* __restrict__ o,
                                                        const bf16* __restrict__ gate,
                                                        const float* __restrict__ onw) {
  __shared__ float red[4];
  int blk = blockIdx.x;
  int h = blk & 3;
  int bt = blk >> 2;
  size_t base = (size_t)bt * VDIM_ + h * DV_;
  int tid = threadIdx.x;
  float o1 = bf2f(o[base + tid]), o2 = bf2f(o[base + tid + 256]);
  float ss = block_sum256(o1 * o1 + o2 * o2, red);
  float s = rsqrtf(ss * (1.f / DV_) + 1e-5f);
  float g1 = bf2f(gate[base + tid]), g2 = bf2f(gate[base + tid + 256]);
  o[base + tid]       = f2bf(o1 * s * onw[tid] * siluf_(g1));
  o[base + tid + 256] = f2bf(o2 * s * onw[tid + 256] * siluf_(g2));
}

// ---------------- launch ----------------

extern "C" void kernel_launch(void* const* d_in, const int* in_sizes, int n_in,
                              void* d_out, int out_size, void* d_ws, size_t ws_size,
                              hipStream_t stream) {
  const float* x        = (const float*)d_in[0];
  const float* Wq       = (const float*)d_in[1];
  const float* Wk       = (const float*)d_in[2];
  const float* Wv       = (const float*)d_in[3];
  const float* Wa       = (const float*)d_in[4];
  const float* Wb       = (const float*)d_in[5];
  const float* Wg       = (const float*)d_in[6];
  const float* conv_q_w = (const float*)d_in[7];
  const float* conv_k_w = (const float*)d_in[8];
  const float* conv_v_w = (const float*)d_in[9];
  const float* A_log    = (const float*)d_in[10];
  const float* dt_bias  = (const float*)d_in[11];
  const float* o_norm_w = (const float*)d_in[12];
  const float* Wo       = (const float*)d_in[13];
  const float* ln1_w    = (const float*)d_in[14];
  const float* ln1_b    = (const float*)d_in[15];
  const float* ln2_w    = (const float*)d_in[16];
  const float* ln2_b    = (const float*)d_in[17];
  const float* ffn_w1   = (const float*)d_in[18];
  const float* ffn_b1   = (const float*)d_in[19];
  const float* ffn_w2   = (const float*)d_in[20];
  const float* ffn_b2   = (const float*)d_in[21];

  size_t required = (size_t)218 << 20;
  if (ws_size < required) {
    sentinel_kernel<<<(out_size + 255) / 256, 256, 0, stream>>>((float*)d_out, out_size);
    return;
  }

  char* base = (char*)d_ws;
  float* pre    = (float*)(base);                        // 64MB scratch (proj outs)
  bf16*  normed = (bf16*)(base + ((size_t)64  << 20));   // 16MB
  bf16*  q16    = (bf16*)(base + ((size_t)80  << 20));   // 16MB
  bf16*  k16    = (bf16*)(base + ((size_t)96  << 20));   // 16MB
  bf16*  v16    = (bf16*)(base + ((size_t)112 << 20));   // 32MB
  bf16*  g16    = (bf16*)(base + ((size_t)144 << 20));   // 32MB
  bf16*  o16    = (bf16*)(base + ((size_t)176 << 20));   // 32MB
  bf16*  wslot  = (bf16*)(base + ((size_t)208 << 20));   // 8MB JIT weight slot
  float* gvec   = (float*)(base + ((size_t)216 << 20));  // 128KB
  float* bvec   = gvec + (size_t)BT_ * H_;               // 128KB
  float* gsc    = (float*)(base + ((size_t)217 << 20));  // 128KB
  // delta-phase buffers (pre region + normed region, dead after ab_kernel):
  bf16*  Yg     = (bf16*)(base);                         // 16MB  [0,16)
  bf16*  Wgb    = (bf16*)(base + ((size_t)16 << 20));    // 32MB  [16,48)
  bf16*  Pg     = (bf16*)(base + ((size_t)48 << 20));    // 4MB   [48,52)
  bf16*  kTg    = (bf16*)(base + ((size_t)52 << 20));    // 16MB  [52,68)
  // later reuses:
  float* x2     = (float*)(base);                        // 32MB (after delta)
  bf16*  hb16   = (bf16*)(base + ((size_t)64  << 20));
  bf16*  ffn1   = (bf16*)(base + ((size_t)80  << 20));

  // 1) LN1 -> bf16
  ln_kernel<<<BT_, 256, 0, stream>>>(x, ln1_w, ln1_b, normed);

  // 2) projections + convs
  convT_kernel<<<dim3(KDIM_ / 32, D_ / 32), 256, 0, stream>>>(Wq, wslot, D_, KDIM_);
  gemm_mfma<float><<<dim3(KDIM_ / 128, BT_ / 128), 256, 0, stream>>>(normed, wslot, nullptr, nullptr, pre, KDIM_, D_, 0);
  conv_qk_kernel<<<BT_ * H_, 256, 0, stream>>>(pre, conv_q_w, q16, 0.0625f);

  convT_kernel<<<dim3(KDIM_ / 32, D_ / 32), 256, 0, stream>>>(Wk, wslot, D_, KDIM_);
  gemm_mfma<float><<<dim3(KDIM_ / 128, BT_ / 128), 256, 0, stream>>>(normed, wslot, nullptr, nullptr, pre, KDIM_, D_, 0);
  conv_qk_kernel<<<BT_ * H_, 256, 0, stream>>>(pre, conv_k_w, k16, 1.0f);

  convT_kernel<<<dim3(VDIM_ / 32, D_ / 32), 256, 0, stream>>>(Wv, wslot, D_, VDIM_);
  gemm_mfma<float><<<dim3(VDIM_ / 128, BT_ / 128), 256, 0, stream>>>(normed, wslot, nullptr, nullptr, pre, VDIM_, D_, 0);
  conv_v_kernel<<<(BT_ * VDIM_) / 256, 256, 0, stream>>>(pre, conv_v_w, v16);

  convT_kernel<<<dim3(VDIM_ / 32, D_ / 32), 256, 0, stream>>>(Wg, wslot, D_, VDIM_);
  gemm_mfma<bf16><<<dim3(VDIM_ / 128, BT_ / 128), 256, 0, stream>>>(normed, wslot, nullptr, nullptr, g16, VDIM_, D_, 0);

  ab_kernel<<<BT_, 256, 0, stream>>>(normed, Wa, Wb, A_log, dt_bias, gvec, bvec);

  // 3) delta rule: kT transpose + parallel phase 1 + pipelined sequential phase 2
  kT_kernel<<<dim3(T_ / 32, DK_ / 32, 16), 256, 0, stream>>>(k16, kTg);
  delta_p1<<<512, 256, 0, stream>>>(q16, k16, v16, gvec, bvec, Pg, Wgb, Yg, gsc);
  delta_p2<<<256, 256, 0, stream>>>(q16, kTg, Wgb, Yg, Pg, gsc, o16);

  // 4) gated RMSNorm (in place)
  gated_rms_kernel<<<BT_ * H_, 256, 0, stream>>>(o16, g16, o_norm_w);

  // 5) x2 = x + o @ Wo
  convT_kernel<<<dim3(D_ / 32, VDIM_ / 32), 256, 0, stream>>>(Wo, wslot, VDIM_, D_);
  gemm_mfma<float><<<dim3(D_ / 128, BT_ / 128), 256, 0, stream>>>(o16, wslot, nullptr, x, x2, D_, VDIM_, 4);

  // 6) LN2 -> bf16
  ln_kernel<<<BT_, 256, 0, stream>>>(x2, ln2_w, ln2_b, hb16);

  // 7) FFN
  convT_kernel<<<dim3(FFN_ / 32, D_ / 32), 256, 0, stream>>>(ffn_w1, wslot, D_, FFN_);
  gemm_mfma<bf16><<<dim3(FFN_ / 128, BT_ / 128), 256, 0, stream>>>(hb16, wslot, ffn_b1, nullptr, ffn1, FFN_, D_, 1 | 2);
  convT_kernel<<<dim3(D_ / 32, FFN_ / 32), 256, 0, stream>>>(ffn_w2, wslot, FFN_, D_);
  gemm_mfma<float><<<dim3(D_ / 128, BT_ / 128), 256, 0, stream>>>(ffn1, wslot, ffn_b2, x2, (float*)d_out, D_, FFN_, 1 | 4);
}

// Round 5
// 1177.992 us; speedup vs baseline: 1.0745x; 1.0239x over previous
//
#include <hip/hip_runtime.h>
#include <math.h>

#define B_    4
#define T_    2048
#define D_    1024
#define H_    4
#define DK_   256
#define DV_   512
#define KDIM_ 1024
#define VDIM_ 2048
#define FFN_  4096
#define BT_   8192   // B_*T_

typedef unsigned short bf16;
typedef __attribute__((ext_vector_type(8))) short short8;   // MFMA A/B frag (8 bf16)
typedef __attribute__((ext_vector_type(4))) short short4v;  // 4 bf16
typedef __attribute__((ext_vector_type(4))) float f32x4;    // MFMA C/D frag

// ---------------- helpers ----------------

__device__ __forceinline__ float sigmoidf_(float x) { return 1.f / (1.f + expf(-x)); }
__device__ __forceinline__ float siluf_(float x)    { return x / (1.f + expf(-x)); }
__device__ __forceinline__ float geluf_(float x)    { return 0.5f * x * (1.f + erff(x * 0.70710678118654752f)); }

__device__ __forceinline__ float bf2f(bf16 u) {
  union { unsigned int i; float f; } c; c.i = (unsigned int)u << 16; return c.f;
}
__device__ __forceinline__ bf16 f2bf(float f) {
  union { unsigned int i; float f; } c; c.f = f;
  unsigned int r = c.i + 0x7fffu + ((c.i >> 16) & 1u);   // RNE
  return (bf16)(r >> 16);
}

// async global->LDS, 16B per lane
__device__ __forceinline__ void gload16(const bf16* g, bf16* l) {
  __builtin_amdgcn_global_load_lds((__attribute__((address_space(1))) const void*)g,
                                   (__attribute__((address_space(3))) void*)l, 16, 0, 0);
}

__device__ __forceinline__ void storeC(float* p, float v) { *p = v; }
__device__ __forceinline__ void storeC(bf16* p, float v)  { *p = f2bf(v); }

// load 8 bf16 from an 8B-aligned LDS address as two b64s
__device__ __forceinline__ short8 ld76(const bf16* p) {
  union { short8 v; short4v h[2]; } u;
  u.h[0] = *(const short4v*)p;
  u.h[1] = *(const short4v*)(p + 4);
  return u.v;
}
// pack f32x4 -> 4 bf16, 8B store
__device__ __forceinline__ void st4bf(bf16* p, f32x4 v) {
  short4v o;
  o[0] = (short)f2bf(v[0]); o[1] = (short)f2bf(v[1]);
  o[2] = (short)f2bf(v[2]); o[3] = (short)f2bf(v[3]);
  *(short4v*)p = o;
}

__device__ __forceinline__ float block_sum256(float v, float* red) {
#pragma unroll
  for (int off = 32; off; off >>= 1) v += __shfl_xor(v, off, 64);
  __syncthreads();
  if ((threadIdx.x & 63) == 0) red[threadIdx.x >> 6] = v;
  __syncthreads();
  return red[0] + red[1] + red[2] + red[3];
}

// ---------------- diagnostic sentinel (ws too small) ----------------

__global__ __launch_bounds__(256) void sentinel_kernel(float* out, int n) {
  int i = blockIdx.x * 256 + threadIdx.x;
  if (i < n) out[i] = 12345.0f;
}

// ---------------- LayerNorm -> bf16 ----------------

__global__ __launch_bounds__(256) void ln_kernel(const float* __restrict__ x,
                                                 const float* __restrict__ w,
                                                 const float* __restrict__ b,
                                                 bf16* __restrict__ y) {
  __shared__ float red[4];
  int row = blockIdx.x;
  const float* xr = x + (size_t)row * D_;
  float xv[4];
  float s = 0.f;
#pragma unroll
  for (int i = 0; i < 4; i++) { xv[i] = xr[threadIdx.x + 256 * i]; s += xv[i]; }
  float mean = block_sum256(s, red) * (1.f / D_);
  float s2 = 0.f;
#pragma unroll
  for (int i = 0; i < 4; i++) { float d = xv[i] - mean; s2 += d * d; }
  float var = block_sum256(s2, red) * (1.f / D_);
  float inv = rsqrtf(var + 1e-5f);
  bf16* yr = y + (size_t)row * D_;
#pragma unroll
  for (int i = 0; i < 4; i++) {
    int c = threadIdx.x + 256 * i;
    yr[c] = f2bf((xv[i] - mean) * inv * w[c] + b[c]);
  }
}

// ---------------- weight convert+transpose: fp32 [K][N] -> bf16 [N][K] ----------------

__global__ __launch_bounds__(256) void convT_kernel(const float* __restrict__ src,
                                                    bf16* __restrict__ dst,
                                                    int K, int N) {
  __shared__ float t[32][33];
  int n0 = blockIdx.x * 32, k0 = blockIdx.y * 32;
  int tx = threadIdx.x & 31, ty = threadIdx.x >> 5;
#pragma unroll
  for (int i = 0; i < 4; i++)
    t[ty + i * 8][tx] = src[(size_t)(k0 + ty + i * 8) * N + n0 + tx];
  __syncthreads();
#pragma unroll
  for (int i = 0; i < 4; i++)
    dst[(size_t)(n0 + ty + i * 8) * K + k0 + tx] = f2bf(t[tx][ty + i * 8]);
}

// ---- k transpose per head, CHUNK-MAJOR: k16 [b][t][h*DK+dk] ->
// kTc [bh][c=t>>6][tb=(t>>3)&7][dk][te=t&7]  (contiguous 32KB per chunk,
// exactly the LDS layout delta_p2 consumes -> fully coalesced gload_lds)

__global__ __launch_bounds__(256) void kT_kernel(const bf16* __restrict__ k16,
                                                 bf16* __restrict__ kT) {
  __shared__ bf16 tile[32][34];
  int t0 = blockIdx.x * 32;
  int d0 = blockIdx.y * 32;
  int bh = blockIdx.z;
  int b = bh >> 2, h = bh & 3;
  int tx = threadIdx.x & 31, ty = threadIdx.x >> 5;
#pragma unroll
  for (int i = 0; i < 4; i++)
    tile[ty + 8 * i][tx] = k16[(size_t)(b * T_ + t0 + ty + 8 * i) * KDIM_ + h * DK_ + d0 + tx];
  __syncthreads();
  int t = t0 + tx;
  int c = t >> 6, tb = (t >> 3) & 7, te = t & 7;
  size_t base = ((size_t)(bh * 32 + c) * 8 + tb) * 2048 + te;
#pragma unroll
  for (int i = 0; i < 4; i++)
    kT[base + (size_t)(d0 + ty + 8 * i) * 8] = tile[tx][ty + 8 * i];
}

// ---------------- bf16 MFMA GEMM (unchanged) ----------------

template <typename TC>
__global__ __launch_bounds__(256) void gemm_mfma(const bf16* __restrict__ A,
                                                 const bf16* __restrict__ Bt,
                                                 const float* __restrict__ bias,
                                                 const float* __restrict__ res,
                                                 TC* __restrict__ C,
                                                 int N, int K, int flags) {
  __shared__ __align__(16) bf16 As[128 * 32];
  __shared__ __align__(16) bf16 Bs[128 * 32];
  int tid = threadIdx.x;
  int wave = tid >> 6, lane = tid & 63;
  int bm = blockIdx.y * 128, bn = blockIdx.x * 128;
  int wm = (wave >> 1) * 64, wn = (wave & 1) * 64;
  int lm = lane & 15;
  int quad = lane >> 4;

  f32x4 acc[4][4];
#pragma unroll
  for (int i = 0; i < 4; i++)
#pragma unroll
    for (int j = 0; j < 4; j++) acc[i][j] = (f32x4){0.f, 0.f, 0.f, 0.f};

  int srow = wave * 32 + (lane >> 2);
  int scol = (lane & 3) * 8;
  const bf16* ag = A  + (size_t)(bm + srow) * K + scol;
  const bf16* bg = Bt + (size_t)(bn + srow) * K + scol;
  bf16* al = As + wave * 32 * 32;
  bf16* bl = Bs + wave * 32 * 32;
  const size_t gstep = (size_t)16 * K;

  for (int k0 = 0; k0 < K; k0 += 32) {
    gload16(ag + k0,         al);
    gload16(ag + k0 + gstep, al + 16 * 32);
    gload16(bg + k0,         bl);
    gload16(bg + k0 + gstep, bl + 16 * 32);
    __syncthreads();

    short8 af[4], bf[4];
#pragma unroll
    for (int i = 0; i < 4; i++)
      af[i] = *(const short8*)&As[(wm + i * 16 + lm) * 32 + quad * 8];
#pragma unroll
    for (int j = 0; j < 4; j++)
      bf[j] = *(const short8*)&Bs[(wn + j * 16 + lm) * 32 + quad * 8];
#pragma unroll
    for (int i = 0; i < 4; i++)
#pragma unroll
      for (int j = 0; j < 4; j++)
        acc[i][j] = __builtin_amdgcn_mfma_f32_16x16x32_bf16(af[i], bf[j], acc[i][j], 0, 0, 0);
    __syncthreads();
  }

#pragma unroll
  for (int i = 0; i < 4; i++) {
    int row0 = bm + wm + i * 16 + quad * 4;
#pragma unroll
    for (int j = 0; j < 4; j++) {
      int col = bn + wn + j * 16 + lm;
      float badd = (flags & 1) ? bias[col] : 0.f;
#pragma unroll
      for (int r = 0; r < 4; r++) {
        float v = acc[i][j][r] + badd;
        if (flags & 2) v = geluf_(v);
        if (flags & 4) v += res[(size_t)(row0 + r) * N + col];
        storeC(&C[(size_t)(row0 + r) * N + col], v);
      }
    }
  }
}

// ---------------- fused Wa/Wb projections -> g, beta ----------------

__global__ __launch_bounds__(256) void ab_kernel(const bf16* __restrict__ normed,
                                                 const float* __restrict__ Wa,
                                                 const float* __restrict__ Wb,
                                                 const float* __restrict__ A_log,
                                                 const float* __restrict__ dt_bias,
                                                 float* __restrict__ g,
                                                 float* __restrict__ beta) {
  __shared__ float red[4];
  int row = blockIdx.x;
  const bf16* xr = normed + (size_t)row * D_;
  float aacc[4] = {}, bacc[4] = {};
#pragma unroll
  for (int i = 0; i < 4; i++) {
    int d = threadIdx.x + 256 * i;
    float xv = bf2f(xr[d]);
    float4 wa = *(const float4*)&Wa[d * 4];
    float4 wb = *(const float4*)&Wb[d * 4];
    aacc[0] += xv * wa.x; aacc[1] += xv * wa.y; aacc[2] += xv * wa.z; aacc[3] += xv * wa.w;
    bacc[0] += xv * wb.x; bacc[1] += xv * wb.y; bacc[2] += xv * wb.z; bacc[3] += xv * wb.w;
  }
  float sa[4], sb[4];
#pragma unroll
  for (int h = 0; h < 4; h++) {
    sa[h] = block_sum256(aacc[h], red);
    sb[h] = block_sum256(bacc[h], red);
  }
  if (threadIdx.x < 4) {
    int h = threadIdx.x;
    float xa = sa[h] + dt_bias[h];
    float sp = (xa > 20.f) ? xa : log1pf(expf(xa));
    g[row * 4 + h] = -expf(A_log[h]) * sp;
    beta[row * 4 + h] = sigmoidf_(sb[h]);
  }
}

// ---------------- causal conv(4) + SiLU (+ L2 norm for q/k) ----------------

__global__ __launch_bounds__(256) void conv_qk_kernel(const float* __restrict__ pre,
                                                      const float* __restrict__ convw,
                                                      bf16* __restrict__ out,
                                                      float scale) {
  __shared__ float red[4];
  int blk = blockIdx.x;
  int h = blk & 3;
  int bt = blk >> 2;
  int t = bt & (T_ - 1);
  int c = h * DK_ + threadIdx.x;
  float y = 0.f;
#pragma unroll
  for (int i = 0; i < 4; i++) {
    int tt = t + i - 3;
    if (tt >= 0) y += pre[(size_t)(bt + i - 3) * KDIM_ + c] * convw[c * 4 + i];
  }
  y = siluf_(y);
  float ss = block_sum256(y * y, red);
  y *= rsqrtf(ss + 1e-6f) * scale;
  out[(size_t)bt * KDIM_ + c] = f2bf(y);
}

__global__ __launch_bounds__(256) void conv_v_kernel(const float* __restrict__ pre,
                                                     const float* __restrict__ convw,
                                                     bf16* __restrict__ out) {
  int idx = blockIdx.x * 256 + threadIdx.x;
  int c = idx & (VDIM_ - 1);
  int bt = idx >> 11;
  int t = bt & (T_ - 1);
  float y = 0.f;
#pragma unroll
  for (int i = 0; i < 4; i++) {
    int tt = t + i - 3;
    if (tt >= 0) y += pre[(size_t)(bt + i - 3) * VDIM_ + c] * convw[c * 4 + i];
  }
  out[idx] = f2bf(siluf_(y));
}

// ---------------- delta rule phase 1 (parallel over bh x chunk) ----------------

#define SP 76

__global__ __launch_bounds__(256, 2) void delta_p1(const bf16* __restrict__ q,
                                                   const bf16* __restrict__ k,
                                                   const bf16* __restrict__ v,
                                                   const float* __restrict__ g,
                                                   const float* __restrict__ beta,
                                                   bf16* __restrict__ Pg,
                                                   bf16* __restrict__ Wg,
                                                   bf16* __restrict__ Yg,
                                                   float* __restrict__ gsc) {
  __shared__ bf16 Abf[64 * SP];
  __shared__ bf16 DTg[64 * SP];
  __shared__ float Ub[64 * 64];
  __shared__ float Gc[64], Lm[64], Bt[64];

  int blk = blockIdx.x;
  int c = blk & 31, bh = blk >> 5;
  int b = bh >> 2, h = bh & 3;
  int tid = threadIdx.x;
  int wave = tid >> 6, lane = tid & 63;
  int lm = lane & 15, quad = lane >> 4;
  int r0 = c * 64;

  const bf16* kb = k + (size_t)b * T_ * KDIM_ + h * DK_;
  const bf16* qb = q + (size_t)b * T_ * KDIM_ + h * DK_;
  const bf16* vb = v + (size_t)b * T_ * VDIM_ + h * DV_;
  const float* gbp = g    + (size_t)b * T_ * H_ + h;
  const float* bbp = beta + (size_t)b * T_ * H_ + h;
  size_t cb = (size_t)bh * 32 + c;
  bf16* PgC = Pg + cb * 4096;
  bf16* WgC = Wg + cb * 64 * 512;
  bf16* YgC = Yg + cb * 64 * 256;

  // (a) cumsum of g -> Gc, Lam, beta
  if (wave == 0) {
    float gv = gbp[(size_t)(r0 + lane) * H_];
    float bv = bbp[(size_t)(r0 + lane) * H_];
#pragma unroll
    for (int d = 1; d < 64; d <<= 1) {
      float nn = __shfl_up(gv, (unsigned)d, 64);
      if (lane >= d) gv += nn;
    }
    Gc[lane] = gv; Lm[lane] = expf(gv); Bt[lane] = bv;
    gsc[cb * 64 + lane] = gv;
  }
  __syncthreads();

  // (b,c) KK^T -> Abf, QK^T -> Pg
  {
    f32x4 akk[4], aqk[4];
#pragma unroll
    for (int j = 0; j < 4; j++) { akk[j] = (f32x4){0.f,0.f,0.f,0.f}; aqk[j] = (f32x4){0.f,0.f,0.f,0.f}; }
    const bf16* krow = kb + (size_t)(r0 + 16 * wave + lm) * KDIM_;
    const bf16* qrow = qb + (size_t)(r0 + 16 * wave + lm) * KDIM_;
#pragma unroll
    for (int ks = 0; ks < 8; ks++) {
      short8 ak = *(const short8*)(krow + 8 * quad + 32 * ks);
      short8 aq = *(const short8*)(qrow + 8 * quad + 32 * ks);
#pragma unroll
      for (int j = 0; j < 4; j++) {
        short8 bk = *(const short8*)(kb + (size_t)(r0 + 16 * j + lm) * KDIM_ + 8 * quad + 32 * ks);
        akk[j] = __builtin_amdgcn_mfma_f32_16x16x32_bf16(ak, bk, akk[j], 0, 0, 0);
        aqk[j] = __builtin_amdgcn_mfma_f32_16x16x32_bf16(aq, bk, aqk[j], 0, 0, 0);
      }
    }
    float gi[4], bi[4];
#pragma unroll
    for (int r = 0; r < 4; r++) {
      int i = 16 * wave + 4 * quad + r;
      gi[r] = Gc[i]; bi[r] = Bt[i];
    }
#pragma unroll
    for (int j = 0; j < 4; j++) {
      int s = 16 * j + lm;
      float gs = Gc[s];
#pragma unroll
      for (int r = 0; r < 4; r++) {
        int i = 16 * wave + 4 * quad + r;
        float dec = expf(gi[r] - gs);
        Abf[(size_t)i * SP + s] = f2bf((s < i)  ? bi[r] * dec * akk[j][r] : 0.f);
        PgC[(size_t)i * 64 + s] = f2bf((s <= i) ? dec * aqk[j][r]        : 0.f);
      }
    }
  }

  // 12 column groups of 64: grp 0..7 -> W (RHS beta*V), grp 8..11 -> Y (RHS beta*Lam*K)
  for (int grp = 0; grp < 12; grp++) {
    __syncthreads();        // Abf ready (grp0) / prev DTg stores done
    {
      int* dz = (int*)DTg;
#pragma unroll
      for (int i = 0; i < 10; i++) {
        int idx = tid + 256 * i;
        if (idx < 64 * SP / 2) dz[idx] = 0;
      }
    }
    int cg = 16 * wave + lm;
#pragma unroll
    for (int ti = 0; ti < 4; ti++)
#pragma unroll
      for (int r = 0; r < 4; r++) {
        int t = 16 * ti + 4 * quad + r;
        float val;
        if (grp < 8) val = Bt[t] * bf2f(vb[(size_t)(r0 + t) * VDIM_ + grp * 64 + cg]);
        else         val = Bt[t] * Lm[t] * bf2f(kb[(size_t)(r0 + t) * KDIM_ + (grp - 8) * 64 + cg]);
        Ub[t * 64 + cg] = val;
      }
    __syncthreads();

    // forward substitution
#pragma unroll
    for (int j = 0; j < 4; j++) {
      if (j > 0) {
        f32x4 racc = (f32x4){0.f, 0.f, 0.f, 0.f};
        int nk = (j == 3) ? 2 : 1;
        for (int ks = 0; ks < nk; ks++) {
          short8 aa = ld76(&Abf[(size_t)(16 * j + lm) * SP + 8 * quad + 32 * ks]);
          short8 bd = ld76(&DTg[(size_t)(16 * wave + lm) * SP + 8 * quad + 32 * ks]);
          racc = __builtin_amdgcn_mfma_f32_16x16x32_bf16(aa, bd, racc, 0, 0, 0);
        }
#pragma unroll
        for (int r = 0; r < 4; r++)
          Ub[(16 * j + 4 * quad + r) * 64 + 16 * wave + lm] -= racc[r];
        __syncthreads();
      }
      if (wave == 0) {
        int tl = lane & 15, sg = lane >> 4;
        short4v ab4 = *(const short4v*)&Abf[(size_t)(16 * j + tl) * SP + 16 * j + 4 * sg];
        float av[4];
        av[0] = bf2f((bf16)ab4[0]); av[1] = bf2f((bf16)ab4[1]);
        av[2] = bf2f((bf16)ab4[2]); av[3] = bf2f((bf16)ab4[3]);
        float d[16];
#pragma unroll
        for (int t = 0; t < 16; t++) {
          float val = Ub[(16 * j + t) * 64 + lane];
#pragma unroll
          for (int s = 0; s < t; s++) {
            float ats = __shfl(av[s & 3], t + 16 * (s >> 2), 64);
            val -= ats * d[s];
          }
          d[t] = val;
          DTg[(size_t)lane * SP + 16 * j + t] = f2bf(val);
        }
      }
      __syncthreads();
    }

    // store group to Wg / Yg (row-major [t][col])
#pragma unroll
    for (int ti = 0; ti < 4; ti++)
#pragma unroll
      for (int r = 0; r < 4; r++) {
        int t = 16 * ti + 4 * quad + r;
        bf16 val = DTg[(size_t)(16 * wave + lm) * SP + t];
        if (grp < 8) WgC[(size_t)t * 512 + grp * 64 + cg] = val;
        else         YgC[(size_t)t * 256 + (grp - 8) * 64 + cg] = val;
      }
  }
}

// ---------------- delta rule phase 2 (sequential chunks; 256 blocks) ----------------
// R5: kT is now CHUNK-MAJOR (32KB contiguous per chunk, matching the Ks LDS
// layout exactly) -> Ks staging is 32 fully-coalesced 1KB gload_lds instrs
// (512 L1 line transactions vs 2048 at 25% efficiency before). Pipeline
// structure (full cross-chunk prefetch, Ks/Ws dbuf, XCD-local bh mapping)
// unchanged from R4. S9 read indexing byte-identical to R4.

#define SP2 264
#define SD  72

__global__ __launch_bounds__(256, 1) void delta_p2(const bf16* __restrict__ q,
                                                   const bf16* __restrict__ kT,
                                                   const bf16* __restrict__ Wg,
                                                   const bf16* __restrict__ Yg,
                                                   const bf16* __restrict__ Pg,
                                                   const float* __restrict__ gsc,
                                                   bf16* __restrict__ o) {
  __shared__ __align__(16) bf16 ST[32 * SP2];       // S^T [v][dk] bf16
  __shared__ __align__(16) bf16 dT[32 * SD];        // delta^T [v][t]
  __shared__ __align__(16) bf16 dTe[32 * SD];       // (e*delta)^T [v][t]
  __shared__ float Gc[64];
  __shared__ __align__(16) bf16 Ks[2][8 * 256 * 8]; // kT chunk (dbuf), [tb][dk][te]
  __shared__ __align__(16) bf16 Ws[2][64 * 32];     // W slab [t][32 cols] (dbuf)

  int blk = blockIdx.x;
  int bh = blk & 15, vs = blk >> 4;    // XCD-local: blk%8 == bh%8 for all vs
  int b = bh >> 2, h = bh & 3;
  int tid = threadIdx.x;
  int wave = tid >> 6, lane = tid & 63;
  int lm = lane & 15, quad = lane >> 4;
  int rt = wave;                       // row-tile (t rows 16rt..16rt+15)
  int v0 = vs * 32;

  const bf16* qb  = q  + (size_t)b * T_ * KDIM_ + h * DK_;
  const bf16* kTb = kT + (size_t)bh * 32 * 16384;   // chunk-major base
  const bf16* WgB = Wg + (size_t)bh * 32 * 32768 + (size_t)(tid >> 2) * 512 + v0 + (tid & 3) * 8;
  const bf16* PgB = Pg + (size_t)bh * 32 * 4096 + (size_t)(16 * rt + lm) * 64 + 8 * quad;
  bf16*       ob  = o  + (size_t)b * T_ * VDIM_ + h * DV_ + v0;

  f32x4 Sacc[4][2];                    // dk-tile (4*wave+dd) x v-col-tile cc
#pragma unroll
  for (int dd = 0; dd < 4; dd++)
#pragma unroll
    for (int cc = 0; cc < 2; cc++) Sacc[dd][cc] = (f32x4){0.f, 0.f, 0.f, 0.f};

  // ---- prologue: stage chunk 0 (Ks/Ws async; P/q/Y/gsc regs) ----
#pragma unroll
  for (int i = 0; i < 8; i++)
    gload16(kTb + i * 2048 + tid * 8, Ks[0] + i * 2048 + wave * 512);
  gload16(WgB, Ws[0] + tid * 8);
  __builtin_amdgcn_sched_barrier(0);
  short8 pfn[2];
  pfn[0] = *(const short8*)(PgB);          // issued AFTER Ks[0]/Ws[0]
  pfn[1] = *(const short8*)(PgB + 32);
  __builtin_amdgcn_sched_barrier(0);
  float gnext = gsc[(size_t)bh * 2048 + lane], gnn = 0.f;
  short8 qfr[8], yfr[8];
  {
    const bf16* qrow = qb + (size_t)(16 * rt + lm) * KDIM_;
    const bf16* yrow = Yg + (size_t)bh * 32 * 16384 + (size_t)(16 * rt + lm) * 256;
#pragma unroll
    for (int kf = 0; kf < 8; kf++) {
      qfr[kf] = *(const short8*)(qrow + 8 * quad + 32 * kf);
      yfr[kf] = *(const short8*)(yrow + 8 * quad + 32 * kf);
    }
  }

  for (int c = 0; c < 32; c++) {
    const int r0 = c * 64;
    const int idx = c & 1;
    const bf16* Ksb = Ks[idx];
    const bf16* Wsb = Ws[idx];
    bf16* Ksn = Ks[idx ^ 1];
    bf16* Wsn = Ws[idx ^ 1];

    // S4: stage S^T + Gc; raw barrier (vm prefetches stay in flight)
#pragma unroll
    for (int dd = 0; dd < 4; dd++)
#pragma unroll
      for (int cc = 0; cc < 2; cc++)
        st4bf(&ST[(size_t)(16 * cc + lm) * SP2 + 16 * (4 * wave + dd) + 4 * quad], Sacc[dd][cc]);
    Gc[lane] = gnext;   // all 4 waves write identical values (benign)
    asm volatile("s_waitcnt lgkmcnt(0)" ::: "memory");
    __builtin_amdgcn_s_barrier();

    // S5: Y = Yg@S^T, O = Q@S^T (consumes qfr/yfr prefetched last chunk)
    f32x4 Yacc[2], Oacc[2];
#pragma unroll
    for (int cc = 0; cc < 2; cc++) { Yacc[cc] = (f32x4){0.f,0.f,0.f,0.f}; Oacc[cc] = (f32x4){0.f,0.f,0.f,0.f}; }
#pragma unroll
    for (int cc = 0; cc < 2; cc++) {
      short8 Bs[8];
#pragma unroll
      for (int kf = 0; kf < 8; kf++)
        Bs[kf] = *(const short8*)&ST[(size_t)(16 * cc + lm) * SP2 + 8 * quad + 32 * kf];
#pragma unroll
      for (int kf = 0; kf < 8; kf++) {
        Yacc[cc] = __builtin_amdgcn_mfma_f32_16x16x32_bf16(yfr[kf], Bs[kf], Yacc[cc], 0, 0, 0);
        Oacc[cc] = __builtin_amdgcn_mfma_f32_16x16x32_bf16(qfr[kf], Bs[kf], Oacc[cc], 0, 0, 0);
      }
    }
    __builtin_amdgcn_sched_barrier(0);

    // ISSUE block for chunk c+1: Ks'/Ws' (gload_lds) then q/Y/gsc reg refill
    {
      int cn = (c + 1) & 31;           // c=31 wraps: valid addresses, unused
      size_t cbn = (size_t)bh * 32 + cn;
      const bf16* slab = kTb + (size_t)cn * 16384;
#pragma unroll
      for (int i = 0; i < 8; i++)
        gload16(slab + i * 2048 + tid * 8, Ksn + i * 2048 + wave * 512);
      gload16(WgB + (size_t)cn * 32768, Wsn + tid * 8);
      __builtin_amdgcn_sched_barrier(0);
      gnn = gsc[cbn * 64 + lane];
      const bf16* qrow = qb + (size_t)(cn * 64 + 16 * rt + lm) * KDIM_;
      const bf16* yrow = Yg + cbn * 16384 + (size_t)(16 * rt + lm) * 256;
#pragma unroll
      for (int kf = 0; kf < 8; kf++) {
        qfr[kf] = *(const short8*)(qrow + 8 * quad + 32 * kf);
        yfr[kf] = *(const short8*)(yrow + 8 * quad + 32 * kf);
      }
    }
    __builtin_amdgcn_sched_barrier(0);

    // S7: tie pfn (loaded last chunk AFTER Ks[idx]/Ws[idx] -> wait covers both,
    // with a full chunk of issue-to-use distance); delta = W - Y@S; dT/dTe.
    asm volatile("" : : "v"(*(const int*)&pfn[0]), "v"(*(const int*)&pfn[1]) : "memory");
    __builtin_amdgcn_sched_barrier(0);
    float g63 = Gc[63];
    float lamv[4], erv[4];
#pragma unroll
    for (int rr = 0; rr < 4; rr++) {
      float gr = Gc[16 * rt + 4 * quad + rr];
      lamv[rr] = __expf(gr);
      erv[rr]  = __expf(g63 - gr);
    }
#pragma unroll
    for (int cc = 0; cc < 2; cc++) {
      short4v dpack, depack;
#pragma unroll
      for (int rr = 0; rr < 4; rr++) {
        int row = 16 * rt + 4 * quad + rr;
        float dv = bf2f(Wsb[row * 32 + 16 * cc + lm]) - Yacc[cc][rr];
        Oacc[cc][rr] *= lamv[rr];
        dpack[rr]  = (short)f2bf(dv);
        depack[rr] = (short)f2bf(dv * erv[rr]);
      }
      *(short4v*)&dT [(size_t)(16 * cc + lm) * SD + 16 * rt + 4 * quad] = dpack;
      *(short4v*)&dTe[(size_t)(16 * cc + lm) * SD + 16 * rt + 4 * quad] = depack;
    }
    asm volatile("s_waitcnt lgkmcnt(0)" ::: "memory");
    __builtin_amdgcn_s_barrier();

    // S9 (critical path first): S <- lend*S + K^T @ (e*delta)
    float lend = __expf(g63);
    short8 Be[2][2];
#pragma unroll
    for (int cc = 0; cc < 2; cc++)
#pragma unroll
      for (int kf = 0; kf < 2; kf++)
        Be[cc][kf] = ld76(&dTe[(size_t)(16 * cc + lm) * SD + 8 * quad + 32 * kf]);
#pragma unroll
    for (int dd = 0; dd < 4; dd++) {
      int Dt = 4 * wave + dd;
#pragma unroll
      for (int cc = 0; cc < 2; cc++) {
        f32x4 s = Sacc[dd][cc];
        s[0] *= lend; s[1] *= lend; s[2] *= lend; s[3] *= lend;
#pragma unroll
        for (int kf = 0; kf < 2; kf++) {
          short8 ka = *(const short8*)&Ksb[((size_t)(quad + 4 * kf) * 256 + 16 * Dt + lm) * 8];
          s = __builtin_amdgcn_mfma_f32_16x16x32_bf16(ka, Be[cc][kf], s, 0, 0, 0);
        }
        Sacc[dd][cc] = s;
      }
    }

    // S8: O += P@delta (consumes pfn), store O
#pragma unroll
    for (int cc = 0; cc < 2; cc++) {
#pragma unroll
      for (int kf = 0; kf < 2; kf++) {
        short8 bd = ld76(&dT[(size_t)(16 * cc + lm) * SD + 8 * quad + 32 * kf]);
        Oacc[cc] = __builtin_amdgcn_mfma_f32_16x16x32_bf16(pfn[kf], bd, Oacc[cc], 0, 0, 0);
      }
#pragma unroll
      for (int rr = 0; rr < 4; rr++) {
        int row = 16 * rt + 4 * quad + rr;
        ob[(size_t)(r0 + row) * VDIM_ + 16 * cc + lm] = f2bf(Oacc[cc][rr]);
      }
    }
    __builtin_amdgcn_sched_barrier(0);

    // refill pfn for chunk c+1 (after consumption; after Ks'/Ws' in issue order)
    {
      int cn = (c + 1) & 31;
      const bf16* pc = PgB + (size_t)cn * 4096;
      pfn[0] = *(const short8*)(pc);
      pfn[1] = *(const short8*)(pc + 32);
    }
    gnext = gnn;
    asm volatile("s_waitcnt lgkmcnt(0)" ::: "memory");
    __builtin_amdgcn_s_barrier();      // protect ST/dT/dTe overwrite next iter
  }
}

// ---------------- gated RMSNorm (in place, bf16) ----------------

__global__ __launch_bounds__(256) void gated_rms_kernel(bf16* __restrict__ o,
                                                        const bf16* __restrict__ gate,
                                                        const float* __restrict__ onw) {
  __shared__ float red[4];
  int blk = blockIdx.x;
  int h = blk & 3;
  int bt = blk >> 2;
  size_t base = (size_t)bt * VDIM_ + h * DV_;
  int tid = threadIdx.x;
  float o1 = bf2f(o[base + tid]), o2 = bf2f(o[base + tid + 256]);
  float ss = block_sum256(o1 * o1 + o2 * o2, red);
  float s = rsqrtf(ss * (1.f / DV_) + 1e-5f);
  float g1 = bf2f(gate[base + tid]), g2 = bf2f(gate[base + tid + 256]);
  o[base + tid]       = f2bf(o1 * s * onw[tid] * siluf_(g1));
  o[base + tid + 256] = f2bf(o2 * s * onw[tid + 256] * siluf_(g2));
}

// ---------------- launch ----------------

extern "C" void kernel_launch(void* const* d_in, const int* in_sizes, int n_in,
                              void* d_out, int out_size, void* d_ws, size_t ws_size,
                              hipStream_t stream) {
  const float* x        = (const float*)d_in[0];
  const float* Wq       = (const float*)d_in[1];
  const float* Wk       = (const float*)d_in[2];
  const float* Wv       = (const float*)d_in[3];
  const float* Wa       = (const float*)d_in[4];
  const float* Wb       = (const float*)d_in[5];
  const float* Wg       = (const float*)d_in[6];
  const float* conv_q_w = (const float*)d_in[7];
  const float* conv_k_w = (const float*)d_in[8];
  const float* conv_v_w = (const float*)d_in[9];
  const float* A_log    = (const float*)d_in[10];
  const float* dt_bias  = (const float*)d_in[11];
  const float* o_norm_w = (const float*)d_in[12];
  const float* Wo       = (const float*)d_in[13];
  const float* ln1_w    = (const float*)d_in[14];
  const float* ln1_b    = (const float*)d_in[15];
  const float* ln2_w    = (const float*)d_in[16];
  const float* ln2_b    = (const float*)d_in[17];
  const float* ffn_w1   = (const float*)d_in[18];
  const float* ffn_b1   = (const float*)d_in[19];
  const float* ffn_w2   = (const float*)d_in[20];
  const float* ffn_b2   = (const float*)d_in[21];

  size_t required = (size_t)218 << 20;
  if (ws_size < required) {
    sentinel_kernel<<<(out_size + 255) / 256, 256, 0, stream>>>((float*)d_out, out_size);
    return;
  }

  char* base = (char*)d_ws;
  float* pre    = (float*)(base);                        // 64MB scratch (proj outs)
  bf16*  normed = (bf16*)(base + ((size_t)64  << 20));   // 16MB
  bf16*  q16    = (bf16*)(base + ((size_t)80  << 20));   // 16MB
  bf16*  k16    = (bf16*)(base + ((size_t)96  << 20));   // 16MB
  bf16*  v16    = (bf16*)(base + ((size_t)112 << 20));   // 32MB
  bf16*  g16    = (bf16*)(base + ((size_t)144 << 20));   // 32MB
  bf16*  o16    = (bf16*)(base + ((size_t)176 << 20));   // 32MB
  bf16*  wslot  = (bf16*)(base + ((size_t)208 << 20));   // 8MB JIT weight slot
  float* gvec   = (float*)(base + ((size_t)216 << 20));  // 128KB
  float* bvec   = gvec + (size_t)BT_ * H_;               // 128KB
  float* gsc    = (float*)(base + ((size_t)217 << 20));  // 128KB
  // delta-phase buffers (pre region + normed region, dead after ab_kernel):
  bf16*  Yg     = (bf16*)(base);                         // 16MB  [0,16)
  bf16*  Wgb    = (bf16*)(base + ((size_t)16 << 20));    // 32MB  [16,48)
  bf16*  Pg     = (bf16*)(base + ((size_t)48 << 20));    // 4MB   [48,52)
  bf16*  kTg    = (bf16*)(base + ((size_t)52 << 20));    // 16MB  [52,68)
  // later reuses:
  float* x2     = (float*)(base);                        // 32MB (after delta)
  bf16*  hb16   = (bf16*)(base + ((size_t)64  << 20));
  bf16*  ffn1   = (bf16*)(base + ((size_t)80  << 20));

  // 1) LN1 -> bf16
  ln_kernel<<<BT_, 256, 0, stream>>>(x, ln1_w, ln1_b, normed);

  // 2) projections + convs
  convT_kernel<<<dim3(KDIM_ / 32, D_ / 32), 256, 0, stream>>>(Wq, wslot, D_, KDIM_);
  gemm_mfma<float><<<dim3(KDIM_ / 128, BT_ / 128), 256, 0, stream>>>(normed, wslot, nullptr, nullptr, pre, KDIM_, D_, 0);
  conv_qk_kernel<<<BT_ * H_, 256, 0, stream>>>(pre, conv_q_w, q16, 0.0625f);

  convT_kernel<<<dim3(KDIM_ / 32, D_ / 32), 256, 0, stream>>>(Wk, wslot, D_, KDIM_);
  gemm_mfma<float><<<dim3(KDIM_ / 128, BT_ / 128), 256, 0, stream>>>(normed, wslot, nullptr, nullptr, pre, KDIM_, D_, 0);
  conv_qk_kernel<<<BT_ * H_, 256, 0, stream>>>(pre, conv_k_w, k16, 1.0f);

  convT_kernel<<<dim3(VDIM_ / 32, D_ / 32), 256, 0, stream>>>(Wv, wslot, D_, VDIM_);
  gemm_mfma<float><<<dim3(VDIM_ / 128, BT_ / 128), 256, 0, stream>>>(normed, wslot, nullptr, nullptr, pre, VDIM_, D_, 0);
  conv_v_kernel<<<(BT_ * VDIM_) / 256, 256, 0, stream>>>(pre, conv_v_w, v16);

  convT_kernel<<<dim3(VDIM_ / 32, D_ / 32), 256, 0, stream>>>(Wg, wslot, D_, VDIM_);
  gemm_mfma<bf16><<<dim3(VDIM_ / 128, BT_ / 128), 256, 0, stream>>>(normed, wslot, nullptr, nullptr, g16, VDIM_, D_, 0);

  ab_kernel<<<BT_, 256, 0, stream>>>(normed, Wa, Wb, A_log, dt_bias, gvec, bvec);

  // 3) delta rule: kT transpose (chunk-major) + phase 1 + pipelined phase 2
  kT_kernel<<<dim3(T_ / 32, DK_ / 32, 16), 256, 0, stream>>>(k16, kTg);
  delta_p1<<<512, 256, 0, stream>>>(q16, k16, v16, gvec, bvec, Pg, Wgb, Yg, gsc);
  delta_p2<<<256, 256, 0, stream>>>(q16, kTg, Wgb, Yg, Pg, gsc, o16);

  // 4) gated RMSNorm (in place)
  gated_rms_kernel<<<BT_ * H_, 256, 0, stream>>>(o16, g16, o_norm_w);

  // 5) x2 = x + o @ Wo
  convT_kernel<<<dim3(D_ / 32, VDIM_ / 32), 256, 0, stream>>>(Wo, wslot, VDIM_, D_);
  gemm_mfma<float><<<dim3(D_ / 128, BT_ / 128), 256, 0, stream>>>(o16, wslot, nullptr, x, x2, D_, VDIM_, 4);

  // 6) LN2 -> bf16
  ln_kernel<<<BT_, 256, 0, stream>>>(x2, ln2_w, ln2_b, hb16);

  // 7) FFN
  convT_kernel<<<dim3(FFN_ / 32, D_ / 32), 256, 0, stream>>>(ffn_w1, wslot, D_, FFN_);
  gemm_mfma<bf16><<<dim3(FFN_ / 128, BT_ / 128), 256, 0, stream>>>(hb16, wslot, ffn_b1, nullptr, ffn1, FFN_, D_, 1 | 2);
  convT_kernel<<<dim3(D_ / 32, FFN_ / 32), 256, 0, stream>>>(ffn_w2, wslot, FFN_, D_);
  gemm_mfma<float><<<dim3(D_ / 128, BT_ / 128), 256, 0, stream>>>(ffn1, wslot, ffn_b2, x2, (float*)d_out, D_, FFN_, 1 | 4);
}

// Round 6
// 1100.653 us; speedup vs baseline: 1.1500x; 1.0703x over previous
//
#include <hip/hip_runtime.h>
#include <math.h>

#define B_    4
#define T_    2048
#define D_    1024
#define H_    4
#define DK_   256
#define DV_   512
#define KDIM_ 1024
#define VDIM_ 2048
#define FFN_  4096
#define BT_   8192   // B_*T_

typedef unsigned short bf16;
typedef __attribute__((ext_vector_type(8))) short short8;   // MFMA A/B frag (8 bf16)
typedef __attribute__((ext_vector_type(4))) short short4v;  // 4 bf16
typedef __attribute__((ext_vector_type(4))) float f32x4;    // MFMA C/D frag

// ---------------- helpers ----------------

__device__ __forceinline__ float sigmoidf_(float x) { return 1.f / (1.f + expf(-x)); }
__device__ __forceinline__ float siluf_(float x)    { return x / (1.f + expf(-x)); }
__device__ __forceinline__ float geluf_(float x)    { return 0.5f * x * (1.f + erff(x * 0.70710678118654752f)); }

__device__ __forceinline__ float bf2f(bf16 u) {
  union { unsigned int i; float f; } c; c.i = (unsigned int)u << 16; return c.f;
}
__device__ __forceinline__ bf16 f2bf(float f) {
  union { unsigned int i; float f; } c; c.f = f;
  unsigned int r = c.i + 0x7fffu + ((c.i >> 16) & 1u);   // RNE
  return (bf16)(r >> 16);
}

// async global->LDS, 16B per lane
__device__ __forceinline__ void gload16(const bf16* g, bf16* l) {
  __builtin_amdgcn_global_load_lds((__attribute__((address_space(1))) const void*)g,
                                   (__attribute__((address_space(3))) void*)l, 16, 0, 0);
}

__device__ __forceinline__ void storeC(float* p, float v) { *p = v; }
__device__ __forceinline__ void storeC(bf16* p, float v)  { *p = f2bf(v); }

// load 8 bf16 from an 8B-aligned LDS address as two b64s
__device__ __forceinline__ short8 ld76(const bf16* p) {
  union { short8 v; short4v h[2]; } u;
  u.h[0] = *(const short4v*)p;
  u.h[1] = *(const short4v*)(p + 4);
  return u.v;
}
// pack f32x4 -> 4 bf16, 8B store
__device__ __forceinline__ void st4bf(bf16* p, f32x4 v) {
  short4v o;
  o[0] = (short)f2bf(v[0]); o[1] = (short)f2bf(v[1]);
  o[2] = (short)f2bf(v[2]); o[3] = (short)f2bf(v[3]);
  *(short4v*)p = o;
}

__device__ __forceinline__ float block_sum256(float v, float* red) {
#pragma unroll
  for (int off = 32; off; off >>= 1) v += __shfl_xor(v, off, 64);
  __syncthreads();
  if ((threadIdx.x & 63) == 0) red[threadIdx.x >> 6] = v;
  __syncthreads();
  return red[0] + red[1] + red[2] + red[3];
}

// ---------------- diagnostic sentinel (ws too small) ----------------

__global__ __launch_bounds__(256) void sentinel_kernel(float* out, int n) {
  int i = blockIdx.x * 256 + threadIdx.x;
  if (i < n) out[i] = 12345.0f;
}

// ---------------- LayerNorm -> bf16 ----------------

__global__ __launch_bounds__(256) void ln_kernel(const float* __restrict__ x,
                                                 const float* __restrict__ w,
                                                 const float* __restrict__ b,
                                                 bf16* __restrict__ y) {
  __shared__ float red[4];
  int row = blockIdx.x;
  const float* xr = x + (size_t)row * D_;
  float xv[4];
  float s = 0.f;
#pragma unroll
  for (int i = 0; i < 4; i++) { xv[i] = xr[threadIdx.x + 256 * i]; s += xv[i]; }
  float mean = block_sum256(s, red) * (1.f / D_);
  float s2 = 0.f;
#pragma unroll
  for (int i = 0; i < 4; i++) { float d = xv[i] - mean; s2 += d * d; }
  float var = block_sum256(s2, red) * (1.f / D_);
  float inv = rsqrtf(var + 1e-5f);
  bf16* yr = y + (size_t)row * D_;
#pragma unroll
  for (int i = 0; i < 4; i++) {
    int c = threadIdx.x + 256 * i;
    yr[c] = f2bf((xv[i] - mean) * inv * w[c] + b[c]);
  }
}

// ---------------- weight convert+transpose: fp32 [K][N] -> bf16 [N][K] ----------------

__global__ __launch_bounds__(256) void convT_kernel(const float* __restrict__ src,
                                                    bf16* __restrict__ dst,
                                                    int K, int N) {
  __shared__ float t[32][33];
  int n0 = blockIdx.x * 32, k0 = blockIdx.y * 32;
  int tx = threadIdx.x & 31, ty = threadIdx.x >> 5;
#pragma unroll
  for (int i = 0; i < 4; i++)
    t[ty + i * 8][tx] = src[(size_t)(k0 + ty + i * 8) * N + n0 + tx];
  __syncthreads();
#pragma unroll
  for (int i = 0; i < 4; i++)
    dst[(size_t)(n0 + ty + i * 8) * K + k0 + tx] = f2bf(t[tx][ty + i * 8]);
}

// ---- k transpose per head, CHUNK-MAJOR: k16 [b][t][h*DK+dk] ->
// kTc [bh][c=t>>6][tb=(t>>3)&7][dk][te=t&7]  (contiguous 32KB per chunk,
// exactly the LDS layout delta_p2 consumes -> fully coalesced gload_lds)

__global__ __launch_bounds__(256) void kT_kernel(const bf16* __restrict__ k16,
                                                 bf16* __restrict__ kT) {
  __shared__ bf16 tile[32][34];
  int t0 = blockIdx.x * 32;
  int d0 = blockIdx.y * 32;
  int bh = blockIdx.z;
  int b = bh >> 2, h = bh & 3;
  int tx = threadIdx.x & 31, ty = threadIdx.x >> 5;
#pragma unroll
  for (int i = 0; i < 4; i++)
    tile[ty + 8 * i][tx] = k16[(size_t)(b * T_ + t0 + ty + 8 * i) * KDIM_ + h * DK_ + d0 + tx];
  __syncthreads();
  int t = t0 + tx;
  int c = t >> 6, tb = (t >> 3) & 7, te = t & 7;
  size_t base = ((size_t)(bh * 32 + c) * 8 + tb) * 2048 + te;
#pragma unroll
  for (int i = 0; i < 4; i++)
    kT[base + (size_t)(d0 + ty + 8 * i) * 8] = tile[tx][ty + 8 * i];
}

// ---------------- bf16 MFMA GEMM (unchanged) ----------------

template <typename TC>
__global__ __launch_bounds__(256) void gemm_mfma(const bf16* __restrict__ A,
                                                 const bf16* __restrict__ Bt,
                                                 const float* __restrict__ bias,
                                                 const float* __restrict__ res,
                                                 TC* __restrict__ C,
                                                 int N, int K, int flags) {
  __shared__ __align__(16) bf16 As[128 * 32];
  __shared__ __align__(16) bf16 Bs[128 * 32];
  int tid = threadIdx.x;
  int wave = tid >> 6, lane = tid & 63;
  int bm = blockIdx.y * 128, bn = blockIdx.x * 128;
  int wm = (wave >> 1) * 64, wn = (wave & 1) * 64;
  int lm = lane & 15;
  int quad = lane >> 4;

  f32x4 acc[4][4];
#pragma unroll
  for (int i = 0; i < 4; i++)
#pragma unroll
    for (int j = 0; j < 4; j++) acc[i][j] = (f32x4){0.f, 0.f, 0.f, 0.f};

  int srow = wave * 32 + (lane >> 2);
  int scol = (lane & 3) * 8;
  const bf16* ag = A  + (size_t)(bm + srow) * K + scol;
  const bf16* bg = Bt + (size_t)(bn + srow) * K + scol;
  bf16* al = As + wave * 32 * 32;
  bf16* bl = Bs + wave * 32 * 32;
  const size_t gstep = (size_t)16 * K;

  for (int k0 = 0; k0 < K; k0 += 32) {
    gload16(ag + k0,         al);
    gload16(ag + k0 + gstep, al + 16 * 32);
    gload16(bg + k0,         bl);
    gload16(bg + k0 + gstep, bl + 16 * 32);
    __syncthreads();

    short8 af[4], bf[4];
#pragma unroll
    for (int i = 0; i < 4; i++)
      af[i] = *(const short8*)&As[(wm + i * 16 + lm) * 32 + quad * 8];
#pragma unroll
    for (int j = 0; j < 4; j++)
      bf[j] = *(const short8*)&Bs[(wn + j * 16 + lm) * 32 + quad * 8];
#pragma unroll
    for (int i = 0; i < 4; i++)
#pragma unroll
      for (int j = 0; j < 4; j++)
        acc[i][j] = __builtin_amdgcn_mfma_f32_16x16x32_bf16(af[i], bf[j], acc[i][j], 0, 0, 0);
    __syncthreads();
  }

#pragma unroll
  for (int i = 0; i < 4; i++) {
    int row0 = bm + wm + i * 16 + quad * 4;
#pragma unroll
    for (int j = 0; j < 4; j++) {
      int col = bn + wn + j * 16 + lm;
      float badd = (flags & 1) ? bias[col] : 0.f;
#pragma unroll
      for (int r = 0; r < 4; r++) {
        float v = acc[i][j][r] + badd;
        if (flags & 2) v = geluf_(v);
        if (flags & 4) v += res[(size_t)(row0 + r) * N + col];
        storeC(&C[(size_t)(row0 + r) * N + col], v);
      }
    }
  }
}

// ---------------- fused Wa/Wb projections -> g, beta ----------------

__global__ __launch_bounds__(256) void ab_kernel(const bf16* __restrict__ normed,
                                                 const float* __restrict__ Wa,
                                                 const float* __restrict__ Wb,
                                                 const float* __restrict__ A_log,
                                                 const float* __restrict__ dt_bias,
                                                 float* __restrict__ g,
                                                 float* __restrict__ beta) {
  __shared__ float red[4];
  int row = blockIdx.x;
  const bf16* xr = normed + (size_t)row * D_;
  float aacc[4] = {}, bacc[4] = {};
#pragma unroll
  for (int i = 0; i < 4; i++) {
    int d = threadIdx.x + 256 * i;
    float xv = bf2f(xr[d]);
    float4 wa = *(const float4*)&Wa[d * 4];
    float4 wb = *(const float4*)&Wb[d * 4];
    aacc[0] += xv * wa.x; aacc[1] += xv * wa.y; aacc[2] += xv * wa.z; aacc[3] += xv * wa.w;
    bacc[0] += xv * wb.x; bacc[1] += xv * wb.y; bacc[2] += xv * wb.z; bacc[3] += xv * wb.w;
  }
  float sa[4], sb[4];
#pragma unroll
  for (int h = 0; h < 4; h++) {
    sa[h] = block_sum256(aacc[h], red);
    sb[h] = block_sum256(bacc[h], red);
  }
  if (threadIdx.x < 4) {
    int h = threadIdx.x;
    float xa = sa[h] + dt_bias[h];
    float sp = (xa > 20.f) ? xa : log1pf(expf(xa));
    g[row * 4 + h] = -expf(A_log[h]) * sp;
    beta[row * 4 + h] = sigmoidf_(sb[h]);
  }
}

// ---------------- causal conv(4) + SiLU (+ L2 norm for q/k) ----------------

__global__ __launch_bounds__(256) void conv_qk_kernel(const float* __restrict__ pre,
                                                      const float* __restrict__ convw,
                                                      bf16* __restrict__ out,
                                                      float scale) {
  __shared__ float red[4];
  int blk = blockIdx.x;
  int h = blk & 3;
  int bt = blk >> 2;
  int t = bt & (T_ - 1);
  int c = h * DK_ + threadIdx.x;
  float y = 0.f;
#pragma unroll
  for (int i = 0; i < 4; i++) {
    int tt = t + i - 3;
    if (tt >= 0) y += pre[(size_t)(bt + i - 3) * KDIM_ + c] * convw[c * 4 + i];
  }
  y = siluf_(y);
  float ss = block_sum256(y * y, red);
  y *= rsqrtf(ss + 1e-6f) * scale;
  out[(size_t)bt * KDIM_ + c] = f2bf(y);
}

__global__ __launch_bounds__(256) void conv_v_kernel(const float* __restrict__ pre,
                                                     const float* __restrict__ convw,
                                                     bf16* __restrict__ out) {
  int idx = blockIdx.x * 256 + threadIdx.x;
  int c = idx & (VDIM_ - 1);
  int bt = idx >> 11;
  int t = bt & (T_ - 1);
  float y = 0.f;
#pragma unroll
  for (int i = 0; i < 4; i++) {
    int tt = t + i - 3;
    if (tt >= 0) y += pre[(size_t)(bt + i - 3) * VDIM_ + c] * convw[c * 4 + i];
  }
  out[idx] = f2bf(siluf_(y));
}

// ---------------- delta rule phase 1 (parallel over bh x chunk) ----------------
// R6: the 48 serial triangular solves (12 groups x 4 blocks, 3/4 waves idle,
// ~120-deep shfl chains each) are replaced by ONE solve with RHS = I giving
// Minv = (I+A)^{-1} (4 serial sections total), after which each group is a
// pure 64x64x64 MFMA GEMM X = Minv @ U stored straight from registers.

#define SP  76
#define UBP 72
#define MTP 68

__global__ __launch_bounds__(256, 2) void delta_p1(const bf16* __restrict__ q,
                                                   const bf16* __restrict__ k,
                                                   const bf16* __restrict__ v,
                                                   const float* __restrict__ g,
                                                   const float* __restrict__ beta,
                                                   bf16* __restrict__ Pg,
                                                   bf16* __restrict__ Wg,
                                                   bf16* __restrict__ Yg,
                                                   float* __restrict__ gsc) {
  __shared__ bf16 Abf[64 * SP];
  __shared__ bf16 DTg[64 * SP];                 // Minv col-major [col][row] (solve)
  __shared__ __align__(8) bf16 MT[64 * MTP];    // Minv row-major [row][col]
  __shared__ __align__(8) bf16 Ubt[64 * UBP];   // U^T per group [col][t]
  __shared__ float UbJ[16 * 64];                // current block-row RHS (f32)
  __shared__ float Gc[64], Lm[64], Bt[64];

  int blk = blockIdx.x;
  int c = blk & 31, bh = blk >> 5;
  int b = bh >> 2, h = bh & 3;
  int tid = threadIdx.x;
  int wave = tid >> 6, lane = tid & 63;
  int lm = lane & 15, quad = lane >> 4;
  int r0 = c * 64;

  const bf16* kb = k + (size_t)b * T_ * KDIM_ + h * DK_;
  const bf16* qb = q + (size_t)b * T_ * KDIM_ + h * DK_;
  const bf16* vb = v + (size_t)b * T_ * VDIM_ + h * DV_;
  const float* gbp = g    + (size_t)b * T_ * H_ + h;
  const float* bbp = beta + (size_t)b * T_ * H_ + h;
  size_t cb = (size_t)bh * 32 + c;
  bf16* PgC = Pg + cb * 4096;
  bf16* WgC = Wg + cb * 64 * 512;
  bf16* YgC = Yg + cb * 64 * 256;

  // (a) cumsum of g -> Gc, Lam, beta
  if (wave == 0) {
    float gv = gbp[(size_t)(r0 + lane) * H_];
    float bv = bbp[(size_t)(r0 + lane) * H_];
#pragma unroll
    for (int d = 1; d < 64; d <<= 1) {
      float nn = __shfl_up(gv, (unsigned)d, 64);
      if (lane >= d) gv += nn;
    }
    Gc[lane] = gv; Lm[lane] = expf(gv); Bt[lane] = bv;
    gsc[cb * 64 + lane] = gv;
  }
  // zero DTg while wave0 does cumsum
  {
    int* dz = (int*)DTg;
#pragma unroll
    for (int i = 0; i < 10; i++) {
      int idx = tid + 256 * i;
      if (idx < 64 * SP / 2) dz[idx] = 0;
    }
  }
  __syncthreads();

  // (b,c) KK^T -> Abf, QK^T -> Pg
  {
    f32x4 akk[4], aqk[4];
#pragma unroll
    for (int j = 0; j < 4; j++) { akk[j] = (f32x4){0.f,0.f,0.f,0.f}; aqk[j] = (f32x4){0.f,0.f,0.f,0.f}; }
    const bf16* krow = kb + (size_t)(r0 + 16 * wave + lm) * KDIM_;
    const bf16* qrow = qb + (size_t)(r0 + 16 * wave + lm) * KDIM_;
#pragma unroll
    for (int ks = 0; ks < 8; ks++) {
      short8 ak = *(const short8*)(krow + 8 * quad + 32 * ks);
      short8 aq = *(const short8*)(qrow + 8 * quad + 32 * ks);
#pragma unroll
      for (int j = 0; j < 4; j++) {
        short8 bk = *(const short8*)(kb + (size_t)(r0 + 16 * j + lm) * KDIM_ + 8 * quad + 32 * ks);
        akk[j] = __builtin_amdgcn_mfma_f32_16x16x32_bf16(ak, bk, akk[j], 0, 0, 0);
        aqk[j] = __builtin_amdgcn_mfma_f32_16x16x32_bf16(aq, bk, aqk[j], 0, 0, 0);
      }
    }
    float gi[4], bi[4];
#pragma unroll
    for (int r = 0; r < 4; r++) {
      int i = 16 * wave + 4 * quad + r;
      gi[r] = Gc[i]; bi[r] = Bt[i];
    }
#pragma unroll
    for (int j = 0; j < 4; j++) {
      int s = 16 * j + lm;
      float gs = Gc[s];
#pragma unroll
      for (int r = 0; r < 4; r++) {
        int i = 16 * wave + 4 * quad + r;
        float dec = expf(gi[r] - gs);
        Abf[(size_t)i * SP + s] = f2bf((s < i)  ? bi[r] * dec * akk[j][r] : 0.f);
        PgC[(size_t)i * 64 + s] = f2bf((s <= i) ? dec * aqk[j][r]        : 0.f);
      }
    }
  }
  __syncthreads();   // Abf + DTg(zero) ready

  // ---- Phase B: Minv = (I+A)^{-1}  (ONE forward-substitution pass, RHS=I) ----
#pragma unroll 1
  for (int j = 0; j < 4; j++) {
    // init UbJ = I block-row slice
#pragma unroll
    for (int i = 0; i < 4; i++) {
      int idx = tid + 256 * i;          // 1024 entries
      int row = idx >> 6, col = idx & 63;
      UbJ[row * 64 + col] = (col == 16 * j + row) ? 1.f : 0.f;
    }
    __syncthreads();
    if (j > 0) {
      f32x4 racc = (f32x4){0.f, 0.f, 0.f, 0.f};
      int nk = (j == 3) ? 2 : 1;
      for (int ks = 0; ks < nk; ks++) {
        short8 aa = ld76(&Abf[(size_t)(16 * j + lm) * SP + 8 * quad + 32 * ks]);
        short8 bd = ld76(&DTg[(size_t)(16 * wave + lm) * SP + 8 * quad + 32 * ks]);
        racc = __builtin_amdgcn_mfma_f32_16x16x32_bf16(aa, bd, racc, 0, 0, 0);
      }
#pragma unroll
      for (int r = 0; r < 4; r++)
        UbJ[(4 * quad + r) * 64 + 16 * wave + lm] -= racc[r];
      __syncthreads();
    }
    if (wave == 0) {
      int tl = lane & 15, sg = lane >> 4;
      short4v ab4 = *(const short4v*)&Abf[(size_t)(16 * j + tl) * SP + 16 * j + 4 * sg];
      float av[4];
      av[0] = bf2f((bf16)ab4[0]); av[1] = bf2f((bf16)ab4[1]);
      av[2] = bf2f((bf16)ab4[2]); av[3] = bf2f((bf16)ab4[3]);
      float d[16];
#pragma unroll
      for (int t = 0; t < 16; t++) {
        float val = UbJ[t * 64 + lane];
#pragma unroll
        for (int s = 0; s < t; s++) {
          float ats = __shfl(av[s & 3], t + 16 * (s >> 2), 64);
          val -= ats * d[s];
        }
        d[t] = val;
        bf16 vb16 = f2bf(val);
        DTg[(size_t)lane * SP + 16 * j + t] = vb16;   // col-major (solve B-reads)
        MT [(size_t)(16 * j + t) * MTP + lane] = vb16; // row-major (group GEMMs)
      }
    }
    __syncthreads();
  }

  // ---- Phase C: 12 group GEMMs  X = Minv @ U, stored straight to Wg/Yg ----
  // grp 0..7 -> W (RHS beta*V), grp 8..11 -> Y (RHS beta*Lam*K)
  int cg = 16 * wave + lm;
#pragma unroll 1
  for (int grp = 0; grp < 12; grp++) {
    // fill Ubt[cg][t] = U^T (bf16); entry barrier was end of Phase B / prev grp
#pragma unroll
    for (int ti = 0; ti < 4; ti++) {
      short4v up;
#pragma unroll
      for (int r = 0; r < 4; r++) {
        int t = 16 * ti + 4 * quad + r;
        float val;
        if (grp < 8) val = Bt[t] * bf2f(vb[(size_t)(r0 + t) * VDIM_ + grp * 64 + cg]);
        else         val = Bt[t] * Lm[t] * bf2f(kb[(size_t)(r0 + t) * KDIM_ + (grp - 8) * 64 + cg]);
        up[r] = (short)f2bf(val);
      }
      *(short4v*)&Ubt[(size_t)cg * UBP + 16 * ti + 4 * quad] = up;
    }
    asm volatile("s_waitcnt lgkmcnt(0)" ::: "memory");
    __builtin_amdgcn_s_barrier();

    // D[t][c] = sum_s Minv[t][s] * U[s][c];  A = MT rows (t), B = Ubt rows (c)
    f32x4 racc[4];
#pragma unroll
    for (int jt = 0; jt < 4; jt++) racc[jt] = (f32x4){0.f, 0.f, 0.f, 0.f};
#pragma unroll
    for (int ks = 0; ks < 2; ks++) {
      short8 aM = ld76(&MT[(size_t)(16 * wave + lm) * MTP + 8 * quad + 32 * ks]);
#pragma unroll
      for (int jt = 0; jt < 4; jt++) {
        short8 bU = ld76(&Ubt[(size_t)(16 * jt + lm) * UBP + 8 * quad + 32 * ks]);
        racc[jt] = __builtin_amdgcn_mfma_f32_16x16x32_bf16(aM, bU, racc[jt], 0, 0, 0);
      }
    }
    // store: t = 16*wave + 4*quad + rr, c = 16*jt + lm
#pragma unroll
    for (int jt = 0; jt < 4; jt++) {
#pragma unroll
      for (int rr = 0; rr < 4; rr++) {
        int t = 16 * wave + 4 * quad + rr;
        int cc = 16 * jt + lm;
        if (grp < 8) WgC[(size_t)t * 512 + grp * 64 + cc]       = f2bf(racc[jt][rr]);
        else         YgC[(size_t)t * 256 + (grp - 8) * 64 + cc] = f2bf(racc[jt][rr]);
      }
    }
    asm volatile("s_waitcnt lgkmcnt(0)" ::: "memory");
    __builtin_amdgcn_s_barrier();   // protect Ubt overwrite next group
  }
}

// ---------------- delta rule phase 2 (unchanged from R5) ----------------

#define SP2 264
#define SD  72

__global__ __launch_bounds__(256, 1) void delta_p2(const bf16* __restrict__ q,
                                                   const bf16* __restrict__ kT,
                                                   const bf16* __restrict__ Wg,
                                                   const bf16* __restrict__ Yg,
                                                   const bf16* __restrict__ Pg,
                                                   const float* __restrict__ gsc,
                                                   bf16* __restrict__ o) {
  __shared__ __align__(16) bf16 ST[32 * SP2];       // S^T [v][dk] bf16
  __shared__ __align__(16) bf16 dT[32 * SD];        // delta^T [v][t]
  __shared__ __align__(16) bf16 dTe[32 * SD];       // (e*delta)^T [v][t]
  __shared__ float Gc[64];
  __shared__ __align__(16) bf16 Ks[2][8 * 256 * 8]; // kT chunk (dbuf), [tb][dk][te]
  __shared__ __align__(16) bf16 Ws[2][64 * 32];     // W slab [t][32 cols] (dbuf)

  int blk = blockIdx.x;
  int bh = blk & 15, vs = blk >> 4;    // XCD-local: blk%8 == bh%8 for all vs
  int b = bh >> 2, h = bh & 3;
  int tid = threadIdx.x;
  int wave = tid >> 6, lane = tid & 63;
  int lm = lane & 15, quad = lane >> 4;
  int rt = wave;                       // row-tile (t rows 16rt..16rt+15)
  int v0 = vs * 32;

  const bf16* qb  = q  + (size_t)b * T_ * KDIM_ + h * DK_;
  const bf16* kTb = kT + (size_t)bh * 32 * 16384;   // chunk-major base
  const bf16* WgB = Wg + (size_t)bh * 32 * 32768 + (size_t)(tid >> 2) * 512 + v0 + (tid & 3) * 8;
  const bf16* PgB = Pg + (size_t)bh * 32 * 4096 + (size_t)(16 * rt + lm) * 64 + 8 * quad;
  bf16*       ob  = o  + (size_t)b * T_ * VDIM_ + h * DV_ + v0;

  f32x4 Sacc[4][2];                    // dk-tile (4*wave+dd) x v-col-tile cc
#pragma unroll
  for (int dd = 0; dd < 4; dd++)
#pragma unroll
    for (int cc = 0; cc < 2; cc++) Sacc[dd][cc] = (f32x4){0.f, 0.f, 0.f, 0.f};

  // ---- prologue: stage chunk 0 (Ks/Ws async; P/q/Y/gsc regs) ----
#pragma unroll
  for (int i = 0; i < 8; i++)
    gload16(kTb + i * 2048 + tid * 8, Ks[0] + i * 2048 + wave * 512);
  gload16(WgB, Ws[0] + tid * 8);
  __builtin_amdgcn_sched_barrier(0);
  short8 pfn[2];
  pfn[0] = *(const short8*)(PgB);          // issued AFTER Ks[0]/Ws[0]
  pfn[1] = *(const short8*)(PgB + 32);
  __builtin_amdgcn_sched_barrier(0);
  float gnext = gsc[(size_t)bh * 2048 + lane], gnn = 0.f;
  short8 qfr[8], yfr[8];
  {
    const bf16* qrow = qb + (size_t)(16 * rt + lm) * KDIM_;
    const bf16* yrow = Yg + (size_t)bh * 32 * 16384 + (size_t)(16 * rt + lm) * 256;
#pragma unroll
    for (int kf = 0; kf < 8; kf++) {
      qfr[kf] = *(const short8*)(qrow + 8 * quad + 32 * kf);
      yfr[kf] = *(const short8*)(yrow + 8 * quad + 32 * kf);
    }
  }

  for (int c = 0; c < 32; c++) {
    const int r0 = c * 64;
    const int idx = c & 1;
    const bf16* Ksb = Ks[idx];
    const bf16* Wsb = Ws[idx];
    bf16* Ksn = Ks[idx ^ 1];
    bf16* Wsn = Ws[idx ^ 1];

    // S4: stage S^T + Gc; raw barrier (vm prefetches stay in flight)
#pragma unroll
    for (int dd = 0; dd < 4; dd++)
#pragma unroll
      for (int cc = 0; cc < 2; cc++)
        st4bf(&ST[(size_t)(16 * cc + lm) * SP2 + 16 * (4 * wave + dd) + 4 * quad], Sacc[dd][cc]);
    Gc[lane] = gnext;   // all 4 waves write identical values (benign)
    asm volatile("s_waitcnt lgkmcnt(0)" ::: "memory");
    __builtin_amdgcn_s_barrier();

    // S5: Y = Yg@S^T, O = Q@S^T (consumes qfr/yfr prefetched last chunk)
    f32x4 Yacc[2], Oacc[2];
#pragma unroll
    for (int cc = 0; cc < 2; cc++) { Yacc[cc] = (f32x4){0.f,0.f,0.f,0.f}; Oacc[cc] = (f32x4){0.f,0.f,0.f,0.f}; }
#pragma unroll
    for (int cc = 0; cc < 2; cc++) {
      short8 Bs[8];
#pragma unroll
      for (int kf = 0; kf < 8; kf++)
        Bs[kf] = *(const short8*)&ST[(size_t)(16 * cc + lm) * SP2 + 8 * quad + 32 * kf];
#pragma unroll
      for (int kf = 0; kf < 8; kf++) {
        Yacc[cc] = __builtin_amdgcn_mfma_f32_16x16x32_bf16(yfr[kf], Bs[kf], Yacc[cc], 0, 0, 0);
        Oacc[cc] = __builtin_amdgcn_mfma_f32_16x16x32_bf16(qfr[kf], Bs[kf], Oacc[cc], 0, 0, 0);
      }
    }
    __builtin_amdgcn_sched_barrier(0);

    // ISSUE block for chunk c+1: Ks'/Ws' (gload_lds) then q/Y/gsc reg refill
    {
      int cn = (c + 1) & 31;           // c=31 wraps: valid addresses, unused
      size_t cbn = (size_t)bh * 32 + cn;
      const bf16* slab = kTb + (size_t)cn * 16384;
#pragma unroll
      for (int i = 0; i < 8; i++)
        gload16(slab + i * 2048 + tid * 8, Ksn + i * 2048 + wave * 512);
      gload16(WgB + (size_t)cn * 32768, Wsn + tid * 8);
      __builtin_amdgcn_sched_barrier(0);
      gnn = gsc[cbn * 64 + lane];
      const bf16* qrow = qb + (size_t)(cn * 64 + 16 * rt + lm) * KDIM_;
      const bf16* yrow = Yg + cbn * 16384 + (size_t)(16 * rt + lm) * 256;
#pragma unroll
      for (int kf = 0; kf < 8; kf++) {
        qfr[kf] = *(const short8*)(qrow + 8 * quad + 32 * kf);
        yfr[kf] = *(const short8*)(yrow + 8 * quad + 32 * kf);
      }
    }
    __builtin_amdgcn_sched_barrier(0);

    // S7: tie pfn (loaded last chunk AFTER Ks[idx]/Ws[idx] -> wait covers both,
    // with a full chunk of issue-to-use distance); delta = W - Y@S; dT/dTe.
    asm volatile("" : : "v"(*(const int*)&pfn[0]), "v"(*(const int*)&pfn[1]) : "memory");
    __builtin_amdgcn_sched_barrier(0);
    float g63 = Gc[63];
    float lamv[4], erv[4];
#pragma unroll
    for (int rr = 0; rr < 4; rr++) {
      float gr = Gc[16 * rt + 4 * quad + rr];
      lamv[rr] = __expf(gr);
      erv[rr]  = __expf(g63 - gr);
    }
#pragma unroll
    for (int cc = 0; cc < 2; cc++) {
      short4v dpack, depack;
#pragma unroll
      for (int rr = 0; rr < 4; rr++) {
        int row = 16 * rt + 4 * quad + rr;
        float dv = bf2f(Wsb[row * 32 + 16 * cc + lm]) - Yacc[cc][rr];
        Oacc[cc][rr] *= lamv[rr];
        dpack[rr]  = (short)f2bf(dv);
        depack[rr] = (short)f2bf(dv * erv[rr]);
      }
      *(short4v*)&dT [(size_t)(16 * cc + lm) * SD + 16 * rt + 4 * quad] = dpack;
      *(short4v*)&dTe[(size_t)(16 * cc + lm) * SD + 16 * rt + 4 * quad] = depack;
    }
    asm volatile("s_waitcnt lgkmcnt(0)" ::: "memory");
    __builtin_amdgcn_s_barrier();

    // S9 (critical path first): S <- lend*S + K^T @ (e*delta)
    float lend = __expf(g63);
    short8 Be[2][2];
#pragma unroll
    for (int cc = 0; cc < 2; cc++)
#pragma unroll
      for (int kf = 0; kf < 2; kf++)
        Be[cc][kf] = ld76(&dTe[(size_t)(16 * cc + lm) * SD + 8 * quad + 32 * kf]);
#pragma unroll
    for (int dd = 0; dd < 4; dd++) {
      int Dt = 4 * wave + dd;
#pragma unroll
      for (int cc = 0; cc < 2; cc++) {
        f32x4 s = Sacc[dd][cc];
        s[0] *= lend; s[1] *= lend; s[2] *= lend; s[3] *= lend;
#pragma unroll
        for (int kf = 0; kf < 2; kf++) {
          short8 ka = *(const short8*)&Ksb[((size_t)(quad + 4 * kf) * 256 + 16 * Dt + lm) * 8];
          s = __builtin_amdgcn_mfma_f32_16x16x32_bf16(ka, Be[cc][kf], s, 0, 0, 0);
        }
        Sacc[dd][cc] = s;
      }
    }

    // S8: O += P@delta (consumes pfn), store O
#pragma unroll
    for (int cc = 0; cc < 2; cc++) {
#pragma unroll
      for (int kf = 0; kf < 2; kf++) {
        short8 bd = ld76(&dT[(size_t)(16 * cc + lm) * SD + 8 * quad + 32 * kf]);
        Oacc[cc] = __builtin_amdgcn_mfma_f32_16x16x32_bf16(pfn[kf], bd, Oacc[cc], 0, 0, 0);
      }
#pragma unroll
      for (int rr = 0; rr < 4; rr++) {
        int row = 16 * rt + 4 * quad + rr;
        ob[(size_t)(r0 + row) * VDIM_ + 16 * cc + lm] = f2bf(Oacc[cc][rr]);
      }
    }
    __builtin_amdgcn_sched_barrier(0);

    // refill pfn for chunk c+1 (after consumption; after Ks'/Ws' in issue order)
    {
      int cn = (c + 1) & 31;
      const bf16* pc = PgB + (size_t)cn * 4096;
      pfn[0] = *(const short8*)(pc);
      pfn[1] = *(const short8*)(pc + 32);
    }
    gnext = gnn;
    asm volatile("s_waitcnt lgkmcnt(0)" ::: "memory");
    __builtin_amdgcn_s_barrier();      // protect ST/dT/dTe overwrite next iter
  }
}

// ---------------- gated RMSNorm (in place, bf16) ----------------

__global__ __launch_bounds__(256) void gated_rms_kernel(bf16* __restrict__ o,
                                                        const bf16* __restrict__ gate,
                                                        const float* __restrict__ onw) {
  __shared__ float red[4];
  int blk = blockIdx.x;
  int h = blk & 3;
  int bt = blk >> 2;
  size_t base = (size_t)bt * VDIM_ + h * DV_;
  int tid = threadIdx.x;
  float o1 = bf2f(o[base + tid]), o2 = bf2f(o[base + tid + 256]);
  float ss = block_sum256(o1 * o1 + o2 * o2, red);
  float s = rsqrtf(ss * (1.f / DV_) + 1e-5f);
  float g1 = bf2f(gate[base + tid]), g2 = bf2f(gate[base + tid + 256]);
  o[base + tid]       = f2bf(o1 * s * onw[tid] * siluf_(g1));
  o[base + tid + 256] = f2bf(o2 * s * onw[tid + 256] * siluf_(g2));
}

// ---------------- launch ----------------

extern "C" void kernel_launch(void* const* d_in, const int* in_sizes, int n_in,
                              void* d_out, int out_size, void* d_ws, size_t ws_size,
                              hipStream_t stream) {
  const float* x        = (const float*)d_in[0];
  const float* Wq       = (const float*)d_in[1];
  const float* Wk       = (const float*)d_in[2];
  const float* Wv       = (const float*)d_in[3];
  const float* Wa       = (const float*)d_in[4];
  const float* Wb       = (const float*)d_in[5];
  const float* Wg       = (const float*)d_in[6];
  const float* conv_q_w = (const float*)d_in[7];
  const float* conv_k_w = (const float*)d_in[8];
  const float* conv_v_w = (const float*)d_in[9];
  const float* A_log    = (const float*)d_in[10];
  const float* dt_bias  = (const float*)d_in[11];
  const float* o_norm_w = (const float*)d_in[12];
  const float* Wo       = (const float*)d_in[13];
  const float* ln1_w    = (const float*)d_in[14];
  const float* ln1_b    = (const float*)d_in[15];
  const float* ln2_w    = (const float*)d_in[16];
  const float* ln2_b    = (const float*)d_in[17];
  const float* ffn_w1   = (const float*)d_in[18];
  const float* ffn_b1   = (const float*)d_in[19];
  const float* ffn_w2   = (const float*)d_in[20];
  const float* ffn_b2   = (const float*)d_in[21];

  size_t required = (size_t)218 << 20;
  if (ws_size < required) {
    sentinel_kernel<<<(out_size + 255) / 256, 256, 0, stream>>>((float*)d_out, out_size);
    return;
  }

  char* base = (char*)d_ws;
  float* pre    = (float*)(base);                        // 64MB scratch (proj outs)
  bf16*  normed = (bf16*)(base + ((size_t)64  << 20));   // 16MB
  bf16*  q16    = (bf16*)(base + ((size_t)80  << 20));   // 16MB
  bf16*  k16    = (bf16*)(base + ((size_t)96  << 20));   // 16MB
  bf16*  v16    = (bf16*)(base + ((size_t)112 << 20));   // 32MB
  bf16*  g16    = (bf16*)(base + ((size_t)144 << 20));   // 32MB
  bf16*  o16    = (bf16*)(base + ((size_t)176 << 20));   // 32MB
  bf16*  wslot  = (bf16*)(base + ((size_t)208 << 20));   // 8MB JIT weight slot
  float* gvec   = (float*)(base + ((size_t)216 << 20));  // 128KB
  float* bvec   = gvec + (size_t)BT_ * H_;               // 128KB
  float* gsc    = (float*)(base + ((size_t)217 << 20));  // 128KB
  // delta-phase buffers (pre region + normed region, dead after ab_kernel):
  bf16*  Yg     = (bf16*)(base);                         // 16MB  [0,16)
  bf16*  Wgb    = (bf16*)(base + ((size_t)16 << 20));    // 32MB  [16,48)
  bf16*  Pg     = (bf16*)(base + ((size_t)48 << 20));    // 4MB   [48,52)
  bf16*  kTg    = (bf16*)(base + ((size_t)52 << 20));    // 16MB  [52,68)
  // later reuses:
  float* x2     = (float*)(base);                        // 32MB (after delta)
  bf16*  hb16   = (bf16*)(base + ((size_t)64  << 20));
  bf16*  ffn1   = (bf16*)(base + ((size_t)80  << 20));

  // 1) LN1 -> bf16
  ln_kernel<<<BT_, 256, 0, stream>>>(x, ln1_w, ln1_b, normed);

  // 2) projections + convs
  convT_kernel<<<dim3(KDIM_ / 32, D_ / 32), 256, 0, stream>>>(Wq, wslot, D_, KDIM_);
  gemm_mfma<float><<<dim3(KDIM_ / 128, BT_ / 128), 256, 0, stream>>>(normed, wslot, nullptr, nullptr, pre, KDIM_, D_, 0);
  conv_qk_kernel<<<BT_ * H_, 256, 0, stream>>>(pre, conv_q_w, q16, 0.0625f);

  convT_kernel<<<dim3(KDIM_ / 32, D_ / 32), 256, 0, stream>>>(Wk, wslot, D_, KDIM_);
  gemm_mfma<float><<<dim3(KDIM_ / 128, BT_ / 128), 256, 0, stream>>>(normed, wslot, nullptr, nullptr, pre, KDIM_, D_, 0);
  conv_qk_kernel<<<BT_ * H_, 256, 0, stream>>>(pre, conv_k_w, k16, 1.0f);

  convT_kernel<<<dim3(VDIM_ / 32, D_ / 32), 256, 0, stream>>>(Wv, wslot, D_, VDIM_);
  gemm_mfma<float><<<dim3(VDIM_ / 128, BT_ / 128), 256, 0, stream>>>(normed, wslot, nullptr, nullptr, pre, VDIM_, D_, 0);
  conv_v_kernel<<<(BT_ * VDIM_) / 256, 256, 0, stream>>>(pre, conv_v_w, v16);

  convT_kernel<<<dim3(VDIM_ / 32, D_ / 32), 256, 0, stream>>>(Wg, wslot, D_, VDIM_);
  gemm_mfma<bf16><<<dim3(VDIM_ / 128, BT_ / 128), 256, 0, stream>>>(normed, wslot, nullptr, nullptr, g16, VDIM_, D_, 0);

  ab_kernel<<<BT_, 256, 0, stream>>>(normed, Wa, Wb, A_log, dt_bias, gvec, bvec);

  // 3) delta rule: kT transpose (chunk-major) + phase 1 + pipelined phase 2
  kT_kernel<<<dim3(T_ / 32, DK_ / 32, 16), 256, 0, stream>>>(k16, kTg);
  delta_p1<<<512, 256, 0, stream>>>(q16, k16, v16, gvec, bvec, Pg, Wgb, Yg, gsc);
  delta_p2<<<256, 256, 0, stream>>>(q16, kTg, Wgb, Yg, Pg, gsc, o16);

  // 4) gated RMSNorm (in place)
  gated_rms_kernel<<<BT_ * H_, 256, 0, stream>>>(o16, g16, o_norm_w);

  // 5) x2 = x + o @ Wo
  convT_kernel<<<dim3(D_ / 32, VDIM_ / 32), 256, 0, stream>>>(Wo, wslot, VDIM_, D_);
  gemm_mfma<float><<<dim3(D_ / 128, BT_ / 128), 256, 0, stream>>>(o16, wslot, nullptr, x, x2, D_, VDIM_, 4);

  // 6) LN2 -> bf16
  ln_kernel<<<BT_, 256, 0, stream>>>(x2, ln2_w, ln2_b, hb16);

  // 7) FFN
  convT_kernel<<<dim3(FFN_ / 32, D_ / 32), 256, 0, stream>>>(ffn_w1, wslot, D_, FFN_);
  gemm_mfma<bf16><<<dim3(FFN_ / 128, BT_ / 128), 256, 0, stream>>>(hb16, wslot, ffn_b1, nullptr, ffn1, FFN_, D_, 1 | 2);
  convT_kernel<<<dim3(D_ / 32, FFN_ / 32), 256, 0, stream>>>(ffn_w2, wslot, FFN_, D_);
  gemm_mfma<float><<<dim3(D_ / 128, BT_ / 128), 256, 0, stream>>>(ffn1, wslot, ffn_b2, x2, (float*)d_out, D_, FFN_, 1 | 4);
}

// Round 7
// 1049.688 us; speedup vs baseline: 1.2058x; 1.0486x over previous
//
#include <hip/hip_runtime.h>
#include <math.h>

#define B_    4
#define T_    2048
#define D_    1024
#define H_    4
#define DK_   256
#define DV_   512
#define KDIM_ 1024
#define VDIM_ 2048
#define FFN_  4096
#define BT_   8192   // B_*T_

typedef unsigned short bf16;
typedef __attribute__((ext_vector_type(8))) short short8;   // MFMA A/B frag (8 bf16)
typedef __attribute__((ext_vector_type(4))) short short4v;  // 4 bf16
typedef __attribute__((ext_vector_type(4))) float f32x4;    // MFMA C/D frag

// ---------------- helpers ----------------

__device__ __forceinline__ float sigmoidf_(float x) { return 1.f / (1.f + expf(-x)); }
__device__ __forceinline__ float siluf_(float x)    { return x / (1.f + expf(-x)); }
__device__ __forceinline__ float geluf_(float x)    { return 0.5f * x * (1.f + erff(x * 0.70710678118654752f)); }

__device__ __forceinline__ float bf2f(bf16 u) {
  union { unsigned int i; float f; } c; c.i = (unsigned int)u << 16; return c.f;
}
__device__ __forceinline__ bf16 f2bf(float f) {
  union { unsigned int i; float f; } c; c.f = f;
  unsigned int r = c.i + 0x7fffu + ((c.i >> 16) & 1u);   // RNE
  return (bf16)(r >> 16);
}

// async global->LDS, 16B per lane
__device__ __forceinline__ void gload16(const bf16* g, bf16* l) {
  __builtin_amdgcn_global_load_lds((__attribute__((address_space(1))) const void*)g,
                                   (__attribute__((address_space(3))) void*)l, 16, 0, 0);
}

__device__ __forceinline__ void storeC(float* p, float v) { *p = v; }
__device__ __forceinline__ void storeC(bf16* p, float v)  { *p = f2bf(v); }

// load 8 bf16 from an 8B-aligned LDS address as two b64s
__device__ __forceinline__ short8 ld76(const bf16* p) {
  union { short8 v; short4v h[2]; } u;
  u.h[0] = *(const short4v*)p;
  u.h[1] = *(const short4v*)(p + 4);
  return u.v;
}
// pack f32x4 -> 4 bf16, 8B store
__device__ __forceinline__ void st4bf(bf16* p, f32x4 v) {
  short4v o;
  o[0] = (short)f2bf(v[0]); o[1] = (short)f2bf(v[1]);
  o[2] = (short)f2bf(v[2]); o[3] = (short)f2bf(v[3]);
  *(short4v*)p = o;
}

__device__ __forceinline__ float block_sum256(float v, float* red) {
#pragma unroll
  for (int off = 32; off; off >>= 1) v += __shfl_xor(v, off, 64);
  __syncthreads();
  if ((threadIdx.x & 63) == 0) red[threadIdx.x >> 6] = v;
  __syncthreads();
  return red[0] + red[1] + red[2] + red[3];
}

// ---------------- diagnostic sentinel (ws too small) ----------------

__global__ __launch_bounds__(256) void sentinel_kernel(float* out, int n) {
  int i = blockIdx.x * 256 + threadIdx.x;
  if (i < n) out[i] = 12345.0f;
}

// ---------------- LayerNorm -> bf16 ----------------

__global__ __launch_bounds__(256) void ln_kernel(const float* __restrict__ x,
                                                 const float* __restrict__ w,
                                                 const float* __restrict__ b,
                                                 bf16* __restrict__ y) {
  __shared__ float red[4];
  int row = blockIdx.x;
  const float* xr = x + (size_t)row * D_;
  float xv[4];
  float s = 0.f;
#pragma unroll
  for (int i = 0; i < 4; i++) { xv[i] = xr[threadIdx.x + 256 * i]; s += xv[i]; }
  float mean = block_sum256(s, red) * (1.f / D_);
  float s2 = 0.f;
#pragma unroll
  for (int i = 0; i < 4; i++) { float d = xv[i] - mean; s2 += d * d; }
  float var = block_sum256(s2, red) * (1.f / D_);
  float inv = rsqrtf(var + 1e-5f);
  bf16* yr = y + (size_t)row * D_;
#pragma unroll
  for (int i = 0; i < 4; i++) {
    int c = threadIdx.x + 256 * i;
    yr[c] = f2bf((xv[i] - mean) * inv * w[c] + b[c]);
  }
}

// ---------------- weight convert+transpose: fp32 [K][N] -> bf16 [N][K] ----------------

__global__ __launch_bounds__(256) void convT_kernel(const float* __restrict__ src,
                                                    bf16* __restrict__ dst,
                                                    int K, int N) {
  __shared__ float t[32][33];
  int n0 = blockIdx.x * 32, k0 = blockIdx.y * 32;
  int tx = threadIdx.x & 31, ty = threadIdx.x >> 5;
#pragma unroll
  for (int i = 0; i < 4; i++)
    t[ty + i * 8][tx] = src[(size_t)(k0 + ty + i * 8) * N + n0 + tx];
  __syncthreads();
#pragma unroll
  for (int i = 0; i < 4; i++)
    dst[(size_t)(n0 + ty + i * 8) * K + k0 + tx] = f2bf(t[tx][ty + i * 8]);
}

// ---- k transpose per head, CHUNK-MAJOR: k16 [b][t][h*DK+dk] ->
// kTc [bh][c=t>>6][tb=(t>>3)&7][dk][te=t&7]  (contiguous 32KB per chunk,
// exactly the LDS layout delta_p2 consumes -> fully coalesced gload_lds)

__global__ __launch_bounds__(256) void kT_kernel(const bf16* __restrict__ k16,
                                                 bf16* __restrict__ kT) {
  __shared__ bf16 tile[32][34];
  int t0 = blockIdx.x * 32;
  int d0 = blockIdx.y * 32;
  int bh = blockIdx.z;
  int b = bh >> 2, h = bh & 3;
  int tx = threadIdx.x & 31, ty = threadIdx.x >> 5;
#pragma unroll
  for (int i = 0; i < 4; i++)
    tile[ty + 8 * i][tx] = k16[(size_t)(b * T_ + t0 + ty + 8 * i) * KDIM_ + h * DK_ + d0 + tx];
  __syncthreads();
  int t = t0 + tx;
  int c = t >> 6, tb = (t >> 3) & 7, te = t & 7;
  size_t base = ((size_t)(bh * 32 + c) * 8 + tb) * 2048 + te;
#pragma unroll
  for (int i = 0; i < 4; i++)
    kT[base + (size_t)(d0 + ty + 8 * i) * 8] = tile[tx][ty + 8 * i];
}

// ---------------- bf16 MFMA GEMM ----------------
// R7: (1) 2-phase software pipeline -- next K-tile's global_load_lds issued
// BEFORE computing the current tile (LDS double-buffered), ONE sync per step;
// the stage flight overlaps ds_read+MFMA instead of serializing. (2) XCD-
// locality block remap: all column-blocks (bx) of one A-row-panel (by) land
// on the same XCD (hw xcd = linear_id % 8, proven R3), so each A panel is
// fetched once per XCD instead of 8x across XCDs.

template <typename TC>
__global__ __launch_bounds__(256) void gemm_mfma(const bf16* __restrict__ A,
                                                 const bf16* __restrict__ Bt,
                                                 const float* __restrict__ bias,
                                                 const float* __restrict__ res,
                                                 TC* __restrict__ C,
                                                 int N, int K, int flags) {
  __shared__ __align__(16) bf16 As[2][128 * 32];
  __shared__ __align__(16) bf16 Bs[2][128 * 32];
  int tid = threadIdx.x;
  int wave = tid >> 6, lane = tid & 63;

  // XCD-locality remap (grids here: gridDim.x in {8,16,32}, gridDim.y = 64)
  int nbx = gridDim.x;
  int id  = blockIdx.y * nbx + blockIdx.x;
  int xcd = id & 7;
  int g   = id >> 3;
  int bx  = g % nbx;
  int by  = xcd + 8 * (g / nbx);
  int bm = by * 128, bn = bx * 128;

  int wm = (wave >> 1) * 64, wn = (wave & 1) * 64;
  int lm = lane & 15;
  int quad = lane >> 4;

  f32x4 acc[4][4];
#pragma unroll
  for (int i = 0; i < 4; i++)
#pragma unroll
    for (int j = 0; j < 4; j++) acc[i][j] = (f32x4){0.f, 0.f, 0.f, 0.f};

  int srow = wave * 32 + (lane >> 2);
  int scol = (lane & 3) * 8;
  const bf16* ag = A  + (size_t)(bm + srow) * K + scol;
  const bf16* bg = Bt + (size_t)(bn + srow) * K + scol;
  const size_t gstep = (size_t)16 * K;
  int woff = wave * 1024;

  // prologue: stage K-tile 0 into buffer 0
  gload16(ag,         &As[0][woff]);
  gload16(ag + gstep, &As[0][woff + 512]);
  gload16(bg,         &Bs[0][woff]);
  gload16(bg + gstep, &Bs[0][woff + 512]);
  __syncthreads();

  int cur = 0;
  for (int k0 = 0; k0 < K; k0 += 32) {
    // issue next tile's stage early (overlaps with compute below)
    if (k0 + 32 < K) {
      int nb = cur ^ 1;
      gload16(ag + k0 + 32,         &As[nb][woff]);
      gload16(ag + k0 + 32 + gstep, &As[nb][woff + 512]);
      gload16(bg + k0 + 32,         &Bs[nb][woff]);
      gload16(bg + k0 + 32 + gstep, &Bs[nb][woff + 512]);
    }
    __builtin_amdgcn_sched_barrier(0);

    short8 af[4], bf[4];
#pragma unroll
    for (int i = 0; i < 4; i++)
      af[i] = *(const short8*)&As[cur][(wm + i * 16 + lm) * 32 + quad * 8];
#pragma unroll
    for (int j = 0; j < 4; j++)
      bf[j] = *(const short8*)&Bs[cur][(wn + j * 16 + lm) * 32 + quad * 8];
#pragma unroll
    for (int i = 0; i < 4; i++)
#pragma unroll
      for (int j = 0; j < 4; j++)
        acc[i][j] = __builtin_amdgcn_mfma_f32_16x16x32_bf16(af[i], bf[j], acc[i][j], 0, 0, 0);

    __syncthreads();   // drains this iteration's stage (vmcnt) + LDS hand-off
    cur ^= 1;
  }

#pragma unroll
  for (int i = 0; i < 4; i++) {
    int row0 = bm + wm + i * 16 + quad * 4;
#pragma unroll
    for (int j = 0; j < 4; j++) {
      int col = bn + wn + j * 16 + lm;
      float badd = (flags & 1) ? bias[col] : 0.f;
#pragma unroll
      for (int r = 0; r < 4; r++) {
        float v = acc[i][j][r] + badd;
        if (flags & 2) v = geluf_(v);
        if (flags & 4) v += res[(size_t)(row0 + r) * N + col];
        storeC(&C[(size_t)(row0 + r) * N + col], v);
      }
    }
  }
}

// ---------------- fused Wa/Wb projections -> g, beta ----------------

__global__ __launch_bounds__(256) void ab_kernel(const bf16* __restrict__ normed,
                                                 const float* __restrict__ Wa,
                                                 const float* __restrict__ Wb,
                                                 const float* __restrict__ A_log,
                                                 const float* __restrict__ dt_bias,
                                                 float* __restrict__ g,
                                                 float* __restrict__ beta) {
  __shared__ float red[4];
  int row = blockIdx.x;
  const bf16* xr = normed + (size_t)row * D_;
  float aacc[4] = {}, bacc[4] = {};
#pragma unroll
  for (int i = 0; i < 4; i++) {
    int d = threadIdx.x + 256 * i;
    float xv = bf2f(xr[d]);
    float4 wa = *(const float4*)&Wa[d * 4];
    float4 wb = *(const float4*)&Wb[d * 4];
    aacc[0] += xv * wa.x; aacc[1] += xv * wa.y; aacc[2] += xv * wa.z; aacc[3] += xv * wa.w;
    bacc[0] += xv * wb.x; bacc[1] += xv * wb.y; bacc[2] += xv * wb.z; bacc[3] += xv * wb.w;
  }
  float sa[4], sb[4];
#pragma unroll
  for (int h = 0; h < 4; h++) {
    sa[h] = block_sum256(aacc[h], red);
    sb[h] = block_sum256(bacc[h], red);
  }
  if (threadIdx.x < 4) {
    int h = threadIdx.x;
    float xa = sa[h] + dt_bias[h];
    float sp = (xa > 20.f) ? xa : log1pf(expf(xa));
    g[row * 4 + h] = -expf(A_log[h]) * sp;
    beta[row * 4 + h] = sigmoidf_(sb[h]);
  }
}

// ---------------- causal conv(4) + SiLU (+ L2 norm for q/k) ----------------

__global__ __launch_bounds__(256) void conv_qk_kernel(const float* __restrict__ pre,
                                                      const float* __restrict__ convw,
                                                      bf16* __restrict__ out,
                                                      float scale) {
  __shared__ float red[4];
  int blk = blockIdx.x;
  int h = blk & 3;
  int bt = blk >> 2;
  int t = bt & (T_ - 1);
  int c = h * DK_ + threadIdx.x;
  float y = 0.f;
#pragma unroll
  for (int i = 0; i < 4; i++) {
    int tt = t + i - 3;
    if (tt >= 0) y += pre[(size_t)(bt + i - 3) * KDIM_ + c] * convw[c * 4 + i];
  }
  y = siluf_(y);
  float ss = block_sum256(y * y, red);
  y *= rsqrtf(ss + 1e-6f) * scale;
  out[(size_t)bt * KDIM_ + c] = f2bf(y);
}

__global__ __launch_bounds__(256) void conv_v_kernel(const float* __restrict__ pre,
                                                     const float* __restrict__ convw,
                                                     bf16* __restrict__ out) {
  int idx = blockIdx.x * 256 + threadIdx.x;
  int c = idx & (VDIM_ - 1);
  int bt = idx >> 11;
  int t = bt & (T_ - 1);
  float y = 0.f;
#pragma unroll
  for (int i = 0; i < 4; i++) {
    int tt = t + i - 3;
    if (tt >= 0) y += pre[(size_t)(bt + i - 3) * VDIM_ + c] * convw[c * 4 + i];
  }
  out[idx] = f2bf(siluf_(y));
}

// ---------------- delta rule phase 1 (parallel over bh x chunk) ----------------
// R6: ONE forward-substitution solve (RHS=I) gives Minv = (I+A)^{-1}; each of
// the 12 column groups is then a pure 64x64x64 MFMA GEMM X = Minv @ U.

#define SP  76
#define UBP 72
#define MTP 68

__global__ __launch_bounds__(256, 2) void delta_p1(const bf16* __restrict__ q,
                                                   const bf16* __restrict__ k,
                                                   const bf16* __restrict__ v,
                                                   const float* __restrict__ g,
                                                   const float* __restrict__ beta,
                                                   bf16* __restrict__ Pg,
                                                   bf16* __restrict__ Wg,
                                                   bf16* __restrict__ Yg,
                                                   float* __restrict__ gsc) {
  __shared__ bf16 Abf[64 * SP];
  __shared__ bf16 DTg[64 * SP];                 // Minv col-major [col][row] (solve)
  __shared__ __align__(8) bf16 MT[64 * MTP];    // Minv row-major [row][col]
  __shared__ __align__(8) bf16 Ubt[64 * UBP];   // U^T per group [col][t]
  __shared__ float UbJ[16 * 64];                // current block-row RHS (f32)
  __shared__ float Gc[64], Lm[64], Bt[64];

  int blk = blockIdx.x;
  int c = blk & 31, bh = blk >> 5;
  int b = bh >> 2, h = bh & 3;
  int tid = threadIdx.x;
  int wave = tid >> 6, lane = tid & 63;
  int lm = lane & 15, quad = lane >> 4;
  int r0 = c * 64;

  const bf16* kb = k + (size_t)b * T_ * KDIM_ + h * DK_;
  const bf16* qb = q + (size_t)b * T_ * KDIM_ + h * DK_;
  const bf16* vb = v + (size_t)b * T_ * VDIM_ + h * DV_;
  const float* gbp = g    + (size_t)b * T_ * H_ + h;
  const float* bbp = beta + (size_t)b * T_ * H_ + h;
  size_t cb = (size_t)bh * 32 + c;
  bf16* PgC = Pg + cb * 4096;
  bf16* WgC = Wg + cb * 64 * 512;
  bf16* YgC = Yg + cb * 64 * 256;

  // (a) cumsum of g -> Gc, Lam, beta
  if (wave == 0) {
    float gv = gbp[(size_t)(r0 + lane) * H_];
    float bv = bbp[(size_t)(r0 + lane) * H_];
#pragma unroll
    for (int d = 1; d < 64; d <<= 1) {
      float nn = __shfl_up(gv, (unsigned)d, 64);
      if (lane >= d) gv += nn;
    }
    Gc[lane] = gv; Lm[lane] = expf(gv); Bt[lane] = bv;
    gsc[cb * 64 + lane] = gv;
  }
  // zero DTg while wave0 does cumsum
  {
    int* dz = (int*)DTg;
#pragma unroll
    for (int i = 0; i < 10; i++) {
      int idx = tid + 256 * i;
      if (idx < 64 * SP / 2) dz[idx] = 0;
    }
  }
  __syncthreads();

  // (b,c) KK^T -> Abf, QK^T -> Pg
  {
    f32x4 akk[4], aqk[4];
#pragma unroll
    for (int j = 0; j < 4; j++) { akk[j] = (f32x4){0.f,0.f,0.f,0.f}; aqk[j] = (f32x4){0.f,0.f,0.f,0.f}; }
    const bf16* krow = kb + (size_t)(r0 + 16 * wave + lm) * KDIM_;
    const bf16* qrow = qb + (size_t)(r0 + 16 * wave + lm) * KDIM_;
#pragma unroll
    for (int ks = 0; ks < 8; ks++) {
      short8 ak = *(const short8*)(krow + 8 * quad + 32 * ks);
      short8 aq = *(const short8*)(qrow + 8 * quad + 32 * ks);
#pragma unroll
      for (int j = 0; j < 4; j++) {
        short8 bk = *(const short8*)(kb + (size_t)(r0 + 16 * j + lm) * KDIM_ + 8 * quad + 32 * ks);
        akk[j] = __builtin_amdgcn_mfma_f32_16x16x32_bf16(ak, bk, akk[j], 0, 0, 0);
        aqk[j] = __builtin_amdgcn_mfma_f32_16x16x32_bf16(aq, bk, aqk[j], 0, 0, 0);
      }
    }
    float gi[4], bi[4];
#pragma unroll
    for (int r = 0; r < 4; r++) {
      int i = 16 * wave + 4 * quad + r;
      gi[r] = Gc[i]; bi[r] = Bt[i];
    }
#pragma unroll
    for (int j = 0; j < 4; j++) {
      int s = 16 * j + lm;
      float gs = Gc[s];
#pragma unroll
      for (int r = 0; r < 4; r++) {
        int i = 16 * wave + 4 * quad + r;
        float dec = expf(gi[r] - gs);
        Abf[(size_t)i * SP + s] = f2bf((s < i)  ? bi[r] * dec * akk[j][r] : 0.f);
        PgC[(size_t)i * 64 + s] = f2bf((s <= i) ? dec * aqk[j][r]        : 0.f);
      }
    }
  }
  __syncthreads();   // Abf + DTg(zero) ready

  // ---- Phase B: Minv = (I+A)^{-1}  (ONE forward-substitution pass, RHS=I) ----
#pragma unroll 1
  for (int j = 0; j < 4; j++) {
    // init UbJ = I block-row slice
#pragma unroll
    for (int i = 0; i < 4; i++) {
      int idx = tid + 256 * i;          // 1024 entries
      int row = idx >> 6, col = idx & 63;
      UbJ[row * 64 + col] = (col == 16 * j + row) ? 1.f : 0.f;
    }
    __syncthreads();
    if (j > 0) {
      f32x4 racc = (f32x4){0.f, 0.f, 0.f, 0.f};
      int nk = (j == 3) ? 2 : 1;
      for (int ks = 0; ks < nk; ks++) {
        short8 aa = ld76(&Abf[(size_t)(16 * j + lm) * SP + 8 * quad + 32 * ks]);
        short8 bd = ld76(&DTg[(size_t)(16 * wave + lm) * SP + 8 * quad + 32 * ks]);
        racc = __builtin_amdgcn_mfma_f32_16x16x32_bf16(aa, bd, racc, 0, 0, 0);
      }
#pragma unroll
      for (int r = 0; r < 4; r++)
        UbJ[(4 * quad + r) * 64 + 16 * wave + lm] -= racc[r];
      __syncthreads();
    }
    if (wave == 0) {
      int tl = lane & 15, sg = lane >> 4;
      short4v ab4 = *(const short4v*)&Abf[(size_t)(16 * j + tl) * SP + 16 * j + 4 * sg];
      float av[4];
      av[0] = bf2f((bf16)ab4[0]); av[1] = bf2f((bf16)ab4[1]);
      av[2] = bf2f((bf16)ab4[2]); av[3] = bf2f((bf16)ab4[3]);
      float d[16];
#pragma unroll
      for (int t = 0; t < 16; t++) {
        float val = UbJ[t * 64 + lane];
#pragma unroll
        for (int s = 0; s < t; s++) {
          float ats = __shfl(av[s & 3], t + 16 * (s >> 2), 64);
          val -= ats * d[s];
        }
        d[t] = val;
        bf16 vb16 = f2bf(val);
        DTg[(size_t)lane * SP + 16 * j + t] = vb16;   // col-major (solve B-reads)
        MT [(size_t)(16 * j + t) * MTP + lane] = vb16; // row-major (group GEMMs)
      }
    }
    __syncthreads();
  }

  // ---- Phase C: 12 group GEMMs  X = Minv @ U, stored straight to Wg/Yg ----
  // grp 0..7 -> W (RHS beta*V), grp 8..11 -> Y (RHS beta*Lam*K)
  int cg = 16 * wave + lm;
#pragma unroll 1
  for (int grp = 0; grp < 12; grp++) {
    // fill Ubt[cg][t] = U^T (bf16); entry barrier was end of Phase B / prev grp
#pragma unroll
    for (int ti = 0; ti < 4; ti++) {
      short4v up;
#pragma unroll
      for (int r = 0; r < 4; r++) {
        int t = 16 * ti + 4 * quad + r;
        float val;
        if (grp < 8) val = Bt[t] * bf2f(vb[(size_t)(r0 + t) * VDIM_ + grp * 64 + cg]);
        else         val = Bt[t] * Lm[t] * bf2f(kb[(size_t)(r0 + t) * KDIM_ + (grp - 8) * 64 + cg]);
        up[r] = (short)f2bf(val);
      }
      *(short4v*)&Ubt[(size_t)cg * UBP + 16 * ti + 4 * quad] = up;
    }
    asm volatile("s_waitcnt lgkmcnt(0)" ::: "memory");
    __builtin_amdgcn_s_barrier();

    // D[t][c] = sum_s Minv[t][s] * U[s][c];  A = MT rows (t), B = Ubt rows (c)
    f32x4 racc[4];
#pragma unroll
    for (int jt = 0; jt < 4; jt++) racc[jt] = (f32x4){0.f, 0.f, 0.f, 0.f};
#pragma unroll
    for (int ks = 0; ks < 2; ks++) {
      short8 aM = ld76(&MT[(size_t)(16 * wave + lm) * MTP + 8 * quad + 32 * ks]);
#pragma unroll
      for (int jt = 0; jt < 4; jt++) {
        short8 bU = ld76(&Ubt[(size_t)(16 * jt + lm) * UBP + 8 * quad + 32 * ks]);
        racc[jt] = __builtin_amdgcn_mfma_f32_16x16x32_bf16(aM, bU, racc[jt], 0, 0, 0);
      }
    }
    // store: t = 16*wave + 4*quad + rr, c = 16*jt + lm
#pragma unroll
    for (int jt = 0; jt < 4; jt++) {
#pragma unroll
      for (int rr = 0; rr < 4; rr++) {
        int t = 16 * wave + 4 * quad + rr;
        int cc = 16 * jt + lm;
        if (grp < 8) WgC[(size_t)t * 512 + grp * 64 + cc]       = f2bf(racc[jt][rr]);
        else         YgC[(size_t)t * 256 + (grp - 8) * 64 + cc] = f2bf(racc[jt][rr]);
      }
    }
    asm volatile("s_waitcnt lgkmcnt(0)" ::: "memory");
    __builtin_amdgcn_s_barrier();   // protect Ubt overwrite next group
  }
}

// ---------------- delta rule phase 2 (unchanged from R5) ----------------

#define SP2 264
#define SD  72

__global__ __launch_bounds__(256, 1) void delta_p2(const bf16* __restrict__ q,
                                                   const bf16* __restrict__ kT,
                                                   const bf16* __restrict__ Wg,
                                                   const bf16* __restrict__ Yg,
                                                   const bf16* __restrict__ Pg,
                                                   const float* __restrict__ gsc,
                                                   bf16* __restrict__ o) {
  __shared__ __align__(16) bf16 ST[32 * SP2];       // S^T [v][dk] bf16
  __shared__ __align__(16) bf16 dT[32 * SD];        // delta^T [v][t]
  __shared__ __align__(16) bf16 dTe[32 * SD];       // (e*delta)^T [v][t]
  __shared__ float Gc[64];
  __shared__ __align__(16) bf16 Ks[2][8 * 256 * 8]; // kT chunk (dbuf), [tb][dk][te]
  __shared__ __align__(16) bf16 Ws[2][64 * 32];     // W slab [t][32 cols] (dbuf)

  int blk = blockIdx.x;
  int bh = blk & 15, vs = blk >> 4;    // XCD-local: blk%8 == bh%8 for all vs
  int b = bh >> 2, h = bh & 3;
  int tid = threadIdx.x;
  int wave = tid >> 6, lane = tid & 63;
  int lm = lane & 15, quad = lane >> 4;
  int rt = wave;                       // row-tile (t rows 16rt..16rt+15)
  int v0 = vs * 32;

  const bf16* qb  = q  + (size_t)b * T_ * KDIM_ + h * DK_;
  const bf16* kTb = kT + (size_t)bh * 32 * 16384;   // chunk-major base
  const bf16* WgB = Wg + (size_t)bh * 32 * 32768 + (size_t)(tid >> 2) * 512 + v0 + (tid & 3) * 8;
  const bf16* PgB = Pg + (size_t)bh * 32 * 4096 + (size_t)(16 * rt + lm) * 64 + 8 * quad;
  bf16*       ob  = o  + (size_t)b * T_ * VDIM_ + h * DV_ + v0;

  f32x4 Sacc[4][2];                    // dk-tile (4*wave+dd) x v-col-tile cc
#pragma unroll
  for (int dd = 0; dd < 4; dd++)
#pragma unroll
    for (int cc = 0; cc < 2; cc++) Sacc[dd][cc] = (f32x4){0.f, 0.f, 0.f, 0.f};

  // ---- prologue: stage chunk 0 (Ks/Ws async; P/q/Y/gsc regs) ----
#pragma unroll
  for (int i = 0; i < 8; i++)
    gload16(kTb + i * 2048 + tid * 8, Ks[0] + i * 2048 + wave * 512);
  gload16(WgB, Ws[0] + tid * 8);
  __builtin_amdgcn_sched_barrier(0);
  short8 pfn[2];
  pfn[0] = *(const short8*)(PgB);          // issued AFTER Ks[0]/Ws[0]
  pfn[1] = *(const short8*)(PgB + 32);
  __builtin_amdgcn_sched_barrier(0);
  float gnext = gsc[(size_t)bh * 2048 + lane], gnn = 0.f;
  short8 qfr[8], yfr[8];
  {
    const bf16* qrow = qb + (size_t)(16 * rt + lm) * KDIM_;
    const bf16* yrow = Yg + (size_t)bh * 32 * 16384 + (size_t)(16 * rt + lm) * 256;
#pragma unroll
    for (int kf = 0; kf < 8; kf++) {
      qfr[kf] = *(const short8*)(qrow + 8 * quad + 32 * kf);
      yfr[kf] = *(const short8*)(yrow + 8 * quad + 32 * kf);
    }
  }

  for (int c = 0; c < 32; c++) {
    const int r0 = c * 64;
    const int idx = c & 1;
    const bf16* Ksb = Ks[idx];
    const bf16* Wsb = Ws[idx];
    bf16* Ksn = Ks[idx ^ 1];
    bf16* Wsn = Ws[idx ^ 1];

    // S4: stage S^T + Gc; raw barrier (vm prefetches stay in flight)
#pragma unroll
    for (int dd = 0; dd < 4; dd++)
#pragma unroll
      for (int cc = 0; cc < 2; cc++)
        st4bf(&ST[(size_t)(16 * cc + lm) * SP2 + 16 * (4 * wave + dd) + 4 * quad], Sacc[dd][cc]);
    Gc[lane] = gnext;   // all 4 waves write identical values (benign)
    asm volatile("s_waitcnt lgkmcnt(0)" ::: "memory");
    __builtin_amdgcn_s_barrier();

    // S5: Y = Yg@S^T, O = Q@S^T (consumes qfr/yfr prefetched last chunk)
    f32x4 Yacc[2], Oacc[2];
#pragma unroll
    for (int cc = 0; cc < 2; cc++) { Yacc[cc] = (f32x4){0.f,0.f,0.f,0.f}; Oacc[cc] = (f32x4){0.f,0.f,0.f,0.f}; }
#pragma unroll
    for (int cc = 0; cc < 2; cc++) {
      short8 Bs2[8];
#pragma unroll
      for (int kf = 0; kf < 8; kf++)
        Bs2[kf] = *(const short8*)&ST[(size_t)(16 * cc + lm) * SP2 + 8 * quad + 32 * kf];
#pragma unroll
      for (int kf = 0; kf < 8; kf++) {
        Yacc[cc] = __builtin_amdgcn_mfma_f32_16x16x32_bf16(yfr[kf], Bs2[kf], Yacc[cc], 0, 0, 0);
        Oacc[cc] = __builtin_amdgcn_mfma_f32_16x16x32_bf16(qfr[kf], Bs2[kf], Oacc[cc], 0, 0, 0);
      }
    }
    __builtin_amdgcn_sched_barrier(0);

    // ISSUE block for chunk c+1: Ks'/Ws' (gload_lds) then q/Y/gsc reg refill
    {
      int cn = (c + 1) & 31;           // c=31 wraps: valid addresses, unused
      size_t cbn = (size_t)bh * 32 + cn;
      const bf16* slab = kTb + (size_t)cn * 16384;
#pragma unroll
      for (int i = 0; i < 8; i++)
        gload16(slab + i * 2048 + tid * 8, Ksn + i * 2048 + wave * 512);
      gload16(WgB + (size_t)cn * 32768, Wsn + tid * 8);
      __builtin_amdgcn_sched_barrier(0);
      gnn = gsc[cbn * 64 + lane];
      const bf16* qrow = qb + (size_t)(cn * 64 + 16 * rt + lm) * KDIM_;
      const bf16* yrow = Yg + cbn * 16384 + (size_t)(16 * rt + lm) * 256;
#pragma unroll
      for (int kf = 0; kf < 8; kf++) {
        qfr[kf] = *(const short8*)(qrow + 8 * quad + 32 * kf);
        yfr[kf] = *(const short8*)(yrow + 8 * quad + 32 * kf);
      }
    }
    __builtin_amdgcn_sched_barrier(0);

    // S7: tie pfn (loaded last chunk AFTER Ks[idx]/Ws[idx] -> wait covers both,
    // with a full chunk of issue-to-use distance); delta = W - Y@S; dT/dTe.
    asm volatile("" : : "v"(*(const int*)&pfn[0]), "v"(*(const int*)&pfn[1]) : "memory");
    __builtin_amdgcn_sched_barrier(0);
    float g63 = Gc[63];
    float lamv[4], erv[4];
#pragma unroll
    for (int rr = 0; rr < 4; rr++) {
      float gr = Gc[16 * rt + 4 * quad + rr];
      lamv[rr] = __expf(gr);
      erv[rr]  = __expf(g63 - gr);
    }
#pragma unroll
    for (int cc = 0; cc < 2; cc++) {
      short4v dpack, depack;
#pragma unroll
      for (int rr = 0; rr < 4; rr++) {
        int row = 16 * rt + 4 * quad + rr;
        float dv = bf2f(Wsb[row * 32 + 16 * cc + lm]) - Yacc[cc][rr];
        Oacc[cc][rr] *= lamv[rr];
        dpack[rr]  = (short)f2bf(dv);
        depack[rr] = (short)f2bf(dv * erv[rr]);
      }
      *(short4v*)&dT [(size_t)(16 * cc + lm) * SD + 16 * rt + 4 * quad] = dpack;
      *(short4v*)&dTe[(size_t)(16 * cc + lm) * SD + 16 * rt + 4 * quad] = depack;
    }
    asm volatile("s_waitcnt lgkmcnt(0)" ::: "memory");
    __builtin_amdgcn_s_barrier();

    // S9 (critical path first): S <- lend*S + K^T @ (e*delta)
    float lend = __expf(g63);
    short8 Be[2][2];
#pragma unroll
    for (int cc = 0; cc < 2; cc++)
#pragma unroll
      for (int kf = 0; kf < 2; kf++)
        Be[cc][kf] = ld76(&dTe[(size_t)(16 * cc + lm) * SD + 8 * quad + 32 * kf]);
#pragma unroll
    for (int dd = 0; dd < 4; dd++) {
      int Dt = 4 * wave + dd;
#pragma unroll
      for (int cc = 0; cc < 2; cc++) {
        f32x4 s = Sacc[dd][cc];
        s[0] *= lend; s[1] *= lend; s[2] *= lend; s[3] *= lend;
#pragma unroll
        for (int kf = 0; kf < 2; kf++) {
          short8 ka = *(const short8*)&Ksb[((size_t)(quad + 4 * kf) * 256 + 16 * Dt + lm) * 8];
          s = __builtin_amdgcn_mfma_f32_16x16x32_bf16(ka, Be[cc][kf], s, 0, 0, 0);
        }
        Sacc[dd][cc] = s;
      }
    }

    // S8: O += P@delta (consumes pfn), store O
#pragma unroll
    for (int cc = 0; cc < 2; cc++) {
#pragma unroll
      for (int kf = 0; kf < 2; kf++) {
        short8 bd = ld76(&dT[(size_t)(16 * cc + lm) * SD + 8 * quad + 32 * kf]);
        Oacc[cc] = __builtin_amdgcn_mfma_f32_16x16x32_bf16(pfn[kf], bd, Oacc[cc], 0, 0, 0);
      }
#pragma unroll
      for (int rr = 0; rr < 4; rr++) {
        int row = 16 * rt + 4 * quad + rr;
        ob[(size_t)(r0 + row) * VDIM_ + 16 * cc + lm] = f2bf(Oacc[cc][rr]);
      }
    }
    __builtin_amdgcn_sched_barrier(0);

    // refill pfn for chunk c+1 (after consumption; after Ks'/Ws' in issue order)
    {
      int cn = (c + 1) & 31;
      const bf16* pc = PgB + (size_t)cn * 4096;
      pfn[0] = *(const short8*)(pc);
      pfn[1] = *(const short8*)(pc + 32);
    }
    gnext = gnn;
    asm volatile("s_waitcnt lgkmcnt(0)" ::: "memory");
    __builtin_amdgcn_s_barrier();      // protect ST/dT/dTe overwrite next iter
  }
}

// ---------------- gated RMSNorm (in place, bf16) ----------------

__global__ __launch_bounds__(256) void gated_rms_kernel(bf16* __restrict__ o,
                                                        const bf16* __restrict__ gate,
                                                        const float* __restrict__ onw) {
  __shared__ float red[4];
  int blk = blockIdx.x;
  int h = blk & 3;
  int bt = blk >> 2;
  size_t base = (size_t)bt * VDIM_ + h * DV_;
  int tid = threadIdx.x;
  float o1 = bf2f(o[base + tid]), o2 = bf2f(o[base + tid + 256]);
  float ss = block_sum256(o1 * o1 + o2 * o2, red);
  float s = rsqrtf(ss * (1.f / DV_) + 1e-5f);
  float g1 = bf2f(gate[base + tid]), g2 = bf2f(gate[base + tid + 256]);
  o[base + tid]       = f2bf(o1 * s * onw[tid] * siluf_(g1));
  o[base + tid + 256] = f2bf(o2 * s * onw[tid + 256] * siluf_(g2));
}

// ---------------- launch ----------------

extern "C" void kernel_launch(void* const* d_in, const int* in_sizes, int n_in,
                              void* d_out, int out_size, void* d_ws, size_t ws_size,
                              hipStream_t stream) {
  const float* x        = (const float*)d_in[0];
  const float* Wq       = (const float*)d_in[1];
  const float* Wk       = (const float*)d_in[2];
  const float* Wv       = (const float*)d_in[3];
  const float* Wa       = (const float*)d_in[4];
  const float* Wb       = (const float*)d_in[5];
  const float* Wg       = (const float*)d_in[6];
  const float* conv_q_w = (const float*)d_in[7];
  const float* conv_k_w = (const float*)d_in[8];
  const float* conv_v_w = (const float*)d_in[9];
  const float* A_log    = (const float*)d_in[10];
  const float* dt_bias  = (const float*)d_in[11];
  const float* o_norm_w = (const float*)d_in[12];
  const float* Wo       = (const float*)d_in[13];
  const float* ln1_w    = (const float*)d_in[14];
  const float* ln1_b    = (const float*)d_in[15];
  const float* ln2_w    = (const float*)d_in[16];
  const float* ln2_b    = (const float*)d_in[17];
  const float* ffn_w1   = (const float*)d_in[18];
  const float* ffn_b1   = (const float*)d_in[19];
  const float* ffn_w2   = (const float*)d_in[20];
  const float* ffn_b2   = (const float*)d_in[21];

  size_t required = (size_t)218 << 20;
  if (ws_size < required) {
    sentinel_kernel<<<(out_size + 255) / 256, 256, 0, stream>>>((float*)d_out, out_size);
    return;
  }

  char* base = (char*)d_ws;
  float* pre    = (float*)(base);                        // 64MB scratch (proj outs)
  bf16*  normed = (bf16*)(base + ((size_t)64  << 20));   // 16MB
  bf16*  q16    = (bf16*)(base + ((size_t)80  << 20));   // 16MB
  bf16*  k16    = (bf16*)(base + ((size_t)96  << 20));   // 16MB
  bf16*  v16    = (bf16*)(base + ((size_t)112 << 20));   // 32MB
  bf16*  g16    = (bf16*)(base + ((size_t)144 << 20));   // 32MB
  bf16*  o16    = (bf16*)(base + ((size_t)176 << 20));   // 32MB
  bf16*  wslot  = (bf16*)(base + ((size_t)208 << 20));   // 8MB JIT weight slot
  float* gvec   = (float*)(base + ((size_t)216 << 20));  // 128KB
  float* bvec   = gvec + (size_t)BT_ * H_;               // 128KB
  float* gsc    = (float*)(base + ((size_t)217 << 20));  // 128KB
  // delta-phase buffers (pre region + normed region, dead after ab_kernel):
  bf16*  Yg     = (bf16*)(base);                         // 16MB  [0,16)
  bf16*  Wgb    = (bf16*)(base + ((size_t)16 << 20));    // 32MB  [16,48)
  bf16*  Pg     = (bf16*)(base + ((size_t)48 << 20));    // 4MB   [48,52)
  bf16*  kTg    = (bf16*)(base + ((size_t)52 << 20));    // 16MB  [52,68)
  // later reuses:
  float* x2     = (float*)(base);                        // 32MB (after delta)
  bf16*  hb16   = (bf16*)(base + ((size_t)64  << 20));
  bf16*  ffn1   = (bf16*)(base + ((size_t)80  << 20));

  // 1) LN1 -> bf16
  ln_kernel<<<BT_, 256, 0, stream>>>(x, ln1_w, ln1_b, normed);

  // 2) projections + convs
  convT_kernel<<<dim3(KDIM_ / 32, D_ / 32), 256, 0, stream>>>(Wq, wslot, D_, KDIM_);
  gemm_mfma<float><<<dim3(KDIM_ / 128, BT_ / 128), 256, 0, stream>>>(normed, wslot, nullptr, nullptr, pre, KDIM_, D_, 0);
  conv_qk_kernel<<<BT_ * H_, 256, 0, stream>>>(pre, conv_q_w, q16, 0.0625f);

  convT_kernel<<<dim3(KDIM_ / 32, D_ / 32), 256, 0, stream>>>(Wk, wslot, D_, KDIM_);
  gemm_mfma<float><<<dim3(KDIM_ / 128, BT_ / 128), 256, 0, stream>>>(normed, wslot, nullptr, nullptr, pre, KDIM_, D_, 0);
  conv_qk_kernel<<<BT_ * H_, 256, 0, stream>>>(pre, conv_k_w, k16, 1.0f);

  convT_kernel<<<dim3(VDIM_ / 32, D_ / 32), 256, 0, stream>>>(Wv, wslot, D_, VDIM_);
  gemm_mfma<float><<<dim3(VDIM_ / 128, BT_ / 128), 256, 0, stream>>>(normed, wslot, nullptr, nullptr, pre, VDIM_, D_, 0);
  conv_v_kernel<<<(BT_ * VDIM_) / 256, 256, 0, stream>>>(pre, conv_v_w, v16);

  convT_kernel<<<dim3(VDIM_ / 32, D_ / 32), 256, 0, stream>>>(Wg, wslot, D_, VDIM_);
  gemm_mfma<bf16><<<dim3(VDIM_ / 128, BT_ / 128), 256, 0, stream>>>(normed, wslot, nullptr, nullptr, g16, VDIM_, D_, 0);

  ab_kernel<<<BT_, 256, 0, stream>>>(normed, Wa, Wb, A_log, dt_bias, gvec, bvec);

  // 3) delta rule: kT transpose (chunk-major) + phase 1 + pipelined phase 2
  kT_kernel<<<dim3(T_ / 32, DK_ / 32, 16), 256, 0, stream>>>(k16, kTg);
  delta_p1<<<512, 256, 0, stream>>>(q16, k16, v16, gvec, bvec, Pg, Wgb, Yg, gsc);
  delta_p2<<<256, 256, 0, stream>>>(q16, kTg, Wgb, Yg, Pg, gsc, o16);

  // 4) gated RMSNorm (in place)
  gated_rms_kernel<<<BT_ * H_, 256, 0, stream>>>(o16, g16, o_norm_w);

  // 5) x2 = x + o @ Wo
  convT_kernel<<<dim3(D_ / 32, VDIM_ / 32), 256, 0, stream>>>(Wo, wslot, VDIM_, D_);
  gemm_mfma<float><<<dim3(D_ / 128, BT_ / 128), 256, 0, stream>>>(o16, wslot, nullptr, x, x2, D_, VDIM_, 4);

  // 6) LN2 -> bf16
  ln_kernel<<<BT_, 256, 0, stream>>>(x2, ln2_w, ln2_b, hb16);

  // 7) FFN
  convT_kernel<<<dim3(FFN_ / 32, D_ / 32), 256, 0, stream>>>(ffn_w1, wslot, D_, FFN_);
  gemm_mfma<bf16><<<dim3(FFN_ / 128, BT_ / 128), 256, 0, stream>>>(hb16, wslot, ffn_b1, nullptr, ffn1, FFN_, D_, 1 | 2);
  convT_kernel<<<dim3(D_ / 32, FFN_ / 32), 256, 0, stream>>>(ffn_w2, wslot, FFN_, D_);
  gemm_mfma<float><<<dim3(D_ / 128, BT_ / 128), 256, 0, stream>>>(ffn1, wslot, ffn_b2, x2, (float*)d_out, D_, FFN_, 1 | 4);
}

// Round 8
// 1045.000 us; speedup vs baseline: 1.2112x; 1.0045x over previous
//
#include <hip/hip_runtime.h>
#include <math.h>

#define B_    4
#define T_    2048
#define D_    1024
#define H_    4
#define DK_   256
#define DV_   512
#define KDIM_ 1024
#define VDIM_ 2048
#define FFN_  4096
#define BT_   8192   // B_*T_

typedef unsigned short bf16;
typedef __attribute__((ext_vector_type(8))) short short8;   // MFMA A/B frag (8 bf16)
typedef __attribute__((ext_vector_type(4))) short short4v;  // 4 bf16
typedef __attribute__((ext_vector_type(4))) float f32x4;    // MFMA C/D frag

// ---------------- helpers ----------------

__device__ __forceinline__ float sigmoidf_(float x) { return 1.f / (1.f + expf(-x)); }
__device__ __forceinline__ float siluf_(float x)    { return x / (1.f + expf(-x)); }
__device__ __forceinline__ float geluf_(float x)    { return 0.5f * x * (1.f + erff(x * 0.70710678118654752f)); }

__device__ __forceinline__ float bf2f(bf16 u) {
  union { unsigned int i; float f; } c; c.i = (unsigned int)u << 16; return c.f;
}
__device__ __forceinline__ bf16 f2bf(float f) {
  union { unsigned int i; float f; } c; c.f = f;
  unsigned int r = c.i + 0x7fffu + ((c.i >> 16) & 1u);   // RNE
  return (bf16)(r >> 16);
}

// async global->LDS, 16B per lane
__device__ __forceinline__ void gload16(const bf16* g, bf16* l) {
  __builtin_amdgcn_global_load_lds((__attribute__((address_space(1))) const void*)g,
                                   (__attribute__((address_space(3))) void*)l, 16, 0, 0);
}

__device__ __forceinline__ void storeC(float* p, float v) { *p = v; }
__device__ __forceinline__ void storeC(bf16* p, float v)  { *p = f2bf(v); }

// load 8 bf16 from an 8B-aligned LDS address as two b64s
__device__ __forceinline__ short8 ld76(const bf16* p) {
  union { short8 v; short4v h[2]; } u;
  u.h[0] = *(const short4v*)p;
  u.h[1] = *(const short4v*)(p + 4);
  return u.v;
}
// pack f32x4 -> 4 bf16, 8B store
__device__ __forceinline__ void st4bf(bf16* p, f32x4 v) {
  short4v o;
  o[0] = (short)f2bf(v[0]); o[1] = (short)f2bf(v[1]);
  o[2] = (short)f2bf(v[2]); o[3] = (short)f2bf(v[3]);
  *(short4v*)p = o;
}

__device__ __forceinline__ float block_sum256(float v, float* red) {
#pragma unroll
  for (int off = 32; off; off >>= 1) v += __shfl_xor(v, off, 64);
  __syncthreads();
  if ((threadIdx.x & 63) == 0) red[threadIdx.x >> 6] = v;
  __syncthreads();
  return red[0] + red[1] + red[2] + red[3];
}

// ---------------- diagnostic sentinel (ws too small) ----------------

__global__ __launch_bounds__(256) void sentinel_kernel(float* out, int n) {
  int i = blockIdx.x * 256 + threadIdx.x;
  if (i < n) out[i] = 12345.0f;
}

// ---------------- LayerNorm -> bf16 ----------------

__global__ __launch_bounds__(256) void ln_kernel(const float* __restrict__ x,
                                                 const float* __restrict__ w,
                                                 const float* __restrict__ b,
                                                 bf16* __restrict__ y) {
  __shared__ float red[4];
  int row = blockIdx.x;
  const float* xr = x + (size_t)row * D_;
  float xv[4];
  float s = 0.f;
#pragma unroll
  for (int i = 0; i < 4; i++) { xv[i] = xr[threadIdx.x + 256 * i]; s += xv[i]; }
  float mean = block_sum256(s, red) * (1.f / D_);
  float s2 = 0.f;
#pragma unroll
  for (int i = 0; i < 4; i++) { float d = xv[i] - mean; s2 += d * d; }
  float var = block_sum256(s2, red) * (1.f / D_);
  float inv = rsqrtf(var + 1e-5f);
  bf16* yr = y + (size_t)row * D_;
#pragma unroll
  for (int i = 0; i < 4; i++) {
    int c = threadIdx.x + 256 * i;
    yr[c] = f2bf((xv[i] - mean) * inv * w[c] + b[c]);
  }
}

// ---------------- weight convert+transpose: fp32 [K][N] -> bf16 [N][K] ----------------

__global__ __launch_bounds__(256) void convT_kernel(const float* __restrict__ src,
                                                    bf16* __restrict__ dst,
                                                    int K, int N) {
  __shared__ float t[32][33];
  int n0 = blockIdx.x * 32, k0 = blockIdx.y * 32;
  int tx = threadIdx.x & 31, ty = threadIdx.x >> 5;
#pragma unroll
  for (int i = 0; i < 4; i++)
    t[ty + i * 8][tx] = src[(size_t)(k0 + ty + i * 8) * N + n0 + tx];
  __syncthreads();
#pragma unroll
  for (int i = 0; i < 4; i++)
    dst[(size_t)(n0 + ty + i * 8) * K + k0 + tx] = f2bf(t[tx][ty + i * 8]);
}

// ---- k transpose per head, CHUNK-MAJOR: k16 [b][t][h*DK+dk] ->
// kTc [bh][c=t>>6][tb=(t>>3)&7][dk][te=t&7]  (contiguous 32KB per chunk,
// exactly the LDS layout delta_p2 consumes -> fully coalesced gload_lds)

__global__ __launch_bounds__(256) void kT_kernel(const bf16* __restrict__ k16,
                                                 bf16* __restrict__ kT) {
  __shared__ bf16 tile[32][34];
  int t0 = blockIdx.x * 32;
  int d0 = blockIdx.y * 32;
  int bh = blockIdx.z;
  int b = bh >> 2, h = bh & 3;
  int tx = threadIdx.x & 31, ty = threadIdx.x >> 5;
#pragma unroll
  for (int i = 0; i < 4; i++)
    tile[ty + 8 * i][tx] = k16[(size_t)(b * T_ + t0 + ty + 8 * i) * KDIM_ + h * DK_ + d0 + tx];
  __syncthreads();
  int t = t0 + tx;
  int c = t >> 6, tb = (t >> 3) & 7, te = t & 7;
  size_t base = ((size_t)(bh * 32 + c) * 8 + tb) * 2048 + te;
#pragma unroll
  for (int i = 0; i < 4; i++)
    kT[base + (size_t)(d0 + ty + 8 * i) * 8] = tile[tx][ty + 8 * i];
}

// ---------------- bf16 MFMA GEMM ----------------
// R8: depth-3 software pipeline with COUNTED vmcnt (never drained in-loop).
// Per iteration (per wave, exactly 4 gload16): wait vmcnt(8) -> the 2 newer
// stages stay in flight; raw s_barrier (no vmcnt drain); ds_read+MFMA;
// lgkmcnt(0)+s_barrier (read-vs-overwrite guard); stage tile i+3 into the
// just-consumed buffer (tail iterations re-stage the last tile to keep the
// per-wave vmcnt ledger uniform). Loads get ~2 iterations of flight. XCD-
// locality remap kept from R7.

template <typename TC>
__global__ __launch_bounds__(256) void gemm_mfma(const bf16* __restrict__ A,
                                                 const bf16* __restrict__ Bt,
                                                 const float* __restrict__ bias,
                                                 const float* __restrict__ res,
                                                 TC* __restrict__ C,
                                                 int N, int K, int flags) {
  __shared__ __align__(16) bf16 As[3][128 * 32];
  __shared__ __align__(16) bf16 Bs[3][128 * 32];
  int tid = threadIdx.x;
  int wave = tid >> 6, lane = tid & 63;

  // XCD-locality remap (grids here: gridDim.x in {8,16,32}, gridDim.y = 64)
  int nbx = gridDim.x;
  int id  = blockIdx.y * nbx + blockIdx.x;
  int xcd = id & 7;
  int g   = id >> 3;
  int bx  = g % nbx;
  int by  = xcd + 8 * (g / nbx);
  int bm = by * 128, bn = bx * 128;

  int wm = (wave >> 1) * 64, wn = (wave & 1) * 64;
  int lm = lane & 15;
  int quad = lane >> 4;

  f32x4 acc[4][4];
#pragma unroll
  for (int i = 0; i < 4; i++)
#pragma unroll
    for (int j = 0; j < 4; j++) acc[i][j] = (f32x4){0.f, 0.f, 0.f, 0.f};

  int srow = wave * 32 + (lane >> 2);
  int scol = (lane & 3) * 8;
  const bf16* ag = A  + (size_t)(bm + srow) * K + scol;
  const bf16* bg = Bt + (size_t)(bn + srow) * K + scol;
  const size_t gstep = (size_t)16 * K;
  int woff = wave * 1024;

  int nt = K >> 5;
  // prologue: stage tiles 0,1,2 (clamped; K here is always >= 1024 so nt >= 32)
#pragma unroll
  for (int p = 0; p < 3; p++) {
    int kt = (p < nt) ? p : nt - 1;
    size_t k0 = (size_t)kt << 5;
    gload16(ag + k0,         &As[p][woff]);
    gload16(ag + k0 + gstep, &As[p][woff + 512]);
    gload16(bg + k0,         &Bs[p][woff]);
    gload16(bg + k0 + gstep, &Bs[p][woff + 512]);
  }
  __builtin_amdgcn_sched_barrier(0);

  int cur = 0;
  for (int i = 0; i < nt; i++) {
    // stage(i) complete when <= 8 outstanding (stages i+1, i+2 in flight)
    asm volatile("s_waitcnt vmcnt(8)" ::: "memory");
    __builtin_amdgcn_s_barrier();
    __builtin_amdgcn_sched_barrier(0);

    short8 af[4], bf[4];
#pragma unroll
    for (int i4 = 0; i4 < 4; i4++)
      af[i4] = *(const short8*)&As[cur][(wm + i4 * 16 + lm) * 32 + quad * 8];
#pragma unroll
    for (int j4 = 0; j4 < 4; j4++)
      bf[j4] = *(const short8*)&Bs[cur][(wn + j4 * 16 + lm) * 32 + quad * 8];
#pragma unroll
    for (int i4 = 0; i4 < 4; i4++)
#pragma unroll
      for (int j4 = 0; j4 < 4; j4++)
        acc[i4][j4] = __builtin_amdgcn_mfma_f32_16x16x32_bf16(af[i4], bf[j4], acc[i4][j4], 0, 0, 0);

    asm volatile("s_waitcnt lgkmcnt(0)" ::: "memory");
    __builtin_amdgcn_s_barrier();     // all waves done reading buf[cur]
    __builtin_amdgcn_sched_barrier(0);

    // stage tile i+3 into the buffer just consumed (clamped tail keeps the
    // per-wave vmcnt ledger at exactly 4 ops/iteration)
    {
      int kt = (i + 3 < nt) ? i + 3 : nt - 1;
      size_t k0 = (size_t)kt << 5;
      gload16(ag + k0,         &As[cur][woff]);
      gload16(ag + k0 + gstep, &As[cur][woff + 512]);
      gload16(bg + k0,         &Bs[cur][woff]);
      gload16(bg + k0 + gstep, &Bs[cur][woff + 512]);
    }
    __builtin_amdgcn_sched_barrier(0);

    cur++; if (cur == 3) cur = 0;
  }

#pragma unroll
  for (int i = 0; i < 4; i++) {
    int row0 = bm + wm + i * 16 + quad * 4;
#pragma unroll
    for (int j = 0; j < 4; j++) {
      int col = bn + wn + j * 16 + lm;
      float badd = (flags & 1) ? bias[col] : 0.f;
#pragma unroll
      for (int r = 0; r < 4; r++) {
        float v = acc[i][j][r] + badd;
        if (flags & 2) v = geluf_(v);
        if (flags & 4) v += res[(size_t)(row0 + r) * N + col];
        storeC(&C[(size_t)(row0 + r) * N + col], v);
      }
    }
  }
}

// ---------------- fused Wa/Wb projections -> g, beta ----------------

__global__ __launch_bounds__(256) void ab_kernel(const bf16* __restrict__ normed,
                                                 const float* __restrict__ Wa,
                                                 const float* __restrict__ Wb,
                                                 const float* __restrict__ A_log,
                                                 const float* __restrict__ dt_bias,
                                                 float* __restrict__ g,
                                                 float* __restrict__ beta) {
  __shared__ float red[4];
  int row = blockIdx.x;
  const bf16* xr = normed + (size_t)row * D_;
  float aacc[4] = {}, bacc[4] = {};
#pragma unroll
  for (int i = 0; i < 4; i++) {
    int d = threadIdx.x + 256 * i;
    float xv = bf2f(xr[d]);
    float4 wa = *(const float4*)&Wa[d * 4];
    float4 wb = *(const float4*)&Wb[d * 4];
    aacc[0] += xv * wa.x; aacc[1] += xv * wa.y; aacc[2] += xv * wa.z; aacc[3] += xv * wa.w;
    bacc[0] += xv * wb.x; bacc[1] += xv * wb.y; bacc[2] += xv * wb.z; bacc[3] += xv * wb.w;
  }
  float sa[4], sb[4];
#pragma unroll
  for (int h = 0; h < 4; h++) {
    sa[h] = block_sum256(aacc[h], red);
    sb[h] = block_sum256(bacc[h], red);
  }
  if (threadIdx.x < 4) {
    int h = threadIdx.x;
    float xa = sa[h] + dt_bias[h];
    float sp = (xa > 20.f) ? xa : log1pf(expf(xa));
    g[row * 4 + h] = -expf(A_log[h]) * sp;
    beta[row * 4 + h] = sigmoidf_(sb[h]);
  }
}

// ---------------- causal conv(4) + SiLU (+ L2 norm for q/k) ----------------

__global__ __launch_bounds__(256) void conv_qk_kernel(const float* __restrict__ pre,
                                                      const float* __restrict__ convw,
                                                      bf16* __restrict__ out,
                                                      float scale) {
  __shared__ float red[4];
  int blk = blockIdx.x;
  int h = blk & 3;
  int bt = blk >> 2;
  int t = bt & (T_ - 1);
  int c = h * DK_ + threadIdx.x;
  float y = 0.f;
#pragma unroll
  for (int i = 0; i < 4; i++) {
    int tt = t + i - 3;
    if (tt >= 0) y += pre[(size_t)(bt + i - 3) * KDIM_ + c] * convw[c * 4 + i];
  }
  y = siluf_(y);
  float ss = block_sum256(y * y, red);
  y *= rsqrtf(ss + 1e-6f) * scale;
  out[(size_t)bt * KDIM_ + c] = f2bf(y);
}

__global__ __launch_bounds__(256) void conv_v_kernel(const float* __restrict__ pre,
                                                     const float* __restrict__ convw,
                                                     bf16* __restrict__ out) {
  int idx = blockIdx.x * 256 + threadIdx.x;
  int c = idx & (VDIM_ - 1);
  int bt = idx >> 11;
  int t = bt & (T_ - 1);
  float y = 0.f;
#pragma unroll
  for (int i = 0; i < 4; i++) {
    int tt = t + i - 3;
    if (tt >= 0) y += pre[(size_t)(bt + i - 3) * VDIM_ + c] * convw[c * 4 + i];
  }
  out[idx] = f2bf(siluf_(y));
}

// ---------------- delta rule phase 1 (parallel over bh x chunk) ----------------
// R6: ONE forward-substitution solve (RHS=I) gives Minv = (I+A)^{-1}; each of
// the 12 column groups is then a pure 64x64x64 MFMA GEMM X = Minv @ U.

#define SP  76
#define UBP 72
#define MTP 68

__global__ __launch_bounds__(256, 2) void delta_p1(const bf16* __restrict__ q,
                                                   const bf16* __restrict__ k,
                                                   const bf16* __restrict__ v,
                                                   const float* __restrict__ g,
                                                   const float* __restrict__ beta,
                                                   bf16* __restrict__ Pg,
                                                   bf16* __restrict__ Wg,
                                                   bf16* __restrict__ Yg,
                                                   float* __restrict__ gsc) {
  __shared__ bf16 Abf[64 * SP];
  __shared__ bf16 DTg[64 * SP];                 // Minv col-major [col][row] (solve)
  __shared__ __align__(8) bf16 MT[64 * MTP];    // Minv row-major [row][col]
  __shared__ __align__(8) bf16 Ubt[64 * UBP];   // U^T per group [col][t]
  __shared__ float UbJ[16 * 64];                // current block-row RHS (f32)
  __shared__ float Gc[64], Lm[64], Bt[64];

  int blk = blockIdx.x;
  int c = blk & 31, bh = blk >> 5;
  int b = bh >> 2, h = bh & 3;
  int tid = threadIdx.x;
  int wave = tid >> 6, lane = tid & 63;
  int lm = lane & 15, quad = lane >> 4;
  int r0 = c * 64;

  const bf16* kb = k + (size_t)b * T_ * KDIM_ + h * DK_;
  const bf16* qb = q + (size_t)b * T_ * KDIM_ + h * DK_;
  const bf16* vb = v + (size_t)b * T_ * VDIM_ + h * DV_;
  const float* gbp = g    + (size_t)b * T_ * H_ + h;
  const float* bbp = beta + (size_t)b * T_ * H_ + h;
  size_t cb = (size_t)bh * 32 + c;
  bf16* PgC = Pg + cb * 4096;
  bf16* WgC = Wg + cb * 64 * 512;
  bf16* YgC = Yg + cb * 64 * 256;

  // (a) cumsum of g -> Gc, Lam, beta
  if (wave == 0) {
    float gv = gbp[(size_t)(r0 + lane) * H_];
    float bv = bbp[(size_t)(r0 + lane) * H_];
#pragma unroll
    for (int d = 1; d < 64; d <<= 1) {
      float nn = __shfl_up(gv, (unsigned)d, 64);
      if (lane >= d) gv += nn;
    }
    Gc[lane] = gv; Lm[lane] = expf(gv); Bt[lane] = bv;
    gsc[cb * 64 + lane] = gv;
  }
  // zero DTg while wave0 does cumsum
  {
    int* dz = (int*)DTg;
#pragma unroll
    for (int i = 0; i < 10; i++) {
      int idx = tid + 256 * i;
      if (idx < 64 * SP / 2) dz[idx] = 0;
    }
  }
  __syncthreads();

  // (b,c) KK^T -> Abf, QK^T -> Pg
  {
    f32x4 akk[4], aqk[4];
#pragma unroll
    for (int j = 0; j < 4; j++) { akk[j] = (f32x4){0.f,0.f,0.f,0.f}; aqk[j] = (f32x4){0.f,0.f,0.f,0.f}; }
    const bf16* krow = kb + (size_t)(r0 + 16 * wave + lm) * KDIM_;
    const bf16* qrow = qb + (size_t)(r0 + 16 * wave + lm) * KDIM_;
#pragma unroll
    for (int ks = 0; ks < 8; ks++) {
      short8 ak = *(const short8*)(krow + 8 * quad + 32 * ks);
      short8 aq = *(const short8*)(qrow + 8 * quad + 32 * ks);
#pragma unroll
      for (int j = 0; j < 4; j++) {
        short8 bk = *(const short8*)(kb + (size_t)(r0 + 16 * j + lm) * KDIM_ + 8 * quad + 32 * ks);
        akk[j] = __builtin_amdgcn_mfma_f32_16x16x32_bf16(ak, bk, akk[j], 0, 0, 0);
        aqk[j] = __builtin_amdgcn_mfma_f32_16x16x32_bf16(aq, bk, aqk[j], 0, 0, 0);
      }
    }
    float gi[4], bi[4];
#pragma unroll
    for (int r = 0; r < 4; r++) {
      int i = 16 * wave + 4 * quad + r;
      gi[r] = Gc[i]; bi[r] = Bt[i];
    }
#pragma unroll
    for (int j = 0; j < 4; j++) {
      int s = 16 * j + lm;
      float gs = Gc[s];
#pragma unroll
      for (int r = 0; r < 4; r++) {
        int i = 16 * wave + 4 * quad + r;
        float dec = expf(gi[r] - gs);
        Abf[(size_t)i * SP + s] = f2bf((s < i)  ? bi[r] * dec * akk[j][r] : 0.f);
        PgC[(size_t)i * 64 + s] = f2bf((s <= i) ? dec * aqk[j][r]        : 0.f);
      }
    }
  }
  __syncthreads();   // Abf + DTg(zero) ready

  // ---- Phase B: Minv = (I+A)^{-1}  (ONE forward-substitution pass, RHS=I) ----
#pragma unroll 1
  for (int j = 0; j < 4; j++) {
    // init UbJ = I block-row slice
#pragma unroll
    for (int i = 0; i < 4; i++) {
      int idx = tid + 256 * i;          // 1024 entries
      int row = idx >> 6, col = idx & 63;
      UbJ[row * 64 + col] = (col == 16 * j + row) ? 1.f : 0.f;
    }
    __syncthreads();
    if (j > 0) {
      f32x4 racc = (f32x4){0.f, 0.f, 0.f, 0.f};
      int nk = (j == 3) ? 2 : 1;
      for (int ks = 0; ks < nk; ks++) {
        short8 aa = ld76(&Abf[(size_t)(16 * j + lm) * SP + 8 * quad + 32 * ks]);
        short8 bd = ld76(&DTg[(size_t)(16 * wave + lm) * SP + 8 * quad + 32 * ks]);
        racc = __builtin_amdgcn_mfma_f32_16x16x32_bf16(aa, bd, racc, 0, 0, 0);
      }
#pragma unroll
      for (int r = 0; r < 4; r++)
        UbJ[(4 * quad + r) * 64 + 16 * wave + lm] -= racc[r];
      __syncthreads();
    }
    if (wave == 0) {
      int tl = lane & 15, sg = lane >> 4;
      short4v ab4 = *(const short4v*)&Abf[(size_t)(16 * j + tl) * SP + 16 * j + 4 * sg];
      float av[4];
      av[0] = bf2f((bf16)ab4[0]); av[1] = bf2f((bf16)ab4[1]);
      av[2] = bf2f((bf16)ab4[2]); av[3] = bf2f((bf16)ab4[3]);
      float d[16];
#pragma unroll
      for (int t = 0; t < 16; t++) {
        float val = UbJ[t * 64 + lane];
#pragma unroll
        for (int s = 0; s < t; s++) {
          float ats = __shfl(av[s & 3], t + 16 * (s >> 2), 64);
          val -= ats * d[s];
        }
        d[t] = val;
        bf16 vb16 = f2bf(val);
        DTg[(size_t)lane * SP + 16 * j + t] = vb16;   // col-major (solve B-reads)
        MT [(size_t)(16 * j + t) * MTP + lane] = vb16; // row-major (group GEMMs)
      }
    }
    __syncthreads();
  }

  // ---- Phase C: 12 group GEMMs  X = Minv @ U, stored straight to Wg/Yg ----
  // grp 0..7 -> W (RHS beta*V), grp 8..11 -> Y (RHS beta*Lam*K)
  int cg = 16 * wave + lm;
#pragma unroll 1
  for (int grp = 0; grp < 12; grp++) {
    // fill Ubt[cg][t] = U^T (bf16); entry barrier was end of Phase B / prev grp
#pragma unroll
    for (int ti = 0; ti < 4; ti++) {
      short4v up;
#pragma unroll
      for (int r = 0; r < 4; r++) {
        int t = 16 * ti + 4 * quad + r;
        float val;
        if (grp < 8) val = Bt[t] * bf2f(vb[(size_t)(r0 + t) * VDIM_ + grp * 64 + cg]);
        else         val = Bt[t] * Lm[t] * bf2f(kb[(size_t)(r0 + t) * KDIM_ + (grp - 8) * 64 + cg]);
        up[r] = (short)f2bf(val);
      }
      *(short4v*)&Ubt[(size_t)cg * UBP + 16 * ti + 4 * quad] = up;
    }
    asm volatile("s_waitcnt lgkmcnt(0)" ::: "memory");
    __builtin_amdgcn_s_barrier();

    // D[t][c] = sum_s Minv[t][s] * U[s][c];  A = MT rows (t), B = Ubt rows (c)
    f32x4 racc[4];
#pragma unroll
    for (int jt = 0; jt < 4; jt++) racc[jt] = (f32x4){0.f, 0.f, 0.f, 0.f};
#pragma unroll
    for (int ks = 0; ks < 2; ks++) {
      short8 aM = ld76(&MT[(size_t)(16 * wave + lm) * MTP + 8 * quad + 32 * ks]);
#pragma unroll
      for (int jt = 0; jt < 4; jt++) {
        short8 bU = ld76(&Ubt[(size_t)(16 * jt + lm) * UBP + 8 * quad + 32 * ks]);
        racc[jt] = __builtin_amdgcn_mfma_f32_16x16x32_bf16(aM, bU, racc[jt], 0, 0, 0);
      }
    }
    // store: t = 16*wave + 4*quad + rr, c = 16*jt + lm
#pragma unroll
    for (int jt = 0; jt < 4; jt++) {
#pragma unroll
      for (int rr = 0; rr < 4; rr++) {
        int t = 16 * wave + 4 * quad + rr;
        int cc = 16 * jt + lm;
        if (grp < 8) WgC[(size_t)t * 512 + grp * 64 + cc]       = f2bf(racc[jt][rr]);
        else         YgC[(size_t)t * 256 + (grp - 8) * 64 + cc] = f2bf(racc[jt][rr]);
      }
    }
    asm volatile("s_waitcnt lgkmcnt(0)" ::: "memory");
    __builtin_amdgcn_s_barrier();   // protect Ubt overwrite next group
  }
}

// ---------------- delta rule phase 2 (unchanged from R5) ----------------

#define SP2 264
#define SD  72

__global__ __launch_bounds__(256, 1) void delta_p2(const bf16* __restrict__ q,
                                                   const bf16* __restrict__ kT,
                                                   const bf16* __restrict__ Wg,
                                                   const bf16* __restrict__ Yg,
                                                   const bf16* __restrict__ Pg,
                                                   const float* __restrict__ gsc,
                                                   bf16* __restrict__ o) {
  __shared__ __align__(16) bf16 ST[32 * SP2];       // S^T [v][dk] bf16
  __shared__ __align__(16) bf16 dT[32 * SD];        // delta^T [v][t]
  __shared__ __align__(16) bf16 dTe[32 * SD];       // (e*delta)^T [v][t]
  __shared__ float Gc[64];
  __shared__ __align__(16) bf16 Ks[2][8 * 256 * 8]; // kT chunk (dbuf), [tb][dk][te]
  __shared__ __align__(16) bf16 Ws[2][64 * 32];     // W slab [t][32 cols] (dbuf)

  int blk = blockIdx.x;
  int bh = blk & 15, vs = blk >> 4;    // XCD-local: blk%8 == bh%8 for all vs
  int b = bh >> 2, h = bh & 3;
  int tid = threadIdx.x;
  int wave = tid >> 6, lane = tid & 63;
  int lm = lane & 15, quad = lane >> 4;
  int rt = wave;                       // row-tile (t rows 16rt..16rt+15)
  int v0 = vs * 32;

  const bf16* qb  = q  + (size_t)b * T_ * KDIM_ + h * DK_;
  const bf16* kTb = kT + (size_t)bh * 32 * 16384;   // chunk-major base
  const bf16* WgB = Wg + (size_t)bh * 32 * 32768 + (size_t)(tid >> 2) * 512 + v0 + (tid & 3) * 8;
  const bf16* PgB = Pg + (size_t)bh * 32 * 4096 + (size_t)(16 * rt + lm) * 64 + 8 * quad;
  bf16*       ob  = o  + (size_t)b * T_ * VDIM_ + h * DV_ + v0;

  f32x4 Sacc[4][2];                    // dk-tile (4*wave+dd) x v-col-tile cc
#pragma unroll
  for (int dd = 0; dd < 4; dd++)
#pragma unroll
    for (int cc = 0; cc < 2; cc++) Sacc[dd][cc] = (f32x4){0.f, 0.f, 0.f, 0.f};

  // ---- prologue: stage chunk 0 (Ks/Ws async; P/q/Y/gsc regs) ----
#pragma unroll
  for (int i = 0; i < 8; i++)
    gload16(kTb + i * 2048 + tid * 8, Ks[0] + i * 2048 + wave * 512);
  gload16(WgB, Ws[0] + tid * 8);
  __builtin_amdgcn_sched_barrier(0);
  short8 pfn[2];
  pfn[0] = *(const short8*)(PgB);          // issued AFTER Ks[0]/Ws[0]
  pfn[1] = *(const short8*)(PgB + 32);
  __builtin_amdgcn_sched_barrier(0);
  float gnext = gsc[(size_t)bh * 2048 + lane], gnn = 0.f;
  short8 qfr[8], yfr[8];
  {
    const bf16* qrow = qb + (size_t)(16 * rt + lm) * KDIM_;
    const bf16* yrow = Yg + (size_t)bh * 32 * 16384 + (size_t)(16 * rt + lm) * 256;
#pragma unroll
    for (int kf = 0; kf < 8; kf++) {
      qfr[kf] = *(const short8*)(qrow + 8 * quad + 32 * kf);
      yfr[kf] = *(const short8*)(yrow + 8 * quad + 32 * kf);
    }
  }

  for (int c = 0; c < 32; c++) {
    const int r0 = c * 64;
    const int idx = c & 1;
    const bf16* Ksb = Ks[idx];
    const bf16* Wsb = Ws[idx];
    bf16* Ksn = Ks[idx ^ 1];
    bf16* Wsn = Ws[idx ^ 1];

    // S4: stage S^T + Gc; raw barrier (vm prefetches stay in flight)
#pragma unroll
    for (int dd = 0; dd < 4; dd++)
#pragma unroll
      for (int cc = 0; cc < 2; cc++)
        st4bf(&ST[(size_t)(16 * cc + lm) * SP2 + 16 * (4 * wave + dd) + 4 * quad], Sacc[dd][cc]);
    Gc[lane] = gnext;   // all 4 waves write identical values (benign)
    asm volatile("s_waitcnt lgkmcnt(0)" ::: "memory");
    __builtin_amdgcn_s_barrier();

    // S5: Y = Yg@S^T, O = Q@S^T (consumes qfr/yfr prefetched last chunk)
    f32x4 Yacc[2], Oacc[2];
#pragma unroll
    for (int cc = 0; cc < 2; cc++) { Yacc[cc] = (f32x4){0.f,0.f,0.f,0.f}; Oacc[cc] = (f32x4){0.f,0.f,0.f,0.f}; }
#pragma unroll
    for (int cc = 0; cc < 2; cc++) {
      short8 Bs2[8];
#pragma unroll
      for (int kf = 0; kf < 8; kf++)
        Bs2[kf] = *(const short8*)&ST[(size_t)(16 * cc + lm) * SP2 + 8 * quad + 32 * kf];
#pragma unroll
      for (int kf = 0; kf < 8; kf++) {
        Yacc[cc] = __builtin_amdgcn_mfma_f32_16x16x32_bf16(yfr[kf], Bs2[kf], Yacc[cc], 0, 0, 0);
        Oacc[cc] = __builtin_amdgcn_mfma_f32_16x16x32_bf16(qfr[kf], Bs2[kf], Oacc[cc], 0, 0, 0);
      }
    }
    __builtin_amdgcn_sched_barrier(0);

    // ISSUE block for chunk c+1: Ks'/Ws' (gload_lds) then q/Y/gsc reg refill
    {
      int cn = (c + 1) & 31;           // c=31 wraps: valid addresses, unused
      size_t cbn = (size_t)bh * 32 + cn;
      const bf16* slab = kTb + (size_t)cn * 16384;
#pragma unroll
      for (int i = 0; i < 8; i++)
        gload16(slab + i * 2048 + tid * 8, Ksn + i * 2048 + wave * 512);
      gload16(WgB + (size_t)cn * 32768, Wsn + tid * 8);
      __builtin_amdgcn_sched_barrier(0);
      gnn = gsc[cbn * 64 + lane];
      const bf16* qrow = qb + (size_t)(cn * 64 + 16 * rt + lm) * KDIM_;
      const bf16* yrow = Yg + cbn * 16384 + (size_t)(16 * rt + lm) * 256;
#pragma unroll
      for (int kf = 0; kf < 8; kf++) {
        qfr[kf] = *(const short8*)(qrow + 8 * quad + 32 * kf);
        yfr[kf] = *(const short8*)(yrow + 8 * quad + 32 * kf);
      }
    }
    __builtin_amdgcn_sched_barrier(0);

    // S7: tie pfn (loaded last chunk AFTER Ks[idx]/Ws[idx] -> wait covers both,
    // with a full chunk of issue-to-use distance); delta = W - Y@S; dT/dTe.
    asm volatile("" : : "v"(*(const int*)&pfn[0]), "v"(*(const int*)&pfn[1]) : "memory");
    __builtin_amdgcn_sched_barrier(0);
    float g63 = Gc[63];
    float lamv[4], erv[4];
#pragma unroll
    for (int rr = 0; rr < 4; rr++) {
      float gr = Gc[16 * rt + 4 * quad + rr];
      lamv[rr] = __expf(gr);
      erv[rr]  = __expf(g63 - gr);
    }
#pragma unroll
    for (int cc = 0; cc < 2; cc++) {
      short4v dpack, depack;
#pragma unroll
      for (int rr = 0; rr < 4; rr++) {
        int row = 16 * rt + 4 * quad + rr;
        float dv = bf2f(Wsb[row * 32 + 16 * cc + lm]) - Yacc[cc][rr];
        Oacc[cc][rr] *= lamv[rr];
        dpack[rr]  = (short)f2bf(dv);
        depack[rr] = (short)f2bf(dv * erv[rr]);
      }
      *(short4v*)&dT [(size_t)(16 * cc + lm) * SD + 16 * rt + 4 * quad] = dpack;
      *(short4v*)&dTe[(size_t)(16 * cc + lm) * SD + 16 * rt + 4 * quad] = depack;
    }
    asm volatile("s_waitcnt lgkmcnt(0)" ::: "memory");
    __builtin_amdgcn_s_barrier();

    // S9 (critical path first): S <- lend*S + K^T @ (e*delta)
    float lend = __expf(g63);
    short8 Be[2][2];
#pragma unroll
    for (int cc = 0; cc < 2; cc++)
#pragma unroll
      for (int kf = 0; kf < 2; kf++)
        Be[cc][kf] = ld76(&dTe[(size_t)(16 * cc + lm) * SD + 8 * quad + 32 * kf]);
#pragma unroll
    for (int dd = 0; dd < 4; dd++) {
      int Dt = 4 * wave + dd;
#pragma unroll
      for (int cc = 0; cc < 2; cc++) {
        f32x4 s = Sacc[dd][cc];
        s[0] *= lend; s[1] *= lend; s[2] *= lend; s[3] *= lend;
#pragma unroll
        for (int kf = 0; kf < 2; kf++) {
          short8 ka = *(const short8*)&Ksb[((size_t)(quad + 4 * kf) * 256 + 16 * Dt + lm) * 8];
          s = __builtin_amdgcn_mfma_f32_16x16x32_bf16(ka, Be[cc][kf], s, 0, 0, 0);
        }
        Sacc[dd][cc] = s;
      }
    }

    // S8: O += P@delta (consumes pfn), store O
#pragma unroll
    for (int cc = 0; cc < 2; cc++) {
#pragma unroll
      for (int kf = 0; kf < 2; kf++) {
        short8 bd = ld76(&dT[(size_t)(16 * cc + lm) * SD + 8 * quad + 32 * kf]);
        Oacc[cc] = __builtin_amdgcn_mfma_f32_16x16x32_bf16(pfn[kf], bd, Oacc[cc], 0, 0, 0);
      }
#pragma unroll
      for (int rr = 0; rr < 4; rr++) {
        int row = 16 * rt + 4 * quad + rr;
        ob[(size_t)(r0 + row) * VDIM_ + 16 * cc + lm] = f2bf(Oacc[cc][rr]);
      }
    }
    __builtin_amdgcn_sched_barrier(0);

    // refill pfn for chunk c+1 (after consumption; after Ks'/Ws' in issue order)
    {
      int cn = (c + 1) & 31;
      const bf16* pc = PgB + (size_t)cn * 4096;
      pfn[0] = *(const short8*)(pc);
      pfn[1] = *(const short8*)(pc + 32);
    }
    gnext = gnn;
    asm volatile("s_waitcnt lgkmcnt(0)" ::: "memory");
    __builtin_amdgcn_s_barrier();      // protect ST/dT/dTe overwrite next iter
  }
}

// ---------------- gated RMSNorm (in place, bf16) ----------------

__global__ __launch_bounds__(256) void gated_rms_kernel(bf16* __restrict__ o,
                                                        const bf16* __restrict__ gate,
                                                        const float* __restrict__ onw) {
  __shared__ float red[4];
  int blk = blockIdx.x;
  int h = blk & 3;
  int bt = blk >> 2;
  size_t base = (size_t)bt * VDIM_ + h * DV_;
  int tid = threadIdx.x;
  float o1 = bf2f(o[base + tid]), o2 = bf2f(o[base + tid + 256]);
  float ss = block_sum256(o1 * o1 + o2 * o2, red);
  float s = rsqrtf(ss * (1.f / DV_) + 1e-5f);
  float g1 = bf2f(gate[base + tid]), g2 = bf2f(gate[base + tid + 256]);
  o[base + tid]       = f2bf(o1 * s * onw[tid] * siluf_(g1));
  o[base + tid + 256] = f2bf(o2 * s * onw[tid + 256] * siluf_(g2));
}

// ---------------- launch ----------------

extern "C" void kernel_launch(void* const* d_in, const int* in_sizes, int n_in,
                              void* d_out, int out_size, void* d_ws, size_t ws_size,
                              hipStream_t stream) {
  const float* x        = (const float*)d_in[0];
  const float* Wq       = (const float*)d_in[1];
  const float* Wk       = (const float*)d_in[2];
  const float* Wv       = (const float*)d_in[3];
  const float* Wa       = (const float*)d_in[4];
  const float* Wb       = (const float*)d_in[5];
  const float* Wg       = (const float*)d_in[6];
  const float* conv_q_w = (const float*)d_in[7];
  const float* conv_k_w = (const float*)d_in[8];
  const float* conv_v_w = (const float*)d_in[9];
  const float* A_log    = (const float*)d_in[10];
  const float* dt_bias  = (const float*)d_in[11];
  const float* o_norm_w = (const float*)d_in[12];
  const float* Wo       = (const float*)d_in[13];
  const float* ln1_w    = (const float*)d_in[14];
  const float* ln1_b    = (const float*)d_in[15];
  const float* ln2_w    = (const float*)d_in[16];
  const float* ln2_b    = (const float*)d_in[17];
  const float* ffn_w1   = (const float*)d_in[18];
  const float* ffn_b1   = (const float*)d_in[19];
  const float* ffn_w2   = (const float*)d_in[20];
  const float* ffn_b2   = (const float*)d_in[21];

  size_t required = (size_t)218 << 20;
  if (ws_size < required) {
    sentinel_kernel<<<(out_size + 255) / 256, 256, 0, stream>>>((float*)d_out, out_size);
    return;
  }

  char* base = (char*)d_ws;
  float* pre    = (float*)(base);                        // 64MB scratch (proj outs)
  bf16*  normed = (bf16*)(base + ((size_t)64  << 20));   // 16MB
  bf16*  q16    = (bf16*)(base + ((size_t)80  << 20));   // 16MB
  bf16*  k16    = (bf16*)(base + ((size_t)96  << 20));   // 16MB
  bf16*  v16    = (bf16*)(base + ((size_t)112 << 20));   // 32MB
  bf16*  g16    = (bf16*)(base + ((size_t)144 << 20));   // 32MB
  bf16*  o16    = (bf16*)(base + ((size_t)176 << 20));   // 32MB
  bf16*  wslot  = (bf16*)(base + ((size_t)208 << 20));   // 8MB JIT weight slot
  float* gvec   = (float*)(base + ((size_t)216 << 20));  // 128KB
  float* bvec   = gvec + (size_t)BT_ * H_;               // 128KB
  float* gsc    = (float*)(base + ((size_t)217 << 20));  // 128KB
  // delta-phase buffers (pre region + normed region, dead after ab_kernel):
  bf16*  Yg     = (bf16*)(base);                         // 16MB  [0,16)
  bf16*  Wgb    = (bf16*)(base + ((size_t)16 << 20));    // 32MB  [16,48)
  bf16*  Pg     = (bf16*)(base + ((size_t)48 << 20));    // 4MB   [48,52)
  bf16*  kTg    = (bf16*)(base + ((size_t)52 << 20));    // 16MB  [52,68)
  // later reuses:
  float* x2     = (float*)(base);                        // 32MB (after delta)
  bf16*  hb16   = (bf16*)(base + ((size_t)64  << 20));
  bf16*  ffn1   = (bf16*)(base + ((size_t)80  << 20));

  // 1) LN1 -> bf16
  ln_kernel<<<BT_, 256, 0, stream>>>(x, ln1_w, ln1_b, normed);

  // 2) projections + convs
  convT_kernel<<<dim3(KDIM_ / 32, D_ / 32), 256, 0, stream>>>(Wq, wslot, D_, KDIM_);
  gemm_mfma<float><<<dim3(KDIM_ / 128, BT_ / 128), 256, 0, stream>>>(normed, wslot, nullptr, nullptr, pre, KDIM_, D_, 0);
  conv_qk_kernel<<<BT_ * H_, 256, 0, stream>>>(pre, conv_q_w, q16, 0.0625f);

  convT_kernel<<<dim3(KDIM_ / 32, D_ / 32), 256, 0, stream>>>(Wk, wslot, D_, KDIM_);
  gemm_mfma<float><<<dim3(KDIM_ / 128, BT_ / 128), 256, 0, stream>>>(normed, wslot, nullptr, nullptr, pre, KDIM_, D_, 0);
  conv_qk_kernel<<<BT_ * H_, 256, 0, stream>>>(pre, conv_k_w, k16, 1.0f);

  convT_kernel<<<dim3(VDIM_ / 32, D_ / 32), 256, 0, stream>>>(Wv, wslot, D_, VDIM_);
  gemm_mfma<float><<<dim3(VDIM_ / 128, BT_ / 128), 256, 0, stream>>>(normed, wslot, nullptr, nullptr, pre, VDIM_, D_, 0);
  conv_v_kernel<<<(BT_ * VDIM_) / 256, 256, 0, stream>>>(pre, conv_v_w, v16);

  convT_kernel<<<dim3(VDIM_ / 32, D_ / 32), 256, 0, stream>>>(Wg, wslot, D_, VDIM_);
  gemm_mfma<bf16><<<dim3(VDIM_ / 128, BT_ / 128), 256, 0, stream>>>(normed, wslot, nullptr, nullptr, g16, VDIM_, D_, 0);

  ab_kernel<<<BT_, 256, 0, stream>>>(normed, Wa, Wb, A_log, dt_bias, gvec, bvec);

  // 3) delta rule: kT transpose (chunk-major) + phase 1 + pipelined phase 2
  kT_kernel<<<dim3(T_ / 32, DK_ / 32, 16), 256, 0, stream>>>(k16, kTg);
  delta_p1<<<512, 256, 0, stream>>>(q16, k16, v16, gvec, bvec, Pg, Wgb, Yg, gsc);
  delta_p2<<<256, 256, 0, stream>>>(q16, kTg, Wgb, Yg, Pg, gsc, o16);

  // 4) gated RMSNorm (in place)
  gated_rms_kernel<<<BT_ * H_, 256, 0, stream>>>(o16, g16, o_norm_w);

  // 5) x2 = x + o @ Wo
  convT_kernel<<<dim3(D_ / 32, VDIM_ / 32), 256, 0, stream>>>(Wo, wslot, VDIM_, D_);
  gemm_mfma<float><<<dim3(D_ / 128, BT_ / 128), 256, 0, stream>>>(o16, wslot, nullptr, x, x2, D_, VDIM_, 4);

  // 6) LN2 -> bf16
  ln_kernel<<<BT_, 256, 0, stream>>>(x2, ln2_w, ln2_b, hb16);

  // 7) FFN
  convT_kernel<<<dim3(FFN_ / 32, D_ / 32), 256, 0, stream>>>(ffn_w1, wslot, D_, FFN_);
  gemm_mfma<bf16><<<dim3(FFN_ / 128, BT_ / 128), 256, 0, stream>>>(hb16, wslot, ffn_b1, nullptr, ffn1, FFN_, D_, 1 | 2);
  convT_kernel<<<dim3(D_ / 32, FFN_ / 32), 256, 0, stream>>>(ffn_w2, wslot, FFN_, D_);
  gemm_mfma<float><<<dim3(D_ / 128, BT_ / 128), 256, 0, stream>>>(ffn1, wslot, ffn_b2, x2, (float*)d_out, D_, FFN_, 1 | 4);
}

// Round 9
// 1028.315 us; speedup vs baseline: 1.2309x; 1.0162x over previous
//
#include <hip/hip_runtime.h>
#include <math.h>

#define B_    4
#define T_    2048
#define D_    1024
#define H_    4
#define DK_   256
#define DV_   512
#define KDIM_ 1024
#define VDIM_ 2048
#define FFN_  4096
#define BT_   8192   // B_*T_

typedef unsigned short bf16;
typedef __attribute__((ext_vector_type(8))) short short8;   // MFMA A/B frag (8 bf16)
typedef __attribute__((ext_vector_type(4))) short short4v;  // 4 bf16
typedef __attribute__((ext_vector_type(4))) float f32x4;    // MFMA C/D frag

// ---------------- helpers ----------------

__device__ __forceinline__ float sigmoidf_(float x) { return 1.f / (1.f + expf(-x)); }
__device__ __forceinline__ float siluf_(float x)    { return x / (1.f + expf(-x)); }
__device__ __forceinline__ float geluf_(float x)    { return 0.5f * x * (1.f + erff(x * 0.70710678118654752f)); }

__device__ __forceinline__ float bf2f(bf16 u) {
  union { unsigned int i; float f; } c; c.i = (unsigned int)u << 16; return c.f;
}
__device__ __forceinline__ bf16 f2bf(float f) {
  union { unsigned int i; float f; } c; c.f = f;
  unsigned int r = c.i + 0x7fffu + ((c.i >> 16) & 1u);   // RNE
  return (bf16)(r >> 16);
}

// async global->LDS, 16B per lane
__device__ __forceinline__ void gload16(const bf16* g, bf16* l) {
  __builtin_amdgcn_global_load_lds((__attribute__((address_space(1))) const void*)g,
                                   (__attribute__((address_space(3))) void*)l, 16, 0, 0);
}

__device__ __forceinline__ void storeC(float* p, float v) { *p = v; }
__device__ __forceinline__ void storeC(bf16* p, float v)  { *p = f2bf(v); }

// load 8 bf16 from an 8B-aligned LDS address as two b64s
__device__ __forceinline__ short8 ld76(const bf16* p) {
  union { short8 v; short4v h[2]; } u;
  u.h[0] = *(const short4v*)p;
  u.h[1] = *(const short4v*)(p + 4);
  return u.v;
}
// pack f32x4 -> 4 bf16, 8B store
__device__ __forceinline__ void st4bf(bf16* p, f32x4 v) {
  short4v o;
  o[0] = (short)f2bf(v[0]); o[1] = (short)f2bf(v[1]);
  o[2] = (short)f2bf(v[2]); o[3] = (short)f2bf(v[3]);
  *(short4v*)p = o;
}

__device__ __forceinline__ float block_sum256(float v, float* red) {
#pragma unroll
  for (int off = 32; off; off >>= 1) v += __shfl_xor(v, off, 64);
  __syncthreads();
  if ((threadIdx.x & 63) == 0) red[threadIdx.x >> 6] = v;
  __syncthreads();
  return red[0] + red[1] + red[2] + red[3];
}

// ---------------- diagnostic sentinel (ws too small) ----------------

__global__ __launch_bounds__(256) void sentinel_kernel(float* out, int n) {
  int i = blockIdx.x * 256 + threadIdx.x;
  if (i < n) out[i] = 12345.0f;
}

// ---------------- LayerNorm -> bf16 ----------------

__global__ __launch_bounds__(256) void ln_kernel(const float* __restrict__ x,
                                                 const float* __restrict__ w,
                                                 const float* __restrict__ b,
                                                 bf16* __restrict__ y) {
  __shared__ float red[4];
  int row = blockIdx.x;
  const float* xr = x + (size_t)row * D_;
  float xv[4];
  float s = 0.f;
#pragma unroll
  for (int i = 0; i < 4; i++) { xv[i] = xr[threadIdx.x + 256 * i]; s += xv[i]; }
  float mean = block_sum256(s, red) * (1.f / D_);
  float s2 = 0.f;
#pragma unroll
  for (int i = 0; i < 4; i++) { float d = xv[i] - mean; s2 += d * d; }
  float var = block_sum256(s2, red) * (1.f / D_);
  float inv = rsqrtf(var + 1e-5f);
  bf16* yr = y + (size_t)row * D_;
#pragma unroll
  for (int i = 0; i < 4; i++) {
    int c = threadIdx.x + 256 * i;
    yr[c] = f2bf((xv[i] - mean) * inv * w[c] + b[c]);
  }
}

// ---------------- weight convert+transpose: fp32 [K][N] -> bf16 [N][K] ----------------

__global__ __launch_bounds__(256) void convT_kernel(const float* __restrict__ src,
                                                    bf16* __restrict__ dst,
                                                    int K, int N) {
  __shared__ float t[32][33];
  int n0 = blockIdx.x * 32, k0 = blockIdx.y * 32;
  int tx = threadIdx.x & 31, ty = threadIdx.x >> 5;
#pragma unroll
  for (int i = 0; i < 4; i++)
    t[ty + i * 8][tx] = src[(size_t)(k0 + ty + i * 8) * N + n0 + tx];
  __syncthreads();
#pragma unroll
  for (int i = 0; i < 4; i++)
    dst[(size_t)(n0 + ty + i * 8) * K + k0 + tx] = f2bf(t[tx][ty + i * 8]);
}

// ---- k transpose per head, CHUNK-MAJOR: k16 [b][t][h*DK+dk] ->
// kTc [bh][c=t>>6][tb=(t>>3)&7][dk][te=t&7]  (contiguous 32KB per chunk,
// exactly the LDS layout delta_p2 consumes -> fully coalesced gload_lds)

__global__ __launch_bounds__(256) void kT_kernel(const bf16* __restrict__ k16,
                                                 bf16* __restrict__ kT) {
  __shared__ bf16 tile[32][34];
  int t0 = blockIdx.x * 32;
  int d0 = blockIdx.y * 32;
  int bh = blockIdx.z;
  int b = bh >> 2, h = bh & 3;
  int tx = threadIdx.x & 31, ty = threadIdx.x >> 5;
#pragma unroll
  for (int i = 0; i < 4; i++)
    tile[ty + 8 * i][tx] = k16[(size_t)(b * T_ + t0 + ty + 8 * i) * KDIM_ + h * DK_ + d0 + tx];
  __syncthreads();
  int t = t0 + tx;
  int c = t >> 6, tb = (t >> 3) & 7, te = t & 7;
  size_t base = ((size_t)(bh * 32 + c) * 8 + tb) * 2048 + te;
#pragma unroll
  for (int i = 0; i < 4; i++)
    kT[base + (size_t)(d0 + ty + 8 * i) * 8] = tile[tx][ty + 8 * i];
}

// ---------------- bf16 MFMA GEMM, 128x128 tile (R8 structure, kept for N=1024 GEMMs) ----------------

template <typename TC>
__global__ __launch_bounds__(256) void gemm_mfma(const bf16* __restrict__ A,
                                                 const bf16* __restrict__ Bt,
                                                 const float* __restrict__ bias,
                                                 const float* __restrict__ res,
                                                 TC* __restrict__ C,
                                                 int N, int K, int flags) {
  __shared__ __align__(16) bf16 As[3][128 * 32];
  __shared__ __align__(16) bf16 Bs[3][128 * 32];
  int tid = threadIdx.x;
  int wave = tid >> 6, lane = tid & 63;

  int nbx = gridDim.x;
  int id  = blockIdx.y * nbx + blockIdx.x;
  int xcd = id & 7;
  int g   = id >> 3;
  int bx  = g % nbx;
  int by  = xcd + 8 * (g / nbx);
  int bm = by * 128, bn = bx * 128;

  int wm = (wave >> 1) * 64, wn = (wave & 1) * 64;
  int lm = lane & 15;
  int quad = lane >> 4;

  f32x4 acc[4][4];
#pragma unroll
  for (int i = 0; i < 4; i++)
#pragma unroll
    for (int j = 0; j < 4; j++) acc[i][j] = (f32x4){0.f, 0.f, 0.f, 0.f};

  int srow = wave * 32 + (lane >> 2);
  int scol = (lane & 3) * 8;
  const bf16* ag = A  + (size_t)(bm + srow) * K + scol;
  const bf16* bg = Bt + (size_t)(bn + srow) * K + scol;
  const size_t gstep = (size_t)16 * K;
  int woff = wave * 1024;

  int nt = K >> 5;
#pragma unroll
  for (int p = 0; p < 3; p++) {
    int kt = (p < nt) ? p : nt - 1;
    size_t k0 = (size_t)kt << 5;
    gload16(ag + k0,         &As[p][woff]);
    gload16(ag + k0 + gstep, &As[p][woff + 512]);
    gload16(bg + k0,         &Bs[p][woff]);
    gload16(bg + k0 + gstep, &Bs[p][woff + 512]);
  }
  __builtin_amdgcn_sched_barrier(0);

  int cur = 0;
  for (int i = 0; i < nt; i++) {
    asm volatile("s_waitcnt vmcnt(8)" ::: "memory");
    __builtin_amdgcn_s_barrier();
    __builtin_amdgcn_sched_barrier(0);

    short8 af[4], bf[4];
#pragma unroll
    for (int i4 = 0; i4 < 4; i4++)
      af[i4] = *(const short8*)&As[cur][(wm + i4 * 16 + lm) * 32 + quad * 8];
#pragma unroll
    for (int j4 = 0; j4 < 4; j4++)
      bf[j4] = *(const short8*)&Bs[cur][(wn + j4 * 16 + lm) * 32 + quad * 8];
#pragma unroll
    for (int i4 = 0; i4 < 4; i4++)
#pragma unroll
      for (int j4 = 0; j4 < 4; j4++)
        acc[i4][j4] = __builtin_amdgcn_mfma_f32_16x16x32_bf16(af[i4], bf[j4], acc[i4][j4], 0, 0, 0);

    asm volatile("s_waitcnt lgkmcnt(0)" ::: "memory");
    __builtin_amdgcn_s_barrier();
    __builtin_amdgcn_sched_barrier(0);

    {
      int kt = (i + 3 < nt) ? i + 3 : nt - 1;
      size_t k0 = (size_t)kt << 5;
      gload16(ag + k0,         &As[cur][woff]);
      gload16(ag + k0 + gstep, &As[cur][woff + 512]);
      gload16(bg + k0,         &Bs[cur][woff]);
      gload16(bg + k0 + gstep, &Bs[cur][woff + 512]);
    }
    __builtin_amdgcn_sched_barrier(0);

    cur++; if (cur == 3) cur = 0;
  }

#pragma unroll
  for (int i = 0; i < 4; i++) {
    int row0 = bm + wm + i * 16 + quad * 4;
#pragma unroll
    for (int j = 0; j < 4; j++) {
      int col = bn + wn + j * 16 + lm;
      float badd = (flags & 1) ? bias[col] : 0.f;
#pragma unroll
      for (int r = 0; r < 4; r++) {
        float v = acc[i][j][r] + badd;
        if (flags & 2) v = geluf_(v);
        if (flags & 4) v += res[(size_t)(row0 + r) * N + col];
        storeC(&C[(size_t)(row0 + r) * N + col], v);
      }
    }
  }
}

// ---------------- bf16 MFMA GEMM, 256x256 tile, 8 waves (R9) ----------------
// 2x arithmetic intensity (128 FLOP/staged-byte), BK=64, LDS double-buffer
// with COUNTED vmcnt (8 gload16/wave/tile; wait vmcnt(8) covers own slice,
// barrier completes the proof), G4 XOR-swizzle byte^=((row&7)<<4) applied as
// inverse-swizzled gload_lds SOURCE + swizzled ds_read col (rule #21:
// both-sides-or-neither), XCD-locality block remap.

template <typename TC>
__global__ __launch_bounds__(512, 1) void gemm256(const bf16* __restrict__ A,
                                                  const bf16* __restrict__ Bt,
                                                  const float* __restrict__ bias,
                                                  const float* __restrict__ res,
                                                  TC* __restrict__ C,
                                                  int N, int K, int flags) {
  __shared__ __align__(16) bf16 As[2][256 * 64];   // 32KB each -> 128KB total
  __shared__ __align__(16) bf16 Bs[2][256 * 64];
  int tid = threadIdx.x;
  int wave = tid >> 6, lane = tid & 63;
  int lm = lane & 15, quad = lane >> 4;
  int wm8 = wave >> 2, wn8 = wave & 3;   // 2 M-halves x 4 N-quarters

  // XCD-locality remap (bijective for 128/256/512-block grids)
  int nbx = gridDim.x;
  int id  = blockIdx.y * nbx + blockIdx.x;
  int xcd = id & 7;
  int g   = id >> 3;
  int bx  = g % nbx;
  int by  = xcd + 8 * (g / nbx);
  int bm = by * 256, bn = bx * 256;

  f32x4 acc[8][4];
#pragma unroll
  for (int i = 0; i < 8; i++)
#pragma unroll
    for (int j = 0; j < 4; j++) acc[i][j] = (f32x4){0.f, 0.f, 0.f, 0.f};

  // staging: round r covers rows r*64..r*64+63; thread t -> row r*64+(t>>3),
  // source col inverse-swizzled so linear LDS dest holds swizzled layout
  int srow = tid >> 3;                               // 0..63
  int scol = ((tid & 7) ^ (srow & 7)) * 8;           // inverse swizzle
  const bf16* agb = A  + (size_t)(bm + srow) * K + scol;
  const bf16* bgb = Bt + (size_t)(bn + srow) * K + scol;
  const size_t rstep = (size_t)64 * K;
  int ldst = tid * 8;                                // + r*4096 per round

  int nt = K >> 6;
  // prologue: stage tiles 0 and 1 (8 gload16/wave each)
#pragma unroll
  for (int p = 0; p < 2; p++) {
    size_t k0 = (size_t)p << 6;
#pragma unroll
    for (int r = 0; r < 4; r++) {
      gload16(agb + r * rstep + k0, (bf16*)As[p] + r * 4096 + ldst);
      gload16(bgb + r * rstep + k0, (bf16*)Bs[p] + r * 4096 + ldst);
    }
  }
  __builtin_amdgcn_sched_barrier(0);

  int cur = 0;
  for (int i = 0; i < nt; i++) {
    // tile i staged when <=8 outstanding (tile i+1's 8 stay in flight)
    asm volatile("s_waitcnt vmcnt(8)" ::: "memory");
    __builtin_amdgcn_s_barrier();
    __builtin_amdgcn_sched_barrier(0);

    const bf16* Ab = As[cur];
    const bf16* Bb = Bs[cur];
#pragma unroll
    for (int kk = 0; kk < 2; kk++) {
      int colr = (8 * quad + 32 * kk) ^ ((lm & 7) << 3);   // swizzled read col
      short8 af[8], bfr[4];
#pragma unroll
      for (int i8 = 0; i8 < 8; i8++)
        af[i8] = *(const short8*)&Ab[(wm8 * 128 + i8 * 16 + lm) * 64 + colr];
#pragma unroll
      for (int j4 = 0; j4 < 4; j4++)
        bfr[j4] = *(const short8*)&Bb[(wn8 * 64 + j4 * 16 + lm) * 64 + colr];
#pragma unroll
      for (int i8 = 0; i8 < 8; i8++)
#pragma unroll
        for (int j4 = 0; j4 < 4; j4++)
          acc[i8][j4] = __builtin_amdgcn_mfma_f32_16x16x32_bf16(af[i8], bfr[j4], acc[i8][j4], 0, 0, 0);
    }

    asm volatile("s_waitcnt lgkmcnt(0)" ::: "memory");
    __builtin_amdgcn_s_barrier();     // all waves done reading buf[cur]
    __builtin_amdgcn_sched_barrier(0);

    // stage tile i+2 into buf[cur] (clamped tail keeps ledger uniform)
    {
      int kt = (i + 2 < nt) ? i + 2 : nt - 1;
      size_t k0 = (size_t)kt << 6;
#pragma unroll
      for (int r = 0; r < 4; r++) {
        gload16(agb + r * rstep + k0, (bf16*)As[cur] + r * 4096 + ldst);
        gload16(bgb + r * rstep + k0, (bf16*)Bs[cur] + r * 4096 + ldst);
      }
    }
    __builtin_amdgcn_sched_barrier(0);
    cur ^= 1;
  }

#pragma unroll
  for (int i8 = 0; i8 < 8; i8++) {
    int row0 = bm + wm8 * 128 + i8 * 16 + quad * 4;
#pragma unroll
    for (int j4 = 0; j4 < 4; j4++) {
      int col = bn + wn8 * 64 + j4 * 16 + lm;
      float badd = (flags & 1) ? bias[col] : 0.f;
#pragma unroll
      for (int r = 0; r < 4; r++) {
        float v = acc[i8][j4][r] + badd;
        if (flags & 2) v = geluf_(v);
        if (flags & 4) v += res[(size_t)(row0 + r) * N + col];
        storeC(&C[(size_t)(row0 + r) * N + col], v);
      }
    }
  }
}

// ---------------- fused Wa/Wb projections -> g, beta ----------------

__global__ __launch_bounds__(256) void ab_kernel(const bf16* __restrict__ normed,
                                                 const float* __restrict__ Wa,
                                                 const float* __restrict__ Wb,
                                                 const float* __restrict__ A_log,
                                                 const float* __restrict__ dt_bias,
                                                 float* __restrict__ g,
                                                 float* __restrict__ beta) {
  __shared__ float red[4];
  int row = blockIdx.x;
  const bf16* xr = normed + (size_t)row * D_;
  float aacc[4] = {}, bacc[4] = {};
#pragma unroll
  for (int i = 0; i < 4; i++) {
    int d = threadIdx.x + 256 * i;
    float xv = bf2f(xr[d]);
    float4 wa = *(const float4*)&Wa[d * 4];
    float4 wb = *(const float4*)&Wb[d * 4];
    aacc[0] += xv * wa.x; aacc[1] += xv * wa.y; aacc[2] += xv * wa.z; aacc[3] += xv * wa.w;
    bacc[0] += xv * wb.x; bacc[1] += xv * wb.y; bacc[2] += xv * wb.z; bacc[3] += xv * wb.w;
  }
  float sa[4], sb[4];
#pragma unroll
  for (int h = 0; h < 4; h++) {
    sa[h] = block_sum256(aacc[h], red);
    sb[h] = block_sum256(bacc[h], red);
  }
  if (threadIdx.x < 4) {
    int h = threadIdx.x;
    float xa = sa[h] + dt_bias[h];
    float sp = (xa > 20.f) ? xa : log1pf(expf(xa));
    g[row * 4 + h] = -expf(A_log[h]) * sp;
    beta[row * 4 + h] = sigmoidf_(sb[h]);
  }
}

// ---------------- causal conv(4) + SiLU (+ L2 norm for q/k) ----------------

__global__ __launch_bounds__(256) void conv_qk_kernel(const float* __restrict__ pre,
                                                      const float* __restrict__ convw,
                                                      bf16* __restrict__ out,
                                                      float scale) {
  __shared__ float red[4];
  int blk = blockIdx.x;
  int h = blk & 3;
  int bt = blk >> 2;
  int t = bt & (T_ - 1);
  int c = h * DK_ + threadIdx.x;
  float y = 0.f;
#pragma unroll
  for (int i = 0; i < 4; i++) {
    int tt = t + i - 3;
    if (tt >= 0) y += pre[(size_t)(bt + i - 3) * KDIM_ + c] * convw[c * 4 + i];
  }
  y = siluf_(y);
  float ss = block_sum256(y * y, red);
  y *= rsqrtf(ss + 1e-6f) * scale;
  out[(size_t)bt * KDIM_ + c] = f2bf(y);
}

__global__ __launch_bounds__(256) void conv_v_kernel(const float* __restrict__ pre,
                                                     const float* __restrict__ convw,
                                                     bf16* __restrict__ out) {
  int idx = blockIdx.x * 256 + threadIdx.x;
  int c = idx & (VDIM_ - 1);
  int bt = idx >> 11;
  int t = bt & (T_ - 1);
  float y = 0.f;
#pragma unroll
  for (int i = 0; i < 4; i++) {
    int tt = t + i - 3;
    if (tt >= 0) y += pre[(size_t)(bt + i - 3) * VDIM_ + c] * convw[c * 4 + i];
  }
  out[idx] = f2bf(siluf_(y));
}

// ---------------- delta rule phase 1 (parallel over bh x chunk) ----------------
// R6: ONE forward-substitution solve (RHS=I) gives Minv = (I+A)^{-1}; each of
// the 12 column groups is then a pure 64x64x64 MFMA GEMM X = Minv @ U.

#define SP  76
#define UBP 72
#define MTP 68

__global__ __launch_bounds__(256, 2) void delta_p1(const bf16* __restrict__ q,
                                                   const bf16* __restrict__ k,
                                                   const bf16* __restrict__ v,
                                                   const float* __restrict__ g,
                                                   const float* __restrict__ beta,
                                                   bf16* __restrict__ Pg,
                                                   bf16* __restrict__ Wg,
                                                   bf16* __restrict__ Yg,
                                                   float* __restrict__ gsc) {
  __shared__ bf16 Abf[64 * SP];
  __shared__ bf16 DTg[64 * SP];                 // Minv col-major [col][row] (solve)
  __shared__ __align__(8) bf16 MT[64 * MTP];    // Minv row-major [row][col]
  __shared__ __align__(8) bf16 Ubt[64 * UBP];   // U^T per group [col][t]
  __shared__ float UbJ[16 * 64];                // current block-row RHS (f32)
  __shared__ float Gc[64], Lm[64], Bt[64];

  int blk = blockIdx.x;
  int c = blk & 31, bh = blk >> 5;
  int b = bh >> 2, h = bh & 3;
  int tid = threadIdx.x;
  int wave = tid >> 6, lane = tid & 63;
  int lm = lane & 15, quad = lane >> 4;
  int r0 = c * 64;

  const bf16* kb = k + (size_t)b * T_ * KDIM_ + h * DK_;
  const bf16* qb = q + (size_t)b * T_ * KDIM_ + h * DK_;
  const bf16* vb = v + (size_t)b * T_ * VDIM_ + h * DV_;
  const float* gbp = g    + (size_t)b * T_ * H_ + h;
  const float* bbp = beta + (size_t)b * T_ * H_ + h;
  size_t cb = (size_t)bh * 32 + c;
  bf16* PgC = Pg + cb * 4096;
  bf16* WgC = Wg + cb * 64 * 512;
  bf16* YgC = Yg + cb * 64 * 256;

  // (a) cumsum of g -> Gc, Lam, beta
  if (wave == 0) {
    float gv = gbp[(size_t)(r0 + lane) * H_];
    float bv = bbp[(size_t)(r0 + lane) * H_];
#pragma unroll
    for (int d = 1; d < 64; d <<= 1) {
      float nn = __shfl_up(gv, (unsigned)d, 64);
      if (lane >= d) gv += nn;
    }
    Gc[lane] = gv; Lm[lane] = expf(gv); Bt[lane] = bv;
    gsc[cb * 64 + lane] = gv;
  }
  // zero DTg while wave0 does cumsum
  {
    int* dz = (int*)DTg;
#pragma unroll
    for (int i = 0; i < 10; i++) {
      int idx = tid + 256 * i;
      if (idx < 64 * SP / 2) dz[idx] = 0;
    }
  }
  __syncthreads();

  // (b,c) KK^T -> Abf, QK^T -> Pg
  {
    f32x4 akk[4], aqk[4];
#pragma unroll
    for (int j = 0; j < 4; j++) { akk[j] = (f32x4){0.f,0.f,0.f,0.f}; aqk[j] = (f32x4){0.f,0.f,0.f,0.f}; }
    const bf16* krow = kb + (size_t)(r0 + 16 * wave + lm) * KDIM_;
    const bf16* qrow = qb + (size_t)(r0 + 16 * wave + lm) * KDIM_;
#pragma unroll
    for (int ks = 0; ks < 8; ks++) {
      short8 ak = *(const short8*)(krow + 8 * quad + 32 * ks);
      short8 aq = *(const short8*)(qrow + 8 * quad + 32 * ks);
#pragma unroll
      for (int j = 0; j < 4; j++) {
        short8 bk = *(const short8*)(kb + (size_t)(r0 + 16 * j + lm) * KDIM_ + 8 * quad + 32 * ks);
        akk[j] = __builtin_amdgcn_mfma_f32_16x16x32_bf16(ak, bk, akk[j], 0, 0, 0);
        aqk[j] = __builtin_amdgcn_mfma_f32_16x16x32_bf16(aq, bk, aqk[j], 0, 0, 0);
      }
    }
    float gi[4], bi[4];
#pragma unroll
    for (int r = 0; r < 4; r++) {
      int i = 16 * wave + 4 * quad + r;
      gi[r] = Gc[i]; bi[r] = Bt[i];
    }
#pragma unroll
    for (int j = 0; j < 4; j++) {
      int s = 16 * j + lm;
      float gs = Gc[s];
#pragma unroll
      for (int r = 0; r < 4; r++) {
        int i = 16 * wave + 4 * quad + r;
        float dec = expf(gi[r] - gs);
        Abf[(size_t)i * SP + s] = f2bf((s < i)  ? bi[r] * dec * akk[j][r] : 0.f);
        PgC[(size_t)i * 64 + s] = f2bf((s <= i) ? dec * aqk[j][r]        : 0.f);
      }
    }
  }
  __syncthreads();   // Abf + DTg(zero) ready

  // ---- Phase B: Minv = (I+A)^{-1}  (ONE forward-substitution pass, RHS=I) ----
#pragma unroll 1
  for (int j = 0; j < 4; j++) {
    // init UbJ = I block-row slice
#pragma unroll
    for (int i = 0; i < 4; i++) {
      int idx = tid + 256 * i;          // 1024 entries
      int row = idx >> 6, col = idx & 63;
      UbJ[row * 64 + col] = (col == 16 * j + row) ? 1.f : 0.f;
    }
    __syncthreads();
    if (j > 0) {
      f32x4 racc = (f32x4){0.f, 0.f, 0.f, 0.f};
      int nk = (j == 3) ? 2 : 1;
      for (int ks = 0; ks < nk; ks++) {
        short8 aa = ld76(&Abf[(size_t)(16 * j + lm) * SP + 8 * quad + 32 * ks]);
        short8 bd = ld76(&DTg[(size_t)(16 * wave + lm) * SP + 8 * quad + 32 * ks]);
        racc = __builtin_amdgcn_mfma_f32_16x16x32_bf16(aa, bd, racc, 0, 0, 0);
      }
#pragma unroll
      for (int r = 0; r < 4; r++)
        UbJ[(4 * quad + r) * 64 + 16 * wave + lm] -= racc[r];
      __syncthreads();
    }
    if (wave == 0) {
      int tl = lane & 15, sg = lane >> 4;
      short4v ab4 = *(const short4v*)&Abf[(size_t)(16 * j + tl) * SP + 16 * j + 4 * sg];
      float av[4];
      av[0] = bf2f((bf16)ab4[0]); av[1] = bf2f((bf16)ab4[1]);
      av[2] = bf2f((bf16)ab4[2]); av[3] = bf2f((bf16)ab4[3]);
      float d[16];
#pragma unroll
      for (int t = 0; t < 16; t++) {
        float val = UbJ[t * 64 + lane];
#pragma unroll
        for (int s = 0; s < t; s++) {
          float ats = __shfl(av[s & 3], t + 16 * (s >> 2), 64);
          val -= ats * d[s];
        }
        d[t] = val;
        bf16 vb16 = f2bf(val);
        DTg[(size_t)lane * SP + 16 * j + t] = vb16;   // col-major (solve B-reads)
        MT [(size_t)(16 * j + t) * MTP + lane] = vb16; // row-major (group GEMMs)
      }
    }
    __syncthreads();
  }

  // ---- Phase C: 12 group GEMMs  X = Minv @ U, stored straight to Wg/Yg ----
  // grp 0..7 -> W (RHS beta*V), grp 8..11 -> Y (RHS beta*Lam*K)
  int cg = 16 * wave + lm;
#pragma unroll 1
  for (int grp = 0; grp < 12; grp++) {
    // fill Ubt[cg][t] = U^T (bf16); entry barrier was end of Phase B / prev grp
#pragma unroll
    for (int ti = 0; ti < 4; ti++) {
      short4v up;
#pragma unroll
      for (int r = 0; r < 4; r++) {
        int t = 16 * ti + 4 * quad + r;
        float val;
        if (grp < 8) val = Bt[t] * bf2f(vb[(size_t)(r0 + t) * VDIM_ + grp * 64 + cg]);
        else         val = Bt[t] * Lm[t] * bf2f(kb[(size_t)(r0 + t) * KDIM_ + (grp - 8) * 64 + cg]);
        up[r] = (short)f2bf(val);
      }
      *(short4v*)&Ubt[(size_t)cg * UBP + 16 * ti + 4 * quad] = up;
    }
    asm volatile("s_waitcnt lgkmcnt(0)" ::: "memory");
    __builtin_amdgcn_s_barrier();

    // D[t][c] = sum_s Minv[t][s] * U[s][c];  A = MT rows (t), B = Ubt rows (c)
    f32x4 racc[4];
#pragma unroll
    for (int jt = 0; jt < 4; jt++) racc[jt] = (f32x4){0.f, 0.f, 0.f, 0.f};
#pragma unroll
    for (int ks = 0; ks < 2; ks++) {
      short8 aM = ld76(&MT[(size_t)(16 * wave + lm) * MTP + 8 * quad + 32 * ks]);
#pragma unroll
      for (int jt = 0; jt < 4; jt++) {
        short8 bU = ld76(&Ubt[(size_t)(16 * jt + lm) * UBP + 8 * quad + 32 * ks]);
        racc[jt] = __builtin_amdgcn_mfma_f32_16x16x32_bf16(aM, bU, racc[jt], 0, 0, 0);
      }
    }
    // store: t = 16*wave + 4*quad + rr, c = 16*jt + lm
#pragma unroll
    for (int jt = 0; jt < 4; jt++) {
#pragma unroll
      for (int rr = 0; rr < 4; rr++) {
        int t = 16 * wave + 4 * quad + rr;
        int cc = 16 * jt + lm;
        if (grp < 8) WgC[(size_t)t * 512 + grp * 64 + cc]       = f2bf(racc[jt][rr]);
        else         YgC[(size_t)t * 256 + (grp - 8) * 64 + cc] = f2bf(racc[jt][rr]);
      }
    }
    asm volatile("s_waitcnt lgkmcnt(0)" ::: "memory");
    __builtin_amdgcn_s_barrier();   // protect Ubt overwrite next group
  }
}

// ---------------- delta rule phase 2 (unchanged from R5) ----------------

#define SP2 264
#define SD  72

__global__ __launch_bounds__(256, 1) void delta_p2(const bf16* __restrict__ q,
                                                   const bf16* __restrict__ kT,
                                                   const bf16* __restrict__ Wg,
                                                   const bf16* __restrict__ Yg,
                                                   const bf16* __restrict__ Pg,
                                                   const float* __restrict__ gsc,
                                                   bf16* __restrict__ o) {
  __shared__ __align__(16) bf16 ST[32 * SP2];       // S^T [v][dk] bf16
  __shared__ __align__(16) bf16 dT[32 * SD];        // delta^T [v][t]
  __shared__ __align__(16) bf16 dTe[32 * SD];       // (e*delta)^T [v][t]
  __shared__ float Gc[64];
  __shared__ __align__(16) bf16 Ks[2][8 * 256 * 8]; // kT chunk (dbuf), [tb][dk][te]
  __shared__ __align__(16) bf16 Ws[2][64 * 32];     // W slab [t][32 cols] (dbuf)

  int blk = blockIdx.x;
  int bh = blk & 15, vs = blk >> 4;    // XCD-local: blk%8 == bh%8 for all vs
  int b = bh >> 2, h = bh & 3;
  int tid = threadIdx.x;
  int wave = tid >> 6, lane = tid & 63;
  int lm = lane & 15, quad = lane >> 4;
  int rt = wave;                       // row-tile (t rows 16rt..16rt+15)
  int v0 = vs * 32;

  const bf16* qb  = q  + (size_t)b * T_ * KDIM_ + h * DK_;
  const bf16* kTb = kT + (size_t)bh * 32 * 16384;   // chunk-major base
  const bf16* WgB = Wg + (size_t)bh * 32 * 32768 + (size_t)(tid >> 2) * 512 + v0 + (tid & 3) * 8;
  const bf16* PgB = Pg + (size_t)bh * 32 * 4096 + (size_t)(16 * rt + lm) * 64 + 8 * quad;
  bf16*       ob  = o  + (size_t)b * T_ * VDIM_ + h * DV_ + v0;

  f32x4 Sacc[4][2];                    // dk-tile (4*wave+dd) x v-col-tile cc
#pragma unroll
  for (int dd = 0; dd < 4; dd++)
#pragma unroll
    for (int cc = 0; cc < 2; cc++) Sacc[dd][cc] = (f32x4){0.f, 0.f, 0.f, 0.f};

  // ---- prologue: stage chunk 0 (Ks/Ws async; P/q/Y/gsc regs) ----
#pragma unroll
  for (int i = 0; i < 8; i++)
    gload16(kTb + i * 2048 + tid * 8, Ks[0] + i * 2048 + wave * 512);
  gload16(WgB, Ws[0] + tid * 8);
  __builtin_amdgcn_sched_barrier(0);
  short8 pfn[2];
  pfn[0] = *(const short8*)(PgB);          // issued AFTER Ks[0]/Ws[0]
  pfn[1] = *(const short8*)(PgB + 32);
  __builtin_amdgcn_sched_barrier(0);
  float gnext = gsc[(size_t)bh * 2048 + lane], gnn = 0.f;
  short8 qfr[8], yfr[8];
  {
    const bf16* qrow = qb + (size_t)(16 * rt + lm) * KDIM_;
    const bf16* yrow = Yg + (size_t)bh * 32 * 16384 + (size_t)(16 * rt + lm) * 256;
#pragma unroll
    for (int kf = 0; kf < 8; kf++) {
      qfr[kf] = *(const short8*)(qrow + 8 * quad + 32 * kf);
      yfr[kf] = *(const short8*)(yrow + 8 * quad + 32 * kf);
    }
  }

  for (int c = 0; c < 32; c++) {
    const int r0 = c * 64;
    const int idx = c & 1;
    const bf16* Ksb = Ks[idx];
    const bf16* Wsb = Ws[idx];
    bf16* Ksn = Ks[idx ^ 1];
    bf16* Wsn = Ws[idx ^ 1];

    // S4: stage S^T + Gc; raw barrier (vm prefetches stay in flight)
#pragma unroll
    for (int dd = 0; dd < 4; dd++)
#pragma unroll
      for (int cc = 0; cc < 2; cc++)
        st4bf(&ST[(size_t)(16 * cc + lm) * SP2 + 16 * (4 * wave + dd) + 4 * quad], Sacc[dd][cc]);
    Gc[lane] = gnext;   // all 4 waves write identical values (benign)
    asm volatile("s_waitcnt lgkmcnt(0)" ::: "memory");
    __builtin_amdgcn_s_barrier();

    // S5: Y = Yg@S^T, O = Q@S^T (consumes qfr/yfr prefetched last chunk)
    f32x4 Yacc[2], Oacc[2];
#pragma unroll
    for (int cc = 0; cc < 2; cc++) { Yacc[cc] = (f32x4){0.f,0.f,0.f,0.f}; Oacc[cc] = (f32x4){0.f,0.f,0.f,0.f}; }
#pragma unroll
    for (int cc = 0; cc < 2; cc++) {
      short8 Bs2[8];
#pragma unroll
      for (int kf = 0; kf < 8; kf++)
        Bs2[kf] = *(const short8*)&ST[(size_t)(16 * cc + lm) * SP2 + 8 * quad + 32 * kf];
#pragma unroll
      for (int kf = 0; kf < 8; kf++) {
        Yacc[cc] = __builtin_amdgcn_mfma_f32_16x16x32_bf16(yfr[kf], Bs2[kf], Yacc[cc], 0, 0, 0);
        Oacc[cc] = __builtin_amdgcn_mfma_f32_16x16x32_bf16(qfr[kf], Bs2[kf], Oacc[cc], 0, 0, 0);
      }
    }
    __builtin_amdgcn_sched_barrier(0);

    // ISSUE block for chunk c+1: Ks'/Ws' (gload_lds) then q/Y/gsc reg refill
    {
      int cn = (c + 1) & 31;           // c=31 wraps: valid addresses, unused
      size_t cbn = (size_t)bh * 32 + cn;
      const bf16* slab = kTb + (size_t)cn * 16384;
#pragma unroll
      for (int i = 0; i < 8; i++)
        gload16(slab + i * 2048 + tid * 8, Ksn + i * 2048 + wave * 512);
      gload16(WgB + (size_t)cn * 32768, Wsn + tid * 8);
      __builtin_amdgcn_sched_barrier(0);
      gnn = gsc[cbn * 64 + lane];
      const bf16* qrow = qb + (size_t)(cn * 64 + 16 * rt + lm) * KDIM_;
      const bf16* yrow = Yg + cbn * 16384 + (size_t)(16 * rt + lm) * 256;
#pragma unroll
      for (int kf = 0; kf < 8; kf++) {
        qfr[kf] = *(const short8*)(qrow + 8 * quad + 32 * kf);
        yfr[kf] = *(const short8*)(yrow + 8 * quad + 32 * kf);
      }
    }
    __builtin_amdgcn_sched_barrier(0);

    // S7: tie pfn (loaded last chunk AFTER Ks[idx]/Ws[idx] -> wait covers both,
    // with a full chunk of issue-to-use distance); delta = W - Y@S; dT/dTe.
    asm volatile("" : : "v"(*(const int*)&pfn[0]), "v"(*(const int*)&pfn[1]) : "memory");
    __builtin_amdgcn_sched_barrier(0);
    float g63 = Gc[63];
    float lamv[4], erv[4];
#pragma unroll
    for (int rr = 0; rr < 4; rr++) {
      float gr = Gc[16 * rt + 4 * quad + rr];
      lamv[rr] = __expf(gr);
      erv[rr]  = __expf(g63 - gr);
    }
#pragma unroll
    for (int cc = 0; cc < 2; cc++) {
      short4v dpack, depack;
#pragma unroll
      for (int rr = 0; rr < 4; rr++) {
        int row = 16 * rt + 4 * quad + rr;
        float dv = bf2f(Wsb[row * 32 + 16 * cc + lm]) - Yacc[cc][rr];
        Oacc[cc][rr] *= lamv[rr];
        dpack[rr]  = (short)f2bf(dv);
        depack[rr] = (short)f2bf(dv * erv[rr]);
      }
      *(short4v*)&dT [(size_t)(16 * cc + lm) * SD + 16 * rt + 4 * quad] = dpack;
      *(short4v*)&dTe[(size_t)(16 * cc + lm) * SD + 16 * rt + 4 * quad] = depack;
    }
    asm volatile("s_waitcnt lgkmcnt(0)" ::: "memory");
    __builtin_amdgcn_s_barrier();

    // S9 (critical path first): S <- lend*S + K^T @ (e*delta)
    float lend = __expf(g63);
    short8 Be[2][2];
#pragma unroll
    for (int cc = 0; cc < 2; cc++)
#pragma unroll
      for (int kf = 0; kf < 2; kf++)
        Be[cc][kf] = ld76(&dTe[(size_t)(16 * cc + lm) * SD + 8 * quad + 32 * kf]);
#pragma unroll
    for (int dd = 0; dd < 4; dd++) {
      int Dt = 4 * wave + dd;
#pragma unroll
      for (int cc = 0; cc < 2; cc++) {
        f32x4 s = Sacc[dd][cc];
        s[0] *= lend; s[1] *= lend; s[2] *= lend; s[3] *= lend;
#pragma unroll
        for (int kf = 0; kf < 2; kf++) {
          short8 ka = *(const short8*)&Ksb[((size_t)(quad + 4 * kf) * 256 + 16 * Dt + lm) * 8];
          s = __builtin_amdgcn_mfma_f32_16x16x32_bf16(ka, Be[cc][kf], s, 0, 0, 0);
        }
        Sacc[dd][cc] = s;
      }
    }

    // S8: O += P@delta (consumes pfn), store O
#pragma unroll
    for (int cc = 0; cc < 2; cc++) {
#pragma unroll
      for (int kf = 0; kf < 2; kf++) {
        short8 bd = ld76(&dT[(size_t)(16 * cc + lm) * SD + 8 * quad + 32 * kf]);
        Oacc[cc] = __builtin_amdgcn_mfma_f32_16x16x32_bf16(pfn[kf], bd, Oacc[cc], 0, 0, 0);
      }
#pragma unroll
      for (int rr = 0; rr < 4; rr++) {
        int row = 16 * rt + 4 * quad + rr;
        ob[(size_t)(r0 + row) * VDIM_ + 16 * cc + lm] = f2bf(Oacc[cc][rr]);
      }
    }
    __builtin_amdgcn_sched_barrier(0);

    // refill pfn for chunk c+1 (after consumption; after Ks'/Ws' in issue order)
    {
      int cn = (c + 1) & 31;
      const bf16* pc = PgB + (size_t)cn * 4096;
      pfn[0] = *(const short8*)(pc);
      pfn[1] = *(const short8*)(pc + 32);
    }
    gnext = gnn;
    asm volatile("s_waitcnt lgkmcnt(0)" ::: "memory");
    __builtin_amdgcn_s_barrier();      // protect ST/dT/dTe overwrite next iter
  }
}

// ---------------- gated RMSNorm (in place, bf16) ----------------

__global__ __launch_bounds__(256) void gated_rms_kernel(bf16* __restrict__ o,
                                                        const bf16* __restrict__ gate,
                                                        const float* __restrict__ onw) {
  __shared__ float red[4];
  int blk = blockIdx.x;
  int h = blk & 3;
  int bt = blk >> 2;
  size_t base = (size_t)bt * VDIM_ + h * DV_;
  int tid = threadIdx.x;
  float o1 = bf2f(o[base + tid]), o2 = bf2f(o[base + tid + 256]);
  float ss = block_sum256(o1 * o1 + o2 * o2, red);
  float s = rsqrtf(ss * (1.f / DV_) + 1e-5f);
  float g1 = bf2f(gate[base + tid]), g2 = bf2f(gate[base + tid + 256]);
  o[base + tid]       = f2bf(o1 * s * onw[tid] * siluf_(g1));
  o[base + tid + 256] = f2bf(o2 * s * onw[tid + 256] * siluf_(g2));
}

// ---------------- launch ----------------

extern "C" void kernel_launch(void* const* d_in, const int* in_sizes, int n_in,
                              void* d_out, int out_size, void* d_ws, size_t ws_size,
                              hipStream_t stream) {
  const float* x        = (const float*)d_in[0];
  const float* Wq       = (const float*)d_in[1];
  const float* Wk       = (const float*)d_in[2];
  const float* Wv       = (const float*)d_in[3];
  const float* Wa       = (const float*)d_in[4];
  const float* Wb       = (const float*)d_in[5];
  const float* Wg       = (const float*)d_in[6];
  const float* conv_q_w = (const float*)d_in[7];
  const float* conv_k_w = (const float*)d_in[8];
  const float* conv_v_w = (const float*)d_in[9];
  const float* A_log    = (const float*)d_in[10];
  const float* dt_bias  = (const float*)d_in[11];
  const float* o_norm_w = (const float*)d_in[12];
  const float* Wo       = (const float*)d_in[13];
  const float* ln1_w    = (const float*)d_in[14];
  const float* ln1_b    = (const float*)d_in[15];
  const float* ln2_w    = (const float*)d_in[16];
  const float* ln2_b    = (const float*)d_in[17];
  const float* ffn_w1   = (const float*)d_in[18];
  const float* ffn_b1   = (const float*)d_in[19];
  const float* ffn_w2   = (const float*)d_in[20];
  const float* ffn_b2   = (const float*)d_in[21];

  size_t required = (size_t)218 << 20;
  if (ws_size < required) {
    sentinel_kernel<<<(out_size + 255) / 256, 256, 0, stream>>>((float*)d_out, out_size);
    return;
  }

  char* base = (char*)d_ws;
  float* pre    = (float*)(base);                        // 64MB scratch (proj outs)
  bf16*  normed = (bf16*)(base + ((size_t)64  << 20));   // 16MB
  bf16*  q16    = (bf16*)(base + ((size_t)80  << 20));   // 16MB
  bf16*  k16    = (bf16*)(base + ((size_t)96  << 20));   // 16MB
  bf16*  v16    = (bf16*)(base + ((size_t)112 << 20));   // 32MB
  bf16*  g16    = (bf16*)(base + ((size_t)144 << 20));   // 32MB
  bf16*  o16    = (bf16*)(base + ((size_t)176 << 20));   // 32MB
  bf16*  wslot  = (bf16*)(base + ((size_t)208 << 20));   // 8MB JIT weight slot
  float* gvec   = (float*)(base + ((size_t)216 << 20));  // 128KB
  float* bvec   = gvec + (size_t)BT_ * H_;               // 128KB
  float* gsc    = (float*)(base + ((size_t)217 << 20));  // 128KB
  // delta-phase buffers (pre region + normed region, dead after ab_kernel):
  bf16*  Yg     = (bf16*)(base);                         // 16MB  [0,16)
  bf16*  Wgb    = (bf16*)(base + ((size_t)16 << 20));    // 32MB  [16,48)
  bf16*  Pg     = (bf16*)(base + ((size_t)48 << 20));    // 4MB   [48,52)
  bf16*  kTg    = (bf16*)(base + ((size_t)52 << 20));    // 16MB  [52,68)
  // later reuses:
  float* x2     = (float*)(base);                        // 32MB (after delta)
  bf16*  hb16   = (bf16*)(base + ((size_t)64  << 20));
  bf16*  ffn1   = (bf16*)(base + ((size_t)80  << 20));

  // 1) LN1 -> bf16
  ln_kernel<<<BT_, 256, 0, stream>>>(x, ln1_w, ln1_b, normed);

  // 2) projections + convs
  convT_kernel<<<dim3(KDIM_ / 32, D_ / 32), 256, 0, stream>>>(Wq, wslot, D_, KDIM_);
  gemm_mfma<float><<<dim3(KDIM_ / 128, BT_ / 128), 256, 0, stream>>>(normed, wslot, nullptr, nullptr, pre, KDIM_, D_, 0);
  conv_qk_kernel<<<BT_ * H_, 256, 0, stream>>>(pre, conv_q_w, q16, 0.0625f);

  convT_kernel<<<dim3(KDIM_ / 32, D_ / 32), 256, 0, stream>>>(Wk, wslot, D_, KDIM_);
  gemm_mfma<float><<<dim3(KDIM_ / 128, BT_ / 128), 256, 0, stream>>>(normed, wslot, nullptr, nullptr, pre, KDIM_, D_, 0);
  conv_qk_kernel<<<BT_ * H_, 256, 0, stream>>>(pre, conv_k_w, k16, 1.0f);

  convT_kernel<<<dim3(VDIM_ / 32, D_ / 32), 256, 0, stream>>>(Wv, wslot, D_, VDIM_);
  gemm256<float><<<dim3(VDIM_ / 256, BT_ / 256), 512, 0, stream>>>(normed, wslot, nullptr, nullptr, pre, VDIM_, D_, 0);
  conv_v_kernel<<<(BT_ * VDIM_) / 256, 256, 0, stream>>>(pre, conv_v_w, v16);

  convT_kernel<<<dim3(VDIM_ / 32, D_ / 32), 256, 0, stream>>>(Wg, wslot, D_, VDIM_);
  gemm256<bf16><<<dim3(VDIM_ / 256, BT_ / 256), 512, 0, stream>>>(normed, wslot, nullptr, nullptr, g16, VDIM_, D_, 0);

  ab_kernel<<<BT_, 256, 0, stream>>>(normed, Wa, Wb, A_log, dt_bias, gvec, bvec);

  // 3) delta rule: kT transpose (chunk-major) + phase 1 + pipelined phase 2
  kT_kernel<<<dim3(T_ / 32, DK_ / 32, 16), 256, 0, stream>>>(k16, kTg);
  delta_p1<<<512, 256, 0, stream>>>(q16, k16, v16, gvec, bvec, Pg, Wgb, Yg, gsc);
  delta_p2<<<256, 256, 0, stream>>>(q16, kTg, Wgb, Yg, Pg, gsc, o16);

  // 4) gated RMSNorm (in place)
  gated_rms_kernel<<<BT_ * H_, 256, 0, stream>>>(o16, g16, o_norm_w);

  // 5) x2 = x + o @ Wo
  convT_kernel<<<dim3(D_ / 32, VDIM_ / 32), 256, 0, stream>>>(Wo, wslot, VDIM_, D_);
  gemm_mfma<float><<<dim3(D_ / 128, BT_ / 128), 256, 0, stream>>>(o16, wslot, nullptr, x, x2, D_, VDIM_, 4);

  // 6) LN2 -> bf16
  ln_kernel<<<BT_, 256, 0, stream>>>(x2, ln2_w, ln2_b, hb16);

  // 7) FFN
  convT_kernel<<<dim3(FFN_ / 32, D_ / 32), 256, 0, stream>>>(ffn_w1, wslot, D_, FFN_);
  gemm256<bf16><<<dim3(FFN_ / 256, BT_ / 256), 512, 0, stream>>>(hb16, wslot, ffn_b1, nullptr, ffn1, FFN_, D_, 1 | 2);
  convT_kernel<<<dim3(D_ / 32, FFN_ / 32), 256, 0, stream>>>(ffn_w2, wslot, FFN_, D_);
  gemm_mfma<float><<<dim3(D_ / 128, BT_ / 128), 256, 0, stream>>>(ffn1, wslot, ffn_b2, x2, (float*)d_out, D_, FFN_, 1 | 4);
}